// Round 1
// baseline (971.688 us; speedup 1.0000x reference)
//
#include <hip/hip_runtime.h>
#include <math.h>

#define GRAVITY_C 9.81007f
#define SIG_G2_C (1.6968e-4f * 1.6968e-4f)
#define SIG_A2_C (2.0e-3f * 2.0e-3f)

// Segment summary: composable preintegration state (92 floats)
struct Seg {
  float q[4];            // segment delta-rotation quat (xyzw)
  float t;               // accumulated time
  float u[3], w[3];      // dv = u - G g', dp = w - H g'
  float G[9], H[9];
  float P10[9], P20[9];  // Phi(1,0), Phi(2,0) blocks of 9x9 transition
  float c00[6], c01[9], c02[9], c11[6], c12[9], c22[6]; // sym cov blocks
};

static __device__ __forceinline__ void q2m(const float q[4], float R[9]) {
  float x = q[0], y = q[1], z = q[2], w = q[3];
  R[0] = 1.f - 2.f * (y * y + z * z); R[1] = 2.f * (x * y - z * w);       R[2] = 2.f * (x * z + y * w);
  R[3] = 2.f * (x * y + z * w);       R[4] = 1.f - 2.f * (x * x + z * z); R[5] = 2.f * (y * z - x * w);
  R[6] = 2.f * (x * z - y * w);       R[7] = 2.f * (y * z + x * w);       R[8] = 1.f - 2.f * (x * x + y * y);
}

static __device__ __forceinline__ void qmul(const float a[4], const float b[4], float o[4]) {
  float x1 = a[0], y1 = a[1], z1 = a[2], w1 = a[3];
  float x2 = b[0], y2 = b[1], z2 = b[2], w2 = b[3];
  o[0] = w1 * x2 + x1 * w2 + y1 * z2 - z1 * y2;
  o[1] = w1 * y2 - x1 * z2 + y1 * w2 + z1 * x2;
  o[2] = w1 * z2 + x1 * y2 - y1 * x2 + z1 * w2;
  o[3] = w1 * w2 - x1 * x2 - y1 * y2 - z1 * z2;
}

// C = A @ B
static __device__ __forceinline__ void mm(const float A[9], const float B[9], float C[9]) {
#pragma unroll
  for (int i = 0; i < 3; i++)
#pragma unroll
    for (int j = 0; j < 3; j++)
      C[3 * i + j] = A[3 * i + 0] * B[0 + j] + A[3 * i + 1] * B[3 + j] + A[3 * i + 2] * B[6 + j];
}
// C = A @ B^T
static __device__ __forceinline__ void mmT(const float A[9], const float B[9], float C[9]) {
#pragma unroll
  for (int i = 0; i < 3; i++)
#pragma unroll
    for (int j = 0; j < 3; j++)
      C[3 * i + j] = A[3 * i + 0] * B[3 * j + 0] + A[3 * i + 1] * B[3 * j + 1] + A[3 * i + 2] * B[3 * j + 2];
}
// C = A^T @ B
static __device__ __forceinline__ void mTm(const float A[9], const float B[9], float C[9]) {
#pragma unroll
  for (int i = 0; i < 3; i++)
#pragma unroll
    for (int j = 0; j < 3; j++)
      C[3 * i + j] = A[0 + i] * B[0 + j] + A[3 + i] * B[3 + j] + A[6 + i] * B[6 + j];
}

static __device__ __forceinline__ void expand6(const float c[6], float f[9]) {
  f[0] = c[0]; f[1] = c[1]; f[2] = c[2];
  f[3] = c[1]; f[4] = c[3]; f[5] = c[4];
  f[6] = c[2]; f[7] = c[4]; f[8] = c[5];
}

// sym index tables: entries (0,0),(0,1),(0,2),(1,1),(1,2),(2,2)
__device__ __constant__ const int SI6[6] = {0, 0, 0, 1, 1, 2};
__device__ __constant__ const int SJ6[6] = {0, 1, 2, 1, 2, 2};

// One IMU step folded into the segment summary (standalone, gravity-affine).
static __device__ __forceinline__ void step(Seg& s, float dtv,
                                            float omx, float omy, float omz,
                                            float acx, float acy, float acz) {
  // ---- dr = Exp(ang*dt) ----
  float px = omx * dtv, py = omy * dtv, pz = omz * dtv;
  float t2 = px * px + py * py + pz * pz;
  bool sm = t2 < 1e-8f;
  float t2s = sm ? 1.0f : t2;
  float t = sqrtf(t2s);
  float rt_ = 1.0f / t;
  float ht = 0.5f * t, ht2 = ht * ht;
  // f32-exact polynomials for |t| <= ~0.05 rad (data range)
  float sh = ht * (1.0f - ht2 * (1.0f / 6.0f) * (1.0f - 0.05f * ht2));
  float ch = 1.0f - 0.5f * ht2 * (1.0f - (1.0f / 12.0f) * ht2);
  float s_ = sm ? (0.5f - t2 * (1.0f / 48.0f)) : sh * rt_;
  float qd[4] = {px * s_, py * s_, pz * s_, sm ? (1.0f - 0.125f * t2) : ch};
  float rt2 = rt_ * rt_;
  float sint = 2.0f * sh * ch;
  float c1 = sm ? (0.5f - t2 * (1.0f / 24.0f)) : (2.0f * sh * sh * rt2);
  float c2 = sm ? (1.0f / 6.0f - t2 * (1.0f / 120.0f)) : ((t - sint) * rt2 * rt_);

  // ---- rotate pieces with OLD q ----
  float Ro[9]; q2m(s.q, Ro);
  float Racc[3];
#pragma unroll
  for (int i = 0; i < 3; i++)
    Racc[i] = Ro[3 * i + 0] * acx + Ro[3 * i + 1] * acy + Ro[3 * i + 2] * acz;
  float vr[3];
#pragma unroll
  for (int i = 0; i < 3; i++)
    vr[i] = Ro[3 * i + 0] * qd[0] + Ro[3 * i + 1] * qd[1] + Ro[3 * i + 2] * qd[2];
  float qs[4] = {-vr[0], -vr[1], -vr[2], qd[3]};
  float S[9]; q2m(qs, S); // S = R(q) R(dr)^T R(q)^T

  // ---- integrate dp/dv (affine in gravity): w,H before u,G ----
  float hdt2 = 0.5f * dtv * dtv;
#pragma unroll
  for (int i = 0; i < 3; i++) s.w[i] += s.u[i] * dtv + Racc[i] * hdt2;
#pragma unroll
  for (int k = 0; k < 9; k++) s.H[k] += s.G[k] * dtv + S[k] * hdt2;
#pragma unroll
  for (int i = 0; i < 3; i++) s.u[i] += Racc[i] * dtv;
#pragma unroll
  for (int k = 0; k < 9; k++) s.G[k] += S[k] * dtv;

  // ---- rotation update ----
  float qn[4]; qmul(s.q, qd, qn);
  float Rn[9]; q2m(qn, Rn);
  float Rd[9]; q2m(qd, Rd); // D = Rd^T

  // ---- M = -dt * (Rn @ skew(acc)) ----
  float M[9];
#pragma unroll
  for (int i = 0; i < 3; i++) {
    M[3 * i + 0] = -dtv * (Rn[3 * i + 1] * acz - Rn[3 * i + 2] * acy);
    M[3 * i + 1] = -dtv * (-Rn[3 * i + 0] * acz + Rn[3 * i + 2] * acx);
    M[3 * i + 2] = -dtv * (Rn[3 * i + 0] * acy - Rn[3 * i + 1] * acx);
  }

  // ---- Phi blocks: P20 before P10 ----
  float TP[9]; mmT(M, Ro, TP); // M @ Ro^T
#pragma unroll
  for (int k = 0; k < 9; k++) s.P20[k] += 0.5f * dtv * TP[k] + dtv * s.P10[k];
#pragma unroll
  for (int k = 0; k < 9; k++) s.P10[k] += TP[k];

  // ---- covariance: cov' = A cov A^T + Q (block-structured) ----
  float C00f[9]; expand6(s.c00, C00f);
  float X0[9]; mTm(Rd, C00f, X0); // D @ C00
  float Y0[9]; mm(M, C00f, Y0);   // M @ C00

  // Jr = (1 - c2 t2) I - c1 K + c2 p p^T ; noise c00 += SIG_G2 dt^2 Jr Jr^T
  float omc = 1.0f - c2 * t2;
  float Jr[9] = {omc + c2 * px * px,  c1 * pz + c2 * px * py, -c1 * py + c2 * px * pz,
                 -c1 * pz + c2 * py * px, omc + c2 * py * py,  c1 * px + c2 * py * pz,
                  c1 * py + c2 * pz * px, -c1 * px + c2 * pz * py, omc + c2 * pz * pz};
  float sgdt2 = SIG_G2_C * dtv * dtv;
#pragma unroll
  for (int s6 = 0; s6 < 6; s6++) {
    const int i = SI6[s6], j = SJ6[s6];
    float v = X0[3 * i + 0] * Rd[0 + j] + X0[3 * i + 1] * Rd[3 + j] + X0[3 * i + 2] * Rd[6 + j];
    float jj = Jr[3 * i + 0] * Jr[3 * j + 0] + Jr[3 * i + 1] * Jr[3 * j + 1] + Jr[3 * i + 2] * Jr[3 * j + 2];
    s.c00[s6] = v + sgdt2 * jj;
  }

  float Z[9];  mmT(X0, M, Z);  // (D C00) M^T
  float Wm[9]; mmT(Y0, M, Wm); // M C00 M^T (sym)
  float X1[9]; mTm(Rd, s.c01, X1);
  float Y1[9]; mm(M, s.c01, Y1);
#pragma unroll
  for (int k = 0; k < 9; k++) s.c01[k] = Z[k] + X1[k];
  float X2[9]; mTm(Rd, s.c02, X2);
  float Y2[9]; mm(M, s.c02, Y2);
  float hdt = 0.5f * dtv;
#pragma unroll
  for (int k = 0; k < 9; k++) s.c02[k] = hdt * Z[k] + dtv * X1[k] + X2[k];

  float C11f[9]; expand6(s.c11, C11f);
  float dt2v = dtv * dtv;
  // c22 first (uses old c11, c12, c22)
#pragma unroll
  for (int s6 = 0; s6 < 6; s6++) {
    const int i = SI6[s6], j = SJ6[s6];
    float v = 0.25f * dt2v * Wm[3 * i + j]
            + 0.5f * dt2v * (Y1[3 * i + j] + Y1[3 * j + i])
            + hdt * (Y2[3 * i + j] + Y2[3 * j + i])
            + dt2v * C11f[3 * i + j]
            + dtv * (s.c12[3 * i + j] + s.c12[3 * j + i])
            + s.c22[s6];
    if (i == j) v += SIG_A2_C * 0.25f * dt2v * dt2v;
    s.c22[s6] = v;
  }
  // c12 (elementwise in place, uses old c11 via C11f)
#pragma unroll
  for (int i = 0; i < 3; i++)
#pragma unroll
    for (int j = 0; j < 3; j++) {
      float v = hdt * (Wm[3 * i + j] + Y1[3 * j + i]) + dtv * Y1[3 * i + j]
              + dtv * C11f[3 * i + j] + Y2[3 * i + j] + s.c12[3 * i + j];
      if (i == j) v += SIG_A2_C * hdt * dt2v;
      s.c12[3 * i + j] = v;
    }
  // c11 last
#pragma unroll
  for (int s6 = 0; s6 < 6; s6++) {
    const int i = SI6[s6], j = SJ6[s6];
    float v = Wm[3 * i + j] + Y1[3 * i + j] + Y1[3 * j + i] + s.c11[s6];
    if (i == j) v += SIG_A2_C * dt2v;
    s.c11[s6] = v;
  }

  // commit
#pragma unroll
  for (int i = 0; i < 4; i++) s.q[i] = qn[i];
  s.t += dtv;
}

template <int CNT>
static __device__ __forceinline__ void shsel(const float* v, int d, bool rt, float* X, float* Y) {
#pragma unroll
  for (int i = 0; i < CNT; i++) {
    float o = __shfl_xor(v[i], d, 64);
    X[i] = rt ? o : v[i];
    Y[i] = rt ? v[i] : o;
  }
}

// Compose partner segments across lanes: result = X (earlier) then Y (later).
static __device__ __forceinline__ void compose(Seg& s, int d, int lane) {
  bool rt = (lane & d) != 0;

  float xq[4], yq[4];
  shsel<4>(s.q, d, rt, xq, yq);
  float ot = __shfl_xor(s.t, d, 64);
  float tY = rt ? s.t : ot;
  s.t = s.t + ot;
  float RX[9], RY[9];
  q2m(xq, RX); q2m(yq, RY);
  qmul(xq, yq, s.q);

  // u, w  (w before u)
  float xu[3], yu[3], xw[3], yw[3];
  shsel<3>(s.u, d, rt, xu, yu);
  shsel<3>(s.w, d, rt, xw, yw);
#pragma unroll
  for (int i = 0; i < 3; i++)
    s.w[i] = xw[i] + tY * xu[i] + RX[3 * i + 0] * yw[0] + RX[3 * i + 1] * yw[1] + RX[3 * i + 2] * yw[2];
#pragma unroll
  for (int i = 0; i < 3; i++)
    s.u[i] = xu[i] + RX[3 * i + 0] * yu[0] + RX[3 * i + 1] * yu[1] + RX[3 * i + 2] * yu[2];

  // H before G
  float xH[9], yH[9], xG[9], yG[9];
  shsel<9>(s.H, d, rt, xH, yH);
  shsel<9>(s.G, d, rt, xG, yG);
  {
    float A2[9], T[9];
    mm(RX, yH, A2); mmT(A2, RX, T);
#pragma unroll
    for (int k = 0; k < 9; k++) s.H[k] = xH[k] + tY * xG[k] + T[k];
    mm(RX, yG, A2); mmT(A2, RX, T);
#pragma unroll
    for (int k = 0; k < 9; k++) s.G[k] = xG[k] + T[k];
  }

  // P20 before P10 ; keep M10,M20 for covariance
  float xP20[9], yP20[9], xP10[9], yP10[9];
  shsel<9>(s.P20, d, rt, xP20, yP20);
  shsel<9>(s.P10, d, rt, xP10, yP10);
  float M20[9], M10[9];
  {
    float T[9];
    mm(RX, yP20, M20); mmT(M20, RX, T);
#pragma unroll
    for (int k = 0; k < 9; k++) s.P20[k] = xP20[k] + tY * xP10[k] + T[k];
    mm(RX, yP10, M10); mmT(M10, RX, T);
#pragma unroll
    for (int k = 0; k < 9; k++) s.P10[k] = xP10[k] + T[k];
  }

  // ---- covariance: cov' = Mm covX Mm^T + T covY T^T ----
  float x00[6], y00[6];
  shsel<6>(s.c00, d, rt, x00, y00);
  float X00f[9]; expand6(x00, X00f);
  float B0[9]; mTm(RY, X00f, B0);
  float U1[9]; mm(M10, X00f, U1);
  float U2[9]; mm(M20, X00f, U2);
#pragma unroll
  for (int s6 = 0; s6 < 6; s6++) {
    const int i = SI6[s6], j = SJ6[s6];
    s.c00[s6] = B0[3 * i + 0] * RY[0 + j] + B0[3 * i + 1] * RY[3 + j] + B0[3 * i + 2] * RY[6 + j] + y00[s6];
  }

  float x01[9], y01[9];
  shsel<9>(s.c01, d, rt, x01, y01);
  float B1[9]; mTm(RY, x01, B1);
  float V1[9]; mm(M10, x01, V1);
  float V2[9]; mm(M20, x01, V2);
  {
    float T1[9], T2[9];
    mmT(B0, M10, T1); mmT(y01, RX, T2);
#pragma unroll
    for (int k = 0; k < 9; k++) s.c01[k] = T1[k] + B1[k] + T2[k];
  }

  float x02[9], y02[9];
  shsel<9>(s.c02, d, rt, x02, y02);
  float W1[9], W2[9];
  {
    float B2[9], T1[9], T2[9];
    mTm(RY, x02, B2); mm(M10, x02, W1); mm(M20, x02, W2);
    mmT(B0, M20, T1); mmT(y02, RX, T2);
#pragma unroll
    for (int k = 0; k < 9; k++) s.c02[k] = T1[k] + tY * B1[k] + B2[k] + T2[k];
  }

  float x11[6], y11[6], x12[9], y12[9], x22[6], y22[6];
  shsel<6>(s.c11, d, rt, x11, y11);
  shsel<9>(s.c12, d, rt, x12, y12);
  shsel<6>(s.c22, d, rt, x22, y22);
  float X11f[9]; expand6(x11, X11f);

  // c22
  {
    float Ta[9]; mmT(U2, M20, Ta);
    float Y22f[9]; expand6(y22, Y22f);
    float A5[9]; mm(RX, Y22f, A5);
#pragma unroll
    for (int s6 = 0; s6 < 6; s6++) {
      const int i = SI6[s6], j = SJ6[s6];
      float cj = A5[3 * i + 0] * RX[3 * j + 0] + A5[3 * i + 1] * RX[3 * j + 1] + A5[3 * i + 2] * RX[3 * j + 2];
      s.c22[s6] = Ta[3 * i + j] + tY * (V2[3 * i + j] + V2[3 * j + i])
                + (W2[3 * i + j] + W2[3 * j + i]) + tY * tY * X11f[3 * i + j]
                + tY * (x12[3 * i + j] + x12[3 * j + i]) + x22[s6] + cj;
    }
  }
  // c12
  {
    float Tb[9]; mmT(U1, M20, Tb);
    float A4[9]; mm(RX, y12, A4);
    float C4[9]; mmT(A4, RX, C4);
#pragma unroll
    for (int i = 0; i < 3; i++)
#pragma unroll
      for (int j = 0; j < 3; j++)
        s.c12[3 * i + j] = Tb[3 * i + j] + tY * V1[3 * i + j] + W1[3 * i + j] + V2[3 * j + i]
                         + tY * X11f[3 * i + j] + x12[3 * i + j] + C4[3 * i + j];
  }
  // c11
  {
    float Tc[9]; mmT(U1, M10, Tc);
    float Y11f[9]; expand6(y11, Y11f);
    float A3[9]; mm(RX, Y11f, A3);
#pragma unroll
    for (int s6 = 0; s6 < 6; s6++) {
      const int i = SI6[s6], j = SJ6[s6];
      float cj = A3[3 * i + 0] * RX[3 * j + 0] + A3[3 * i + 1] * RX[3 * j + 1] + A3[3 * i + 2] * RX[3 * j + 2];
      s.c11[s6] = Tc[3 * i + j] + V1[3 * i + j] + V1[3 * j + i] + x11[s6] + cj;
    }
  }
}

__global__ __launch_bounds__(256, 2) void imu_kernel(
    const float* __restrict__ dt, const float* __restrict__ ang, const float* __restrict__ acc,
    const float* __restrict__ pos0, const float* __restrict__ vel0, const float* __restrict__ rot0,
    float* __restrict__ out, int B, int N) {
  int wave = threadIdx.x >> 6;
  int lane = threadIdx.x & 63;
  int b = blockIdx.x * 4 + wave;
  if (b >= B) return;
  int chunk = N >> 6; // 16 steps per lane

  Seg s = {};
  s.q[3] = 1.0f;

  long base = (long)b * N + (long)lane * chunk;
  const float* dtp = dt + base;
  const float* angp = ang + base * 3;
  const float* accp = acc + base * 3;

  // phase 1: sequential chunk integration, 4 steps per iteration (float4 loads)
#pragma unroll 1
  for (int jb = 0; jb < (chunk >> 2); ++jb) {
    float4 d4 = *reinterpret_cast<const float4*>(dtp + jb * 4);
    float4 g0 = *reinterpret_cast<const float4*>(angp + jb * 12 + 0);
    float4 g1 = *reinterpret_cast<const float4*>(angp + jb * 12 + 4);
    float4 g2 = *reinterpret_cast<const float4*>(angp + jb * 12 + 8);
    float4 a0 = *reinterpret_cast<const float4*>(accp + jb * 12 + 0);
    float4 a1 = *reinterpret_cast<const float4*>(accp + jb * 12 + 4);
    float4 a2 = *reinterpret_cast<const float4*>(accp + jb * 12 + 8);
    step(s, d4.x, g0.x, g0.y, g0.z, a0.x, a0.y, a0.z);
    step(s, d4.y, g0.w, g1.x, g1.y, a0.w, a1.x, a1.y);
    step(s, d4.z, g1.z, g1.w, g2.x, a1.z, a1.w, a2.x);
    step(s, d4.w, g2.y, g2.z, g2.w, a2.y, a2.z, a2.w);
  }

  // phase 2: non-commutative butterfly reduction over 64 chunks
#pragma unroll 1
  for (int d = 1; d < 64; d <<= 1) compose(s, d, lane);

  if (lane == 0) {
    float r0q[4] = {rot0[b * 4 + 0], rot0[b * 4 + 1], rot0[b * 4 + 2], rot0[b * 4 + 3]};
    float p0[3] = {pos0[b * 3 + 0], pos0[b * 3 + 1], pos0[b * 3 + 2]};
    float v0[3] = {vel0[b * 3 + 0], vel0[b * 3 + 1], vel0[b * 3 + 2]};
    float R0[9]; q2m(r0q, R0);
    float gp[3]; // R0^T * (0,0,g)
#pragma unroll
    for (int i = 0; i < 3; i++) gp[i] = R0[6 + i] * GRAVITY_C;
    float dv[3], dp[3];
#pragma unroll
    for (int i = 0; i < 3; i++) {
      dv[i] = s.u[i] - (s.G[3 * i + 0] * gp[0] + s.G[3 * i + 1] * gp[1] + s.G[3 * i + 2] * gp[2]);
      dp[i] = s.w[i] - (s.H[3 * i + 0] * gp[0] + s.H[3 * i + 1] * gp[1] + s.H[3 * i + 2] * gp[2]);
    }
    float qo[4]; qmul(r0q, s.q, qo);
#pragma unroll
    for (int i = 0; i < 4; i++) out[b * 4 + i] = qo[i];
#pragma unroll
    for (int i = 0; i < 3; i++) {
      float vv = v0[i] + R0[3 * i + 0] * dv[0] + R0[3 * i + 1] * dv[1] + R0[3 * i + 2] * dv[2];
      float pv = p0[i] + v0[i] * s.t + R0[3 * i + 0] * dp[0] + R0[3 * i + 1] * dp[1] + R0[3 * i + 2] * dp[2];
      out[4 * B + b * 3 + i] = vv;
      out[7 * B + b * 3 + i] = pv;
    }
    long cb = 10L * B + (long)b * 81;
    float C00f[9], C11f[9], C22f[9];
    expand6(s.c00, C00f); expand6(s.c11, C11f); expand6(s.c22, C22f);
#pragma unroll
    for (int i = 0; i < 3; i++)
#pragma unroll
      for (int j = 0; j < 3; j++) {
        out[cb + i * 9 + j]           = C00f[3 * i + j];
        out[cb + i * 9 + (j + 3)]     = s.c01[3 * i + j];
        out[cb + i * 9 + (j + 6)]     = s.c02[3 * i + j];
        out[cb + (i + 3) * 9 + j]     = s.c01[3 * j + i];
        out[cb + (i + 3) * 9 + j + 3] = C11f[3 * i + j];
        out[cb + (i + 3) * 9 + j + 6] = s.c12[3 * i + j];
        out[cb + (i + 6) * 9 + j]     = s.c02[3 * j + i];
        out[cb + (i + 6) * 9 + j + 3] = s.c12[3 * j + i];
        out[cb + (i + 6) * 9 + j + 6] = C22f[3 * i + j];
      }
  }
}

extern "C" void kernel_launch(void* const* d_in, const int* in_sizes, int n_in,
                              void* d_out, int out_size, void* d_ws, size_t ws_size,
                              hipStream_t stream) {
  const float* dt   = (const float*)d_in[0];
  const float* ang  = (const float*)d_in[1];
  const float* acc  = (const float*)d_in[2];
  const float* pos0 = (const float*)d_in[3];
  const float* vel0 = (const float*)d_in[4];
  const float* rot0 = (const float*)d_in[5];
  int B = in_sizes[5] / 4;
  int N = in_sizes[0] / B;
  float* out = (float*)d_out;
  dim3 grid(B / 4), block(256);
  imu_kernel<<<grid, block, 0, stream>>>(dt, ang, acc, pos0, vel0, rot0, out, B, N);
}

// Round 2
// 318.584 us; speedup vs baseline: 3.0500x; 3.0500x over previous
//
#include <hip/hip_runtime.h>
#include <math.h>

#define GRAVITY_C 9.81007f
#define SIG_G2_C (1.6968e-4f * 1.6968e-4f)
#define SIG_A2_C (2.0e-3f * 2.0e-3f)

// Segment summary: composable preintegration state (92 floats)
struct Seg {
  float q[4];            // segment delta-rotation quat (xyzw)
  float t;               // accumulated time
  float u[3], w[3];      // dv = u - G g', dp = w - H g'
  float G[9], H[9];
  float P10[9], P20[9];  // Phi(1,0), Phi(2,0) blocks of 9x9 transition
  float c00[6], c01[9], c02[9], c11[6], c12[9], c22[6]; // sym cov blocks
};

static __device__ __forceinline__ void q2m(const float q[4], float R[9]) {
  float x = q[0], y = q[1], z = q[2], w = q[3];
  R[0] = 1.f - 2.f * (y * y + z * z); R[1] = 2.f * (x * y - z * w);       R[2] = 2.f * (x * z + y * w);
  R[3] = 2.f * (x * y + z * w);       R[4] = 1.f - 2.f * (x * x + z * z); R[5] = 2.f * (y * z - x * w);
  R[6] = 2.f * (x * z - y * w);       R[7] = 2.f * (y * z + x * w);       R[8] = 1.f - 2.f * (x * x + y * y);
}

static __device__ __forceinline__ void qmul(const float a[4], const float b[4], float o[4]) {
  float x1 = a[0], y1 = a[1], z1 = a[2], w1 = a[3];
  float x2 = b[0], y2 = b[1], z2 = b[2], w2 = b[3];
  o[0] = w1 * x2 + x1 * w2 + y1 * z2 - z1 * y2;
  o[1] = w1 * y2 - x1 * z2 + y1 * w2 + z1 * x2;
  o[2] = w1 * z2 + x1 * y2 - y1 * x2 + z1 * w2;
  o[3] = w1 * w2 - x1 * x2 - y1 * y2 - z1 * z2;
}

// C = A @ B
static __device__ __forceinline__ void mm(const float A[9], const float B[9], float C[9]) {
#pragma unroll
  for (int i = 0; i < 3; i++)
#pragma unroll
    for (int j = 0; j < 3; j++)
      C[3 * i + j] = A[3 * i + 0] * B[0 + j] + A[3 * i + 1] * B[3 + j] + A[3 * i + 2] * B[6 + j];
}
// C = A @ B^T
static __device__ __forceinline__ void mmT(const float A[9], const float B[9], float C[9]) {
#pragma unroll
  for (int i = 0; i < 3; i++)
#pragma unroll
    for (int j = 0; j < 3; j++)
      C[3 * i + j] = A[3 * i + 0] * B[3 * j + 0] + A[3 * i + 1] * B[3 * j + 1] + A[3 * i + 2] * B[3 * j + 2];
}
// C = A^T @ B
static __device__ __forceinline__ void mTm(const float A[9], const float B[9], float C[9]) {
#pragma unroll
  for (int i = 0; i < 3; i++)
#pragma unroll
    for (int j = 0; j < 3; j++)
      C[3 * i + j] = A[0 + i] * B[0 + j] + A[3 + i] * B[3 + j] + A[6 + i] * B[6 + j];
}

static __device__ __forceinline__ void expand6(const float c[6], float f[9]) {
  f[0] = c[0]; f[1] = c[1]; f[2] = c[2];
  f[3] = c[1]; f[4] = c[3]; f[5] = c[4];
  f[6] = c[2]; f[7] = c[4]; f[8] = c[5];
}

// sym index tables: entries (0,0),(0,1),(0,2),(1,1),(1,2),(2,2)
__device__ __constant__ const int SI6[6] = {0, 0, 0, 1, 1, 2};
__device__ __constant__ const int SJ6[6] = {0, 1, 2, 1, 2, 2};

// One IMU step folded into the segment summary (standalone, gravity-affine).
static __device__ __forceinline__ void step(Seg& s, float dtv,
                                            float omx, float omy, float omz,
                                            float acx, float acy, float acz) {
  // ---- dr = Exp(ang*dt) ----
  float px = omx * dtv, py = omy * dtv, pz = omz * dtv;
  float t2 = px * px + py * py + pz * pz;
  bool sm = t2 < 1e-8f;
  float t2s = sm ? 1.0f : t2;
  float t = sqrtf(t2s);
  float rt_ = 1.0f / t;
  float ht = 0.5f * t, ht2 = ht * ht;
  // f32-exact polynomials for |t| <= ~0.05 rad (data range)
  float sh = ht * (1.0f - ht2 * (1.0f / 6.0f) * (1.0f - 0.05f * ht2));
  float ch = 1.0f - 0.5f * ht2 * (1.0f - (1.0f / 12.0f) * ht2);
  float s_ = sm ? (0.5f - t2 * (1.0f / 48.0f)) : sh * rt_;
  float qd[4] = {px * s_, py * s_, pz * s_, sm ? (1.0f - 0.125f * t2) : ch};
  float rt2 = rt_ * rt_;
  float sint = 2.0f * sh * ch;
  float c1 = sm ? (0.5f - t2 * (1.0f / 24.0f)) : (2.0f * sh * sh * rt2);
  float c2 = sm ? (1.0f / 6.0f - t2 * (1.0f / 120.0f)) : ((t - sint) * rt2 * rt_);

  // ---- rotate pieces with OLD q ----
  float Ro[9]; q2m(s.q, Ro);
  float Racc[3];
#pragma unroll
  for (int i = 0; i < 3; i++)
    Racc[i] = Ro[3 * i + 0] * acx + Ro[3 * i + 1] * acy + Ro[3 * i + 2] * acz;
  float vr[3];
#pragma unroll
  for (int i = 0; i < 3; i++)
    vr[i] = Ro[3 * i + 0] * qd[0] + Ro[3 * i + 1] * qd[1] + Ro[3 * i + 2] * qd[2];
  float qs[4] = {-vr[0], -vr[1], -vr[2], qd[3]};
  float S[9]; q2m(qs, S); // S = R(q) R(dr)^T R(q)^T

  // ---- integrate dp/dv (affine in gravity): w,H before u,G ----
  float hdt2 = 0.5f * dtv * dtv;
#pragma unroll
  for (int i = 0; i < 3; i++) s.w[i] += s.u[i] * dtv + Racc[i] * hdt2;
#pragma unroll
  for (int k = 0; k < 9; k++) s.H[k] += s.G[k] * dtv + S[k] * hdt2;
#pragma unroll
  for (int i = 0; i < 3; i++) s.u[i] += Racc[i] * dtv;
#pragma unroll
  for (int k = 0; k < 9; k++) s.G[k] += S[k] * dtv;

  // ---- rotation update ----
  float qn[4]; qmul(s.q, qd, qn);
  float Rn[9]; q2m(qn, Rn);
  float Rd[9]; q2m(qd, Rd);

  // ---- M = -dt * (Rn @ skew(acc)) ----
  float M[9];
#pragma unroll
  for (int i = 0; i < 3; i++) {
    M[3 * i + 0] = -dtv * (Rn[3 * i + 1] * acz - Rn[3 * i + 2] * acy);
    M[3 * i + 1] = -dtv * (-Rn[3 * i + 0] * acz + Rn[3 * i + 2] * acx);
    M[3 * i + 2] = -dtv * (Rn[3 * i + 0] * acy - Rn[3 * i + 1] * acx);
  }

  // ---- Phi blocks: P20 before P10 ----
  {
    float TP[9]; mmT(M, Ro, TP); // M @ Ro^T
#pragma unroll
    for (int k = 0; k < 9; k++) s.P20[k] += 0.5f * dtv * TP[k] + dtv * s.P10[k];
#pragma unroll
    for (int k = 0; k < 9; k++) s.P10[k] += TP[k];
  }

  // ---- covariance: cov' = A cov A^T + Q (block-structured) ----
  float X0[9], Y0[9];
  {
    float C00f[9]; expand6(s.c00, C00f);
    mTm(Rd, C00f, X0); // D @ C00
    mm(M, C00f, Y0);   // M @ C00
  }

  // Jr = (1 - c2 t2) I - c1 K + c2 p p^T ; noise c00 += SIG_G2 dt^2 Jr Jr^T
  {
    float omc = 1.0f - c2 * t2;
    float Jr[9] = {omc + c2 * px * px,  c1 * pz + c2 * px * py, -c1 * py + c2 * px * pz,
                   -c1 * pz + c2 * py * px, omc + c2 * py * py,  c1 * px + c2 * py * pz,
                    c1 * py + c2 * pz * px, -c1 * px + c2 * pz * py, omc + c2 * pz * pz};
    float sgdt2 = SIG_G2_C * dtv * dtv;
#pragma unroll
    for (int s6 = 0; s6 < 6; s6++) {
      const int i = SI6[s6], j = SJ6[s6];
      float v = X0[3 * i + 0] * Rd[0 + j] + X0[3 * i + 1] * Rd[3 + j] + X0[3 * i + 2] * Rd[6 + j];
      float jj = Jr[3 * i + 0] * Jr[3 * j + 0] + Jr[3 * i + 1] * Jr[3 * j + 1] + Jr[3 * i + 2] * Jr[3 * j + 2];
      s.c00[s6] = v + sgdt2 * jj;
    }
  }

  float Z[9];  mmT(X0, M, Z);  // (D C00) M^T
  float Wm[9]; mmT(Y0, M, Wm); // M C00 M^T (sym)
  float Y1[9], Y2[9];
  {
    float X1[9]; mTm(Rd, s.c01, X1);
    mm(M, s.c01, Y1);
#pragma unroll
    for (int k = 0; k < 9; k++) s.c01[k] = Z[k] + X1[k];
    float X2[9]; mTm(Rd, s.c02, X2);
    mm(M, s.c02, Y2);
    float hdt = 0.5f * dtv;
#pragma unroll
    for (int k = 0; k < 9; k++) s.c02[k] = hdt * Z[k] + dtv * X1[k] + X2[k];
  }

  float C11f[9]; expand6(s.c11, C11f);
  float dt2v = dtv * dtv;
  float hdt = 0.5f * dtv;
  // c22 first (uses old c11, c12, c22)
#pragma unroll
  for (int s6 = 0; s6 < 6; s6++) {
    const int i = SI6[s6], j = SJ6[s6];
    float v = 0.25f * dt2v * Wm[3 * i + j]
            + 0.5f * dt2v * (Y1[3 * i + j] + Y1[3 * j + i])
            + hdt * (Y2[3 * i + j] + Y2[3 * j + i])
            + dt2v * C11f[3 * i + j]
            + dtv * (s.c12[3 * i + j] + s.c12[3 * j + i])
            + s.c22[s6];
    if (i == j) v += SIG_A2_C * 0.25f * dt2v * dt2v;
    s.c22[s6] = v;
  }
  // c12 (elementwise in place, uses old c11 via C11f)
#pragma unroll
  for (int i = 0; i < 3; i++)
#pragma unroll
    for (int j = 0; j < 3; j++) {
      float v = hdt * (Wm[3 * i + j] + Y1[3 * j + i]) + dtv * Y1[3 * i + j]
              + dtv * C11f[3 * i + j] + Y2[3 * i + j] + s.c12[3 * i + j];
      if (i == j) v += SIG_A2_C * hdt * dt2v;
      s.c12[3 * i + j] = v;
    }
  // c11 last
#pragma unroll
  for (int s6 = 0; s6 < 6; s6++) {
    const int i = SI6[s6], j = SJ6[s6];
    float v = Wm[3 * i + j] + Y1[3 * i + j] + Y1[3 * j + i] + s.c11[s6];
    if (i == j) v += SIG_A2_C * dt2v;
    s.c11[s6] = v;
  }

  // commit
#pragma unroll
  for (int i = 0; i < 4; i++) s.q[i] = qn[i];
  s.t += dtv;
}

template <int CNT>
static __device__ __forceinline__ void shsel(const float* v, int d, bool rt, float* X, float* Y) {
#pragma unroll
  for (int i = 0; i < CNT; i++) {
    float o = __shfl_xor(v[i], d, 64);
    X[i] = rt ? o : v[i];
    Y[i] = rt ? v[i] : o;
  }
}

// Compose partner segments across lanes: result = X (earlier) then Y (later).
// Restructured for minimal live-range overlap (anti-spill).
static __device__ __forceinline__ void compose(Seg& s, int d, int lane) {
  bool rt = (lane & d) != 0;

  // ---- rotation + time ----
  float RX[9], RY[9], tY;
  {
    float xq[4], yq[4];
    shsel<4>(s.q, d, rt, xq, yq);
    float ot = __shfl_xor(s.t, d, 64);
    tY = rt ? s.t : ot;
    s.t = s.t + ot;
    q2m(xq, RX); q2m(yq, RY);
    qmul(xq, yq, s.q);
  }

  // ---- u, w (w before u) ----
  {
    float xu[3], yu[3], xw[3], yw[3];
    shsel<3>(s.u, d, rt, xu, yu);
    shsel<3>(s.w, d, rt, xw, yw);
#pragma unroll
    for (int i = 0; i < 3; i++)
      s.w[i] = xw[i] + tY * xu[i] + RX[3 * i + 0] * yw[0] + RX[3 * i + 1] * yw[1] + RX[3 * i + 2] * yw[2];
#pragma unroll
    for (int i = 0; i < 3; i++)
      s.u[i] = xu[i] + RX[3 * i + 0] * yu[0] + RX[3 * i + 1] * yu[1] + RX[3 * i + 2] * yu[2];
  }

  // ---- H before G ----
  {
    float xH[9], yH[9];
    shsel<9>(s.H, d, rt, xH, yH);
    float xG[9], yG[9];
    shsel<9>(s.G, d, rt, xG, yG);
    float A2[9], T[9];
    mm(RX, yH, A2); mmT(A2, RX, T);
#pragma unroll
    for (int k = 0; k < 9; k++) s.H[k] = xH[k] + tY * xG[k] + T[k];
    mm(RX, yG, A2); mmT(A2, RX, T);
#pragma unroll
    for (int k = 0; k < 9; k++) s.G[k] = xG[k] + T[k];
  }

  // ---- P20 before P10; keep M10, M20 for covariance ----
  float M20[9], M10[9];
  {
    float xP20[9], yP20[9], xP10[9], yP10[9];
    shsel<9>(s.P20, d, rt, xP20, yP20);
    shsel<9>(s.P10, d, rt, xP10, yP10);
    float T[9];
    mm(RX, yP20, M20); mmT(M20, RX, T);
#pragma unroll
    for (int k = 0; k < 9; k++) s.P20[k] = xP20[k] + tY * xP10[k] + T[k];
    mm(RX, yP10, M10); mmT(M10, RX, T);
#pragma unroll
    for (int k = 0; k < 9; k++) s.P10[k] = xP10[k] + T[k];
  }

  // ---- covariance: cov' = T covX T^T + Trot covY Trot^T ----
  float B0[9], U1[9], U2[9];
  {
    float x00[6], y00[6];
    shsel<6>(s.c00, d, rt, x00, y00);
    float X00f[9]; expand6(x00, X00f);
    mTm(RY, X00f, B0);
    mm(M10, X00f, U1);
    mm(M20, X00f, U2);
#pragma unroll
    for (int s6 = 0; s6 < 6; s6++) {
      const int i = SI6[s6], j = SJ6[s6];
      s.c00[s6] = B0[3 * i + 0] * RY[0 + j] + B0[3 * i + 1] * RY[3 + j] + B0[3 * i + 2] * RY[6 + j] + y00[s6];
    }
  }

  float V1[9], V2[9], B1[9];
  {
    float x01[9], y01[9];
    shsel<9>(s.c01, d, rt, x01, y01);
    mTm(RY, x01, B1);
    mm(M10, x01, V1);
    mm(M20, x01, V2);
    float T1[9]; mmT(B0, M10, T1);
    float T2[9]; mmT(y01, RX, T2);
#pragma unroll
    for (int k = 0; k < 9; k++) s.c01[k] = T1[k] + B1[k] + T2[k];
  }

  float W1[9], W2[9];
  {
    float x02[9], y02[9];
    shsel<9>(s.c02, d, rt, x02, y02);
    float B2[9]; mTm(RY, x02, B2);
    mm(M10, x02, W1);
    mm(M20, x02, W2);
    float T1[9]; mmT(B0, M20, T1);
    float T2[9]; mmT(y02, RX, T2);
#pragma unroll
    for (int k = 0; k < 9; k++) s.c02[k] = T1[k] + tY * B1[k] + B2[k] + T2[k];
  }
  // B0, B1, RY dead from here on.

  float x11[6], y11[6], x12[9], y12[9];
  shsel<6>(s.c11, d, rt, x11, y11);
  shsel<9>(s.c12, d, rt, x12, y12);
  float X11f[9]; expand6(x11, X11f);

  // c22 (retires U2, M20 afterwards w.r.t. c22 path)
  {
    float x22[6], y22[6];
    shsel<6>(s.c22, d, rt, x22, y22);
    float Ta[9]; mmT(U2, M20, Ta);
    float A5[9];
    {
      float Y22f[9]; expand6(y22, Y22f);
      mm(RX, Y22f, A5);
    }
#pragma unroll
    for (int s6 = 0; s6 < 6; s6++) {
      const int i = SI6[s6], j = SJ6[s6];
      float cj = A5[3 * i + 0] * RX[3 * j + 0] + A5[3 * i + 1] * RX[3 * j + 1] + A5[3 * i + 2] * RX[3 * j + 2];
      s.c22[s6] = Ta[3 * i + j] + tY * (V2[3 * i + j] + V2[3 * j + i])
                + (W2[3 * i + j] + W2[3 * j + i]) + tY * tY * X11f[3 * i + j]
                + tY * (x12[3 * i + j] + x12[3 * j + i]) + x22[s6] + cj;
    }
  }
  // c12
  {
    float Tb[9]; mmT(U1, M20, Tb);
    float C4[9];
    {
      float A4[9]; mm(RX, y12, A4);
      mmT(A4, RX, C4);
    }
#pragma unroll
    for (int i = 0; i < 3; i++)
#pragma unroll
      for (int j = 0; j < 3; j++)
        s.c12[3 * i + j] = Tb[3 * i + j] + tY * V1[3 * i + j] + W1[3 * i + j] + V2[3 * j + i]
                         + tY * X11f[3 * i + j] + x12[3 * i + j] + C4[3 * i + j];
  }
  // c11
  {
    float Tc[9]; mmT(U1, M10, Tc);
    float A3[9];
    {
      float Y11f[9]; expand6(y11, Y11f);
      mm(RX, Y11f, A3);
    }
#pragma unroll
    for (int s6 = 0; s6 < 6; s6++) {
      const int i = SI6[s6], j = SJ6[s6];
      float cj = A3[3 * i + 0] * RX[3 * j + 0] + A3[3 * i + 1] * RX[3 * j + 1] + A3[3 * i + 2] * RX[3 * j + 2];
      s.c11[s6] = Tc[3 * i + j] + V1[3 * i + j] + V1[3 * j + i] + x11[s6] + cj;
    }
  }
}

__global__ __launch_bounds__(64, 1) void imu_kernel(
    const float* __restrict__ dt, const float* __restrict__ ang, const float* __restrict__ acc,
    const float* __restrict__ pos0, const float* __restrict__ vel0, const float* __restrict__ rot0,
    float* __restrict__ out, int B, int N) {
  int lane = threadIdx.x & 63;
  int b = blockIdx.x;
  int chunk = N >> 6; // 16 steps per lane

  Seg s = {};
  s.q[3] = 1.0f;

  long base = (long)b * N + (long)lane * chunk;
  const float* dtp = dt + base;
  const float* angp = ang + base * 3;
  const float* accp = acc + base * 3;

  // phase 1: sequential chunk integration, 4 steps per iteration (float4 loads)
#pragma unroll 1
  for (int jb = 0; jb < (chunk >> 2); ++jb) {
    float4 d4 = *reinterpret_cast<const float4*>(dtp + jb * 4);
    float4 g0 = *reinterpret_cast<const float4*>(angp + jb * 12 + 0);
    float4 g1 = *reinterpret_cast<const float4*>(angp + jb * 12 + 4);
    float4 g2 = *reinterpret_cast<const float4*>(angp + jb * 12 + 8);
    float4 a0 = *reinterpret_cast<const float4*>(accp + jb * 12 + 0);
    float4 a1 = *reinterpret_cast<const float4*>(accp + jb * 12 + 4);
    float4 a2 = *reinterpret_cast<const float4*>(accp + jb * 12 + 8);
    step(s, d4.x, g0.x, g0.y, g0.z, a0.x, a0.y, a0.z);
    step(s, d4.y, g0.w, g1.x, g1.y, a0.w, a1.x, a1.y);
    step(s, d4.z, g1.z, g1.w, g2.x, a1.z, a1.w, a2.x);
    step(s, d4.w, g2.y, g2.z, g2.w, a2.y, a2.z, a2.w);
  }

  // phase 2: non-commutative butterfly reduction over 64 chunks
#pragma unroll 1
  for (int d = 1; d < 64; d <<= 1) compose(s, d, lane);

  if (lane == 0) {
    float r0q[4] = {rot0[b * 4 + 0], rot0[b * 4 + 1], rot0[b * 4 + 2], rot0[b * 4 + 3]};
    float p0[3] = {pos0[b * 3 + 0], pos0[b * 3 + 1], pos0[b * 3 + 2]};
    float v0[3] = {vel0[b * 3 + 0], vel0[b * 3 + 1], vel0[b * 3 + 2]};
    float R0[9]; q2m(r0q, R0);
    float gp[3]; // R0^T * (0,0,g)
#pragma unroll
    for (int i = 0; i < 3; i++) gp[i] = R0[6 + i] * GRAVITY_C;
    float dv[3], dp[3];
#pragma unroll
    for (int i = 0; i < 3; i++) {
      dv[i] = s.u[i] - (s.G[3 * i + 0] * gp[0] + s.G[3 * i + 1] * gp[1] + s.G[3 * i + 2] * gp[2]);
      dp[i] = s.w[i] - (s.H[3 * i + 0] * gp[0] + s.H[3 * i + 1] * gp[1] + s.H[3 * i + 2] * gp[2]);
    }
    float qo[4]; qmul(r0q, s.q, qo);
#pragma unroll
    for (int i = 0; i < 4; i++) out[b * 4 + i] = qo[i];
#pragma unroll
    for (int i = 0; i < 3; i++) {
      float vv = v0[i] + R0[3 * i + 0] * dv[0] + R0[3 * i + 1] * dv[1] + R0[3 * i + 2] * dv[2];
      float pv = p0[i] + v0[i] * s.t + R0[3 * i + 0] * dp[0] + R0[3 * i + 1] * dp[1] + R0[3 * i + 2] * dp[2];
      out[4 * B + b * 3 + i] = vv;
      out[7 * B + b * 3 + i] = pv;
    }
    long cb = 10L * B + (long)b * 81;
    float C00f[9], C11f[9], C22f[9];
    expand6(s.c00, C00f); expand6(s.c11, C11f); expand6(s.c22, C22f);
#pragma unroll
    for (int i = 0; i < 3; i++)
#pragma unroll
      for (int j = 0; j < 3; j++) {
        out[cb + i * 9 + j]           = C00f[3 * i + j];
        out[cb + i * 9 + (j + 3)]     = s.c01[3 * i + j];
        out[cb + i * 9 + (j + 6)]     = s.c02[3 * i + j];
        out[cb + (i + 3) * 9 + j]     = s.c01[3 * j + i];
        out[cb + (i + 3) * 9 + j + 3] = C11f[3 * i + j];
        out[cb + (i + 3) * 9 + j + 6] = s.c12[3 * i + j];
        out[cb + (i + 6) * 9 + j]     = s.c02[3 * j + i];
        out[cb + (i + 6) * 9 + j + 3] = s.c12[3 * j + i];
        out[cb + (i + 6) * 9 + j + 6] = C22f[3 * i + j];
      }
  }
}

extern "C" void kernel_launch(void* const* d_in, const int* in_sizes, int n_in,
                              void* d_out, int out_size, void* d_ws, size_t ws_size,
                              hipStream_t stream) {
  const float* dt   = (const float*)d_in[0];
  const float* ang  = (const float*)d_in[1];
  const float* acc  = (const float*)d_in[2];
  const float* pos0 = (const float*)d_in[3];
  const float* vel0 = (const float*)d_in[4];
  const float* rot0 = (const float*)d_in[5];
  int B = in_sizes[5] / 4;
  int N = in_sizes[0] / B;
  float* out = (float*)d_out;
  dim3 grid(B), block(64);
  imu_kernel<<<grid, block, 0, stream>>>(dt, ang, acc, pos0, vel0, rot0, out, B, N);
}

// Round 3
// 128.279 us; speedup vs baseline: 7.5748x; 2.4835x over previous
//
#include <hip/hip_runtime.h>
#include <math.h>

#define GRAVITY_C 9.81007f
#define SIG_G2_C (1.6968e-4f * 1.6968e-4f)
#define SIG_A2_C (2.0e-3f * 2.0e-3f)

// Segment summary: composable preintegration state (74 floats).
// Gravity is folded per-lane via prefix rotation, so dp/dv are TRUE deltas
// in the segment-start frame (no G/H affine blocks needed).
struct Seg {
  float q[4];            // segment delta-rotation quat (xyzw)
  float t;               // accumulated time
  float dv[3], dp[3];    // true velocity/position deltas (gravity included)
  float P10[9], P20[9];  // Phi(1,0), Phi(2,0) blocks of 9x9 transition
  float c00[6], c01[9], c02[9], c11[6], c12[9], c22[6]; // sym cov blocks
};

static __device__ __forceinline__ void q2m(const float q[4], float R[9]) {
  float x = q[0], y = q[1], z = q[2], w = q[3];
  R[0] = 1.f - 2.f * (y * y + z * z); R[1] = 2.f * (x * y - z * w);       R[2] = 2.f * (x * z + y * w);
  R[3] = 2.f * (x * y + z * w);       R[4] = 1.f - 2.f * (x * x + z * z); R[5] = 2.f * (y * z - x * w);
  R[6] = 2.f * (x * z - y * w);       R[7] = 2.f * (y * z + x * w);       R[8] = 1.f - 2.f * (x * x + y * y);
}

static __device__ __forceinline__ void qmul(const float a[4], const float b[4], float o[4]) {
  float x1 = a[0], y1 = a[1], z1 = a[2], w1 = a[3];
  float x2 = b[0], y2 = b[1], z2 = b[2], w2 = b[3];
  o[0] = w1 * x2 + x1 * w2 + y1 * z2 - z1 * y2;
  o[1] = w1 * y2 - x1 * z2 + y1 * w2 + z1 * x2;
  o[2] = w1 * z2 + x1 * y2 - y1 * x2 + z1 * w2;
  o[3] = w1 * w2 - x1 * x2 - y1 * y2 - z1 * z2;
}

// C = A @ B
static __device__ __forceinline__ void mm(const float A[9], const float B[9], float C[9]) {
#pragma unroll
  for (int i = 0; i < 3; i++)
#pragma unroll
    for (int j = 0; j < 3; j++)
      C[3 * i + j] = A[3 * i + 0] * B[0 + j] + A[3 * i + 1] * B[3 + j] + A[3 * i + 2] * B[6 + j];
}
// C = A @ B^T
static __device__ __forceinline__ void mmT(const float A[9], const float B[9], float C[9]) {
#pragma unroll
  for (int i = 0; i < 3; i++)
#pragma unroll
    for (int j = 0; j < 3; j++)
      C[3 * i + j] = A[3 * i + 0] * B[3 * j + 0] + A[3 * i + 1] * B[3 * j + 1] + A[3 * i + 2] * B[3 * j + 2];
}
// C = A^T @ B
static __device__ __forceinline__ void mTm(const float A[9], const float B[9], float C[9]) {
#pragma unroll
  for (int i = 0; i < 3; i++)
#pragma unroll
    for (int j = 0; j < 3; j++)
      C[3 * i + j] = A[0 + i] * B[0 + j] + A[3 + i] * B[3 + j] + A[6 + i] * B[6 + j];
}

static __device__ __forceinline__ void expand6(const float c[6], float f[9]) {
  f[0] = c[0]; f[1] = c[1]; f[2] = c[2];
  f[3] = c[1]; f[4] = c[3]; f[5] = c[4];
  f[6] = c[2]; f[7] = c[4]; f[8] = c[5];
}

// sym index tables: entries (0,0),(0,1),(0,2),(1,1),(1,2),(2,2)
__device__ __constant__ const int SI6[6] = {0, 0, 0, 1, 1, 2};
__device__ __constant__ const int SJ6[6] = {0, 1, 2, 1, 2, 2};

// One IMU step folded into the segment summary. g_l = constant gravity in the
// segment-start frame (known from the rotation prefix pre-pass).
static __device__ __forceinline__ void step(Seg& s, float dtv,
                                            float omx, float omy, float omz,
                                            float acx, float acy, float acz,
                                            const float g_l[3]) {
  // ---- dr = Exp(ang*dt) ----
  float px = omx * dtv, py = omy * dtv, pz = omz * dtv;
  float t2 = px * px + py * py + pz * pz;
  bool sm = t2 < 1e-8f;
  float t2s = sm ? 1.0f : t2;
  float t = sqrtf(t2s);
  float rt_ = 1.0f / t;
  float ht = 0.5f * t, ht2 = ht * ht;
  // f32-exact polynomials for |t| <= ~0.05 rad (data range)
  float sh = ht * (1.0f - ht2 * (1.0f / 6.0f) * (1.0f - 0.05f * ht2));
  float ch = 1.0f - 0.5f * ht2 * (1.0f - (1.0f / 12.0f) * ht2);
  float s_ = sm ? (0.5f - t2 * (1.0f / 48.0f)) : sh * rt_;
  float qd[4] = {px * s_, py * s_, pz * s_, sm ? (1.0f - 0.125f * t2) : ch};
  float rt2 = rt_ * rt_;
  float sint = 2.0f * sh * ch;
  float c1 = sm ? (0.5f - t2 * (1.0f / 24.0f)) : (2.0f * sh * sh * rt2);
  float c2 = sm ? (1.0f / 6.0f - t2 * (1.0f / 120.0f)) : ((t - sint) * rt2 * rt_);

  float Ro[9]; q2m(s.q, Ro);
  float Rd[9]; q2m(qd, Rd);

  // ---- Ra = Ro*acc - Ro Rd^T Ro^T g_l  (true accel in segment-start frame) ----
  float Ra[3];
  {
    float t1[3], t2v[3];
#pragma unroll
    for (int i = 0; i < 3; i++)  // t1 = Ro^T g_l
      t1[i] = Ro[0 + i] * g_l[0] + Ro[3 + i] * g_l[1] + Ro[6 + i] * g_l[2];
#pragma unroll
    for (int i = 0; i < 3; i++)  // t2v = Rd^T t1
      t2v[i] = Rd[0 + i] * t1[0] + Rd[3 + i] * t1[1] + Rd[6 + i] * t1[2];
#pragma unroll
    for (int i = 0; i < 3; i++)  // Ra = Ro*acc - Ro*t2v
      Ra[i] = Ro[3 * i + 0] * (acx - t2v[0]) + Ro[3 * i + 1] * (acy - t2v[1]) + Ro[3 * i + 2] * (acz - t2v[2]);
  }

  // ---- integrate dp (uses old dv) then dv ----
  float hdt2 = 0.5f * dtv * dtv;
#pragma unroll
  for (int i = 0; i < 3; i++) s.dp[i] += s.dv[i] * dtv + Ra[i] * hdt2;
#pragma unroll
  for (int i = 0; i < 3; i++) s.dv[i] += Ra[i] * dtv;

  // ---- rotation update ----
  float qn[4]; qmul(s.q, qd, qn);
  float Rn[9]; q2m(qn, Rn);

  // ---- M = -dt * (Rn @ skew(acc)) ----
  float M[9];
#pragma unroll
  for (int i = 0; i < 3; i++) {
    M[3 * i + 0] = -dtv * (Rn[3 * i + 1] * acz - Rn[3 * i + 2] * acy);
    M[3 * i + 1] = -dtv * (-Rn[3 * i + 0] * acz + Rn[3 * i + 2] * acx);
    M[3 * i + 2] = -dtv * (Rn[3 * i + 0] * acy - Rn[3 * i + 1] * acx);
  }

  // ---- Phi blocks: P20 before P10 ----
  {
    float TP[9]; mmT(M, Ro, TP); // M @ Ro^T
#pragma unroll
    for (int k = 0; k < 9; k++) s.P20[k] += 0.5f * dtv * TP[k] + dtv * s.P10[k];
#pragma unroll
    for (int k = 0; k < 9; k++) s.P10[k] += TP[k];
  }

  // ---- covariance: cov' = A cov A^T + Q (block-structured) ----
  float X0[9], Y0[9];
  {
    float C00f[9]; expand6(s.c00, C00f);
    mTm(Rd, C00f, X0); // D @ C00
    mm(M, C00f, Y0);   // M @ C00
  }

  // Jr = (1 - c2 t2) I - c1 K + c2 p p^T ; noise c00 += SIG_G2 dt^2 Jr Jr^T
  {
    float omc = 1.0f - c2 * t2;
    float Jr[9] = {omc + c2 * px * px,  c1 * pz + c2 * px * py, -c1 * py + c2 * px * pz,
                   -c1 * pz + c2 * py * px, omc + c2 * py * py,  c1 * px + c2 * py * pz,
                    c1 * py + c2 * pz * px, -c1 * px + c2 * pz * py, omc + c2 * pz * pz};
    float sgdt2 = SIG_G2_C * dtv * dtv;
#pragma unroll
    for (int s6 = 0; s6 < 6; s6++) {
      const int i = SI6[s6], j = SJ6[s6];
      float v = X0[3 * i + 0] * Rd[0 + j] + X0[3 * i + 1] * Rd[3 + j] + X0[3 * i + 2] * Rd[6 + j];
      float jj = Jr[3 * i + 0] * Jr[3 * j + 0] + Jr[3 * i + 1] * Jr[3 * j + 1] + Jr[3 * i + 2] * Jr[3 * j + 2];
      s.c00[s6] = v + sgdt2 * jj;
    }
  }

  float Z[9];  mmT(X0, M, Z);  // (D C00) M^T
  float Wm[9]; mmT(Y0, M, Wm); // M C00 M^T (sym)
  float Y1[9], Y2[9];
  {
    float X1[9]; mTm(Rd, s.c01, X1);
    mm(M, s.c01, Y1);
#pragma unroll
    for (int k = 0; k < 9; k++) s.c01[k] = Z[k] + X1[k];
    float X2[9]; mTm(Rd, s.c02, X2);
    mm(M, s.c02, Y2);
    float hdt = 0.5f * dtv;
#pragma unroll
    for (int k = 0; k < 9; k++) s.c02[k] = hdt * Z[k] + dtv * X1[k] + X2[k];
  }

  float C11f[9]; expand6(s.c11, C11f);
  float dt2v = dtv * dtv;
  float hdt = 0.5f * dtv;
  // c22 first (uses old c11, c12, c22)
#pragma unroll
  for (int s6 = 0; s6 < 6; s6++) {
    const int i = SI6[s6], j = SJ6[s6];
    float v = 0.25f * dt2v * Wm[3 * i + j]
            + 0.5f * dt2v * (Y1[3 * i + j] + Y1[3 * j + i])
            + hdt * (Y2[3 * i + j] + Y2[3 * j + i])
            + dt2v * C11f[3 * i + j]
            + dtv * (s.c12[3 * i + j] + s.c12[3 * j + i])
            + s.c22[s6];
    if (i == j) v += SIG_A2_C * 0.25f * dt2v * dt2v;
    s.c22[s6] = v;
  }
  // c12 (elementwise in place, uses old c11 via C11f)
#pragma unroll
  for (int i = 0; i < 3; i++)
#pragma unroll
    for (int j = 0; j < 3; j++) {
      float v = hdt * (Wm[3 * i + j] + Y1[3 * j + i]) + dtv * Y1[3 * i + j]
              + dtv * C11f[3 * i + j] + Y2[3 * i + j] + s.c12[3 * i + j];
      if (i == j) v += SIG_A2_C * hdt * dt2v;
      s.c12[3 * i + j] = v;
    }
  // c11 last
#pragma unroll
  for (int s6 = 0; s6 < 6; s6++) {
    const int i = SI6[s6], j = SJ6[s6];
    float v = Wm[3 * i + j] + Y1[3 * i + j] + Y1[3 * j + i] + s.c11[s6];
    if (i == j) v += SIG_A2_C * dt2v;
    s.c11[s6] = v;
  }

  // commit
#pragma unroll
  for (int i = 0; i < 4; i++) s.q[i] = qn[i];
  s.t += dtv;
}

template <int CNT>
static __device__ __forceinline__ void shsel(const float* v, int d, bool rt, float* X, float* Y) {
#pragma unroll
  for (int i = 0; i < CNT; i++) {
    float o = __shfl_xor(v[i], d, 64);
    X[i] = rt ? o : v[i];
    Y[i] = rt ? v[i] : o;
  }
}

// Compose partner segments across lanes: result = X (earlier) then Y (later).
static __device__ __forceinline__ void compose(Seg& s, int d, int lane) {
  bool rt = (lane & d) != 0;

  // ---- rotation + time ----
  float RX[9], RY[9], tY;
  {
    float xq[4], yq[4];
    shsel<4>(s.q, d, rt, xq, yq);
    float ot = __shfl_xor(s.t, d, 64);
    tY = rt ? s.t : ot;
    s.t = s.t + ot;
    q2m(xq, RX); q2m(yq, RY);
    qmul(xq, yq, s.q);
  }

  // ---- dv, dp (dp before dv) ----
  {
    float xu[3], yu[3], xw[3], yw[3];
    shsel<3>(s.dv, d, rt, xu, yu);
    shsel<3>(s.dp, d, rt, xw, yw);
#pragma unroll
    for (int i = 0; i < 3; i++)
      s.dp[i] = xw[i] + tY * xu[i] + RX[3 * i + 0] * yw[0] + RX[3 * i + 1] * yw[1] + RX[3 * i + 2] * yw[2];
#pragma unroll
    for (int i = 0; i < 3; i++)
      s.dv[i] = xu[i] + RX[3 * i + 0] * yu[0] + RX[3 * i + 1] * yu[1] + RX[3 * i + 2] * yu[2];
  }

  // ---- P20 before P10; keep M10, M20 for covariance ----
  float M20[9], M10[9];
  {
    float xP20[9], yP20[9], xP10[9], yP10[9];
    shsel<9>(s.P20, d, rt, xP20, yP20);
    shsel<9>(s.P10, d, rt, xP10, yP10);
    float T[9];
    mm(RX, yP20, M20); mmT(M20, RX, T);
#pragma unroll
    for (int k = 0; k < 9; k++) s.P20[k] = xP20[k] + tY * xP10[k] + T[k];
    mm(RX, yP10, M10); mmT(M10, RX, T);
#pragma unroll
    for (int k = 0; k < 9; k++) s.P10[k] = xP10[k] + T[k];
  }

  // ---- covariance: cov' = F covX F^T + T covY T^T ----
  float B0[9], U1[9], U2[9];
  {
    float x00[6], y00[6];
    shsel<6>(s.c00, d, rt, x00, y00);
    float X00f[9]; expand6(x00, X00f);
    mTm(RY, X00f, B0);
    mm(M10, X00f, U1);
    mm(M20, X00f, U2);
#pragma unroll
    for (int s6 = 0; s6 < 6; s6++) {
      const int i = SI6[s6], j = SJ6[s6];
      s.c00[s6] = B0[3 * i + 0] * RY[0 + j] + B0[3 * i + 1] * RY[3 + j] + B0[3 * i + 2] * RY[6 + j] + y00[s6];
    }
  }

  float V1[9], V2[9], B1[9];
  {
    float x01[9], y01[9];
    shsel<9>(s.c01, d, rt, x01, y01);
    mTm(RY, x01, B1);
    mm(M10, x01, V1);
    mm(M20, x01, V2);
    float T1[9]; mmT(B0, M10, T1);
    float T2[9]; mmT(y01, RX, T2);
#pragma unroll
    for (int k = 0; k < 9; k++) s.c01[k] = T1[k] + B1[k] + T2[k];
  }

  float W1[9], W2[9];
  {
    float x02[9], y02[9];
    shsel<9>(s.c02, d, rt, x02, y02);
    float B2[9]; mTm(RY, x02, B2);
    mm(M10, x02, W1);
    mm(M20, x02, W2);
    float T1[9]; mmT(B0, M20, T1);
    float T2[9]; mmT(y02, RX, T2);
#pragma unroll
    for (int k = 0; k < 9; k++) s.c02[k] = T1[k] + tY * B1[k] + B2[k] + T2[k];
  }
  // B0, B1, RY dead from here on.

  float x11[6], y11[6], x12[9], y12[9];
  shsel<6>(s.c11, d, rt, x11, y11);
  shsel<9>(s.c12, d, rt, x12, y12);
  float X11f[9]; expand6(x11, X11f);

  // c22
  {
    float x22[6], y22[6];
    shsel<6>(s.c22, d, rt, x22, y22);
    float Ta[9]; mmT(U2, M20, Ta);
    float A5[9];
    {
      float Y22f[9]; expand6(y22, Y22f);
      mm(RX, Y22f, A5);
    }
#pragma unroll
    for (int s6 = 0; s6 < 6; s6++) {
      const int i = SI6[s6], j = SJ6[s6];
      float cj = A5[3 * i + 0] * RX[3 * j + 0] + A5[3 * i + 1] * RX[3 * j + 1] + A5[3 * i + 2] * RX[3 * j + 2];
      s.c22[s6] = Ta[3 * i + j] + tY * (V2[3 * i + j] + V2[3 * j + i])
                + (W2[3 * i + j] + W2[3 * j + i]) + tY * tY * X11f[3 * i + j]
                + tY * (x12[3 * i + j] + x12[3 * j + i]) + x22[s6] + cj;
    }
  }
  // c12
  {
    float Tb[9]; mmT(U1, M20, Tb);
    float C4[9];
    {
      float A4[9]; mm(RX, y12, A4);
      mmT(A4, RX, C4);
    }
#pragma unroll
    for (int i = 0; i < 3; i++)
#pragma unroll
      for (int j = 0; j < 3; j++)
        s.c12[3 * i + j] = Tb[3 * i + j] + tY * V1[3 * i + j] + W1[3 * i + j] + V2[3 * j + i]
                         + tY * X11f[3 * i + j] + x12[3 * i + j] + C4[3 * i + j];
  }
  // c11
  {
    float Tc[9]; mmT(U1, M10, Tc);
    float A3[9];
    {
      float Y11f[9]; expand6(y11, Y11f);
      mm(RX, Y11f, A3);
    }
#pragma unroll
    for (int s6 = 0; s6 < 6; s6++) {
      const int i = SI6[s6], j = SJ6[s6];
      float cj = A3[3 * i + 0] * RX[3 * j + 0] + A3[3 * i + 1] * RX[3 * j + 1] + A3[3 * i + 2] * RX[3 * j + 2];
      s.c11[s6] = Tc[3 * i + j] + V1[3 * i + j] + V1[3 * j + i] + x11[s6] + cj;
    }
  }
}

__global__ __launch_bounds__(64, 1) void imu_kernel(
    const float* __restrict__ dt, const float* __restrict__ ang, const float* __restrict__ acc,
    const float* __restrict__ pos0, const float* __restrict__ vel0, const float* __restrict__ rot0,
    float* __restrict__ out, int B, int N) {
  int lane = threadIdx.x & 63;
  int b = blockIdx.x;
  int chunk = N >> 6; // 16 steps per lane

  long base = (long)b * N + (long)lane * chunk;
  const float* dtp = dt + base;
  const float* angp = ang + base * 3;
  const float* accp = acc + base * 3;

  // ---- pre-pass: chunk rotation product (cheap, warms cache) ----
  float qc[4] = {0.f, 0.f, 0.f, 1.f};
#pragma unroll 1
  for (int j = 0; j < chunk; ++j) {
    float dtv = dtp[j];
    float px = angp[3 * j + 0] * dtv, py = angp[3 * j + 1] * dtv, pz = angp[3 * j + 2] * dtv;
    float t2 = px * px + py * py + pz * pz;
    bool sm = t2 < 1e-8f;
    float t2s = sm ? 1.0f : t2;
    float t = sqrtf(t2s);
    float rt_ = 1.0f / t;
    float ht = 0.5f * t, ht2 = ht * ht;
    float sh = ht * (1.0f - ht2 * (1.0f / 6.0f) * (1.0f - 0.05f * ht2));
    float ch = 1.0f - 0.5f * ht2 * (1.0f - (1.0f / 12.0f) * ht2);
    float s_ = sm ? (0.5f - t2 * (1.0f / 48.0f)) : sh * rt_;
    float qd[4] = {px * s_, py * s_, pz * s_, sm ? (1.0f - 0.125f * t2) : ch};
    float qn[4]; qmul(qc, qd, qn);
    qc[0] = qn[0]; qc[1] = qn[1]; qc[2] = qn[2]; qc[3] = qn[3];
  }
  // inclusive shuffle-up scan (non-commutative: earlier on the left)
#pragma unroll
  for (int d = 1; d < 64; d <<= 1) {
    float o0 = __shfl_up(qc[0], d, 64);
    float o1 = __shfl_up(qc[1], d, 64);
    float o2 = __shfl_up(qc[2], d, 64);
    float o3 = __shfl_up(qc[3], d, 64);
    if (lane >= d) {
      float oq[4] = {o0, o1, o2, o3};
      float nn[4]; qmul(oq, qc, nn);
      qc[0] = nn[0]; qc[1] = nn[1]; qc[2] = nn[2]; qc[3] = nn[3];
    }
  }
  // exclusive prefix Q (rotation from sequence start to this lane's chunk start)
  float Q[4];
  Q[0] = __shfl_up(qc[0], 1, 64);
  Q[1] = __shfl_up(qc[1], 1, 64);
  Q[2] = __shfl_up(qc[2], 1, 64);
  Q[3] = __shfl_up(qc[3], 1, 64);
  if (lane == 0) { Q[0] = 0.f; Q[1] = 0.f; Q[2] = 0.f; Q[3] = 1.f; }

  // per-lane constant gravity in chunk-start frame: g_l = R(Q)^T R0^T g
  float r0q[4] = {rot0[b * 4 + 0], rot0[b * 4 + 1], rot0[b * 4 + 2], rot0[b * 4 + 3]};
  float g_l[3];
  {
    float R0[9]; q2m(r0q, R0);
    float gp[3] = {R0[6] * GRAVITY_C, R0[7] * GRAVITY_C, R0[8] * GRAVITY_C}; // R0^T g
    float RQ[9]; q2m(Q, RQ);
#pragma unroll
    for (int i = 0; i < 3; i++)
      g_l[i] = RQ[0 + i] * gp[0] + RQ[3 + i] * gp[1] + RQ[6 + i] * gp[2];
  }

  Seg s = {};
  s.q[3] = 1.0f;

  // ---- phase 1: sequential chunk integration (one step/iter, low pressure) ----
#pragma unroll 1
  for (int j = 0; j < chunk; ++j) {
    float dtv = dtp[j];
    float gx = angp[3 * j + 0], gy = angp[3 * j + 1], gz = angp[3 * j + 2];
    float ax = accp[3 * j + 0], ay = accp[3 * j + 1], az = accp[3 * j + 2];
    step(s, dtv, gx, gy, gz, ax, ay, az, g_l);
  }

  // ---- phase 2: non-commutative butterfly reduction over 64 chunks ----
#pragma unroll 1
  for (int d = 1; d < 64; d <<= 1) compose(s, d, lane);

  if (lane == 0) {
    float p0[3] = {pos0[b * 3 + 0], pos0[b * 3 + 1], pos0[b * 3 + 2]};
    float v0[3] = {vel0[b * 3 + 0], vel0[b * 3 + 1], vel0[b * 3 + 2]};
    float R0[9]; q2m(r0q, R0);
    float qo[4]; qmul(r0q, s.q, qo);
#pragma unroll
    for (int i = 0; i < 4; i++) out[b * 4 + i] = qo[i];
#pragma unroll
    for (int i = 0; i < 3; i++) {
      float vv = v0[i] + R0[3 * i + 0] * s.dv[0] + R0[3 * i + 1] * s.dv[1] + R0[3 * i + 2] * s.dv[2];
      float pv = p0[i] + v0[i] * s.t + R0[3 * i + 0] * s.dp[0] + R0[3 * i + 1] * s.dp[1] + R0[3 * i + 2] * s.dp[2];
      out[4 * B + b * 3 + i] = vv;
      out[7 * B + b * 3 + i] = pv;
    }
    long cb = 10L * B + (long)b * 81;
    float C00f[9], C11f[9], C22f[9];
    expand6(s.c00, C00f); expand6(s.c11, C11f); expand6(s.c22, C22f);
#pragma unroll
    for (int i = 0; i < 3; i++)
#pragma unroll
      for (int j = 0; j < 3; j++) {
        out[cb + i * 9 + j]           = C00f[3 * i + j];
        out[cb + i * 9 + (j + 3)]     = s.c01[3 * i + j];
        out[cb + i * 9 + (j + 6)]     = s.c02[3 * i + j];
        out[cb + (i + 3) * 9 + j]     = s.c01[3 * j + i];
        out[cb + (i + 3) * 9 + j + 3] = C11f[3 * i + j];
        out[cb + (i + 3) * 9 + j + 6] = s.c12[3 * i + j];
        out[cb + (i + 6) * 9 + j]     = s.c02[3 * j + i];
        out[cb + (i + 6) * 9 + j + 3] = s.c12[3 * j + i];
        out[cb + (i + 6) * 9 + j + 6] = C22f[3 * i + j];
      }
  }
}

extern "C" void kernel_launch(void* const* d_in, const int* in_sizes, int n_in,
                              void* d_out, int out_size, void* d_ws, size_t ws_size,
                              hipStream_t stream) {
  const float* dt   = (const float*)d_in[0];
  const float* ang  = (const float*)d_in[1];
  const float* acc  = (const float*)d_in[2];
  const float* pos0 = (const float*)d_in[3];
  const float* vel0 = (const float*)d_in[4];
  const float* rot0 = (const float*)d_in[5];
  int B = in_sizes[5] / 4;
  int N = in_sizes[0] / B;
  float* out = (float*)d_out;
  dim3 grid(B), block(64);
  imu_kernel<<<grid, block, 0, stream>>>(dt, ang, acc, pos0, vel0, rot0, out, B, N);
}

// Round 4
// 100.490 us; speedup vs baseline: 9.6695x; 1.2765x over previous
//
#include <hip/hip_runtime.h>
#include <math.h>

#define GRAVITY_C 9.81007f
#define SIG_G2_C (1.6968e-4f * 1.6968e-4f)
#define SIG_A2_C (2.0e-3f * 2.0e-3f)

// Segment summary: composable preintegration state (74 floats).
// Gravity folded per-lane via prefix rotation => dp/dv are TRUE deltas
// in the segment-start frame.
struct Seg {
  float q[4];            // segment delta-rotation quat (xyzw)
  float t;               // accumulated time
  float dv[3], dp[3];    // true velocity/position deltas (gravity included)
  float P10[9], P20[9];  // Phi(1,0), Phi(2,0) blocks of 9x9 transition
  float c00[6], c01[9], c02[9], c11[6], c12[9], c22[6]; // sym cov blocks
};

static __device__ __forceinline__ void q2m(const float q[4], float R[9]) {
  float x = q[0], y = q[1], z = q[2], w = q[3];
  R[0] = 1.f - 2.f * (y * y + z * z); R[1] = 2.f * (x * y - z * w);       R[2] = 2.f * (x * z + y * w);
  R[3] = 2.f * (x * y + z * w);       R[4] = 1.f - 2.f * (x * x + z * z); R[5] = 2.f * (y * z - x * w);
  R[6] = 2.f * (x * z - y * w);       R[7] = 2.f * (y * z + x * w);       R[8] = 1.f - 2.f * (x * x + y * y);
}

static __device__ __forceinline__ void qmul(const float a[4], const float b[4], float o[4]) {
  float x1 = a[0], y1 = a[1], z1 = a[2], w1 = a[3];
  float x2 = b[0], y2 = b[1], z2 = b[2], w2 = b[3];
  o[0] = w1 * x2 + x1 * w2 + y1 * z2 - z1 * y2;
  o[1] = w1 * y2 - x1 * z2 + y1 * w2 + z1 * x2;
  o[2] = w1 * z2 + x1 * y2 - y1 * x2 + z1 * w2;
  o[3] = w1 * w2 - x1 * x2 - y1 * y2 - z1 * z2;
}

// C = A @ B
static __device__ __forceinline__ void mm(const float A[9], const float B[9], float C[9]) {
#pragma unroll
  for (int i = 0; i < 3; i++)
#pragma unroll
    for (int j = 0; j < 3; j++)
      C[3 * i + j] = A[3 * i + 0] * B[0 + j] + A[3 * i + 1] * B[3 + j] + A[3 * i + 2] * B[6 + j];
}
// C = A @ B^T
static __device__ __forceinline__ void mmT(const float A[9], const float B[9], float C[9]) {
#pragma unroll
  for (int i = 0; i < 3; i++)
#pragma unroll
    for (int j = 0; j < 3; j++)
      C[3 * i + j] = A[3 * i + 0] * B[3 * j + 0] + A[3 * i + 1] * B[3 * j + 1] + A[3 * i + 2] * B[3 * j + 2];
}
// C = A^T @ B
static __device__ __forceinline__ void mTm(const float A[9], const float B[9], float C[9]) {
#pragma unroll
  for (int i = 0; i < 3; i++)
#pragma unroll
    for (int j = 0; j < 3; j++)
      C[3 * i + j] = A[0 + i] * B[0 + j] + A[3 + i] * B[3 + j] + A[6 + i] * B[6 + j];
}

static __device__ __forceinline__ void expand6(const float c[6], float f[9]) {
  f[0] = c[0]; f[1] = c[1]; f[2] = c[2];
  f[3] = c[1]; f[4] = c[3]; f[5] = c[4];
  f[6] = c[2]; f[7] = c[4]; f[8] = c[5];
}

// sym index tables: entries (0,0),(0,1),(0,2),(1,1),(1,2),(2,2)
__device__ __constant__ const int SI6[6] = {0, 0, 0, 1, 1, 2};
__device__ __constant__ const int SJ6[6] = {0, 1, 2, 1, 2, 2};

// One IMU step. Ro = R(s.q) carried; gb = R_total^T g_l carried (body gravity).
// Taylor forms valid for |phi| <~ 0.05 rad (data: <= ~0.02), err ~1e-10.
static __device__ __forceinline__ void step(Seg& s, float Ro[9], float gb[3], float dtv,
                                            float omx, float omy, float omz,
                                            float acx, float acy, float acz) {
  float px = omx * dtv, py = omy * dtv, pz = omz * dtv;
  float t2 = px * px + py * py + pz * pz;
  float s_ = 0.5f - t2 * (1.0f / 48.0f);
  float qd[4] = {px * s_, py * s_, pz * s_, 1.0f - 0.125f * t2};
  float c1 = 0.5f - t2 * (1.0f / 24.0f);
  float c2 = (1.0f / 6.0f) - t2 * (1.0f / 120.0f);

  float Rd[9]; q2m(qd, Rd);
  float qn[4]; qmul(s.q, qd, qn);
  float Rn[9]; q2m(qn, Rn);

  // gb' = Rd^T gb  (gravity in new body frame)
  float gbn[3];
#pragma unroll
  for (int i = 0; i < 3; i++)
    gbn[i] = Rd[0 + i] * gb[0] + Rd[3 + i] * gb[1] + Rd[6 + i] * gb[2];
  // Ra = Ro * (acc - gb')
  float bx = acx - gbn[0], by = acy - gbn[1], bz = acz - gbn[2];
  float Ra[3];
#pragma unroll
  for (int i = 0; i < 3; i++)
    Ra[i] = Ro[3 * i + 0] * bx + Ro[3 * i + 1] * by + Ro[3 * i + 2] * bz;

  // dp (old dv) then dv
  float hdt = 0.5f * dtv;
  float hdt2 = hdt * dtv;
#pragma unroll
  for (int i = 0; i < 3; i++) s.dp[i] += s.dv[i] * dtv + Ra[i] * hdt2;
#pragma unroll
  for (int i = 0; i < 3; i++) s.dv[i] += Ra[i] * dtv;

  // M = -dt * (Rn @ skew(acc))
  float M[9];
#pragma unroll
  for (int i = 0; i < 3; i++) {
    M[3 * i + 0] = -dtv * (Rn[3 * i + 1] * acz - Rn[3 * i + 2] * acy);
    M[3 * i + 1] = -dtv * (-Rn[3 * i + 0] * acz + Rn[3 * i + 2] * acx);
    M[3 * i + 2] = -dtv * (Rn[3 * i + 0] * acy - Rn[3 * i + 1] * acx);
  }

  // Phi blocks: P20 before P10
  {
    float TP[9]; mmT(M, Ro, TP); // M @ Ro^T  (Ro = OLD rotation)
#pragma unroll
    for (int k = 0; k < 9; k++) s.P20[k] += hdt * TP[k] + dtv * s.P10[k];
#pragma unroll
    for (int k = 0; k < 9; k++) s.P10[k] += TP[k];
  }

  // ---- covariance ----
  float X0[9], Y0[9];
  {
    float C00f[9]; expand6(s.c00, C00f);
    mTm(Rd, C00f, X0); // Rd^T C00
    mm(M, C00f, Y0);   // M C00
  }

  // c00' = X0 Rd + SIG_G2 dt^2 Jr Jr^T
  {
    float omc = 1.0f - c2 * t2;
    float Jr[9] = {omc + c2 * px * px,  c1 * pz + c2 * px * py, -c1 * py + c2 * px * pz,
                   -c1 * pz + c2 * py * px, omc + c2 * py * py,  c1 * px + c2 * py * pz,
                    c1 * py + c2 * pz * px, -c1 * px + c2 * pz * py, omc + c2 * pz * pz};
    float sgdt2 = SIG_G2_C * dtv * dtv;
#pragma unroll
    for (int s6 = 0; s6 < 6; s6++) {
      const int i = SI6[s6], j = SJ6[s6];
      float v = X0[3 * i + 0] * Rd[0 + j] + X0[3 * i + 1] * Rd[3 + j] + X0[3 * i + 2] * Rd[6 + j];
      float jj = Jr[3 * i + 0] * Jr[3 * j + 0] + Jr[3 * i + 1] * Jr[3 * j + 1] + Jr[3 * i + 2] * Jr[3 * j + 2];
      s.c00[s6] = v + sgdt2 * jj;
    }
  }

  float Z[9];  mmT(X0, M, Z);  // (Rd^T C00) M^T
  // Wm = M C00 M^T, symmetric: 6 entries only
  float Wm6[6];
#pragma unroll
  for (int s6 = 0; s6 < 6; s6++) {
    const int i = SI6[s6], j = SJ6[s6];
    Wm6[s6] = Y0[3 * i + 0] * M[3 * j + 0] + Y0[3 * i + 1] * M[3 * j + 1] + Y0[3 * i + 2] * M[3 * j + 2];
  }
  float WmF[9]; expand6(Wm6, WmF);

  float Y1[9], Y2[9];
  {
    float X1[9]; mTm(Rd, s.c01, X1);
    mm(M, s.c01, Y1);
    float X2[9]; mTm(Rd, s.c02, X2);
    mm(M, s.c02, Y2);
#pragma unroll
    for (int k = 0; k < 9; k++) s.c01[k] = Z[k] + X1[k];
    // c02' = hdt*(c01' + X1) + X2   (== hdt*Z + dt*X1 + X2)
#pragma unroll
    for (int k = 0; k < 9; k++) s.c02[k] = hdt * (s.c01[k] + X1[k]) + X2[k];
  }

  float C11f[9]; expand6(s.c11, C11f);
  // c11pre = Wm + Y1 + Y1^T + c11_old (pre-noise), full 9
  float c11p[9];
#pragma unroll
  for (int i = 0; i < 3; i++)
#pragma unroll
    for (int j = 0; j < 3; j++)
      c11p[3 * i + j] = WmF[3 * i + j] + Y1[3 * i + j] + Y1[3 * j + i] + C11f[3 * i + j];

  float dt2v = dtv * dtv;
  // c22 (old c11, old c12, old c22)
#pragma unroll
  for (int s6 = 0; s6 < 6; s6++) {
    const int i = SI6[s6], j = SJ6[s6];
    float v = 0.25f * dt2v * WmF[3 * i + j]
            + 0.5f * dt2v * (Y1[3 * i + j] + Y1[3 * j + i])
            + hdt * (Y2[3 * i + j] + Y2[3 * j + i])
            + dt2v * C11f[3 * i + j]
            + dtv * (s.c12[3 * i + j] + s.c12[3 * j + i])
            + s.c22[s6];
    if (i == j) v += SIG_A2_C * 0.25f * dt2v * dt2v;
    s.c22[s6] = v;
  }
  // c12' = hdt*(c11pre + Y1 + c11_old) + Y2 + c12_old  (+ noise diag)
#pragma unroll
  for (int i = 0; i < 3; i++)
#pragma unroll
    for (int j = 0; j < 3; j++) {
      float v = hdt * (c11p[3 * i + j] + Y1[3 * i + j] + C11f[3 * i + j])
              + Y2[3 * i + j] + s.c12[3 * i + j];
      if (i == j) v += SIG_A2_C * hdt * dt2v;
      s.c12[3 * i + j] = v;
    }
  // c11 = c11pre + noise diag
#pragma unroll
  for (int s6 = 0; s6 < 6; s6++) {
    const int i = SI6[s6], j = SJ6[s6];
    float v = c11p[3 * i + j];
    if (i == j) v += SIG_A2_C * dt2v;
    s.c11[s6] = v;
  }

  // commit
#pragma unroll
  for (int i = 0; i < 4; i++) s.q[i] = qn[i];
#pragma unroll
  for (int k = 0; k < 9; k++) Ro[k] = Rn[k];
#pragma unroll
  for (int i = 0; i < 3; i++) gb[i] = gbn[i];
  s.t += dtv;
}

template <int CNT>
static __device__ __forceinline__ void shsel(const float* v, int d, bool rt, float* X, float* Y) {
#pragma unroll
  for (int i = 0; i < CNT; i++) {
    float o = __shfl_xor(v[i], d, 64);
    X[i] = rt ? o : v[i];
    Y[i] = rt ? v[i] : o;
  }
}

// Compose partner segments across lanes: result = X (earlier) then Y (later).
static __device__ __forceinline__ void compose(Seg& s, int d, int lane) {
  bool rt = (lane & d) != 0;

  // ---- rotation + time ----
  float RX[9], RY[9], tY;
  {
    float xq[4], yq[4];
    shsel<4>(s.q, d, rt, xq, yq);
    float ot = __shfl_xor(s.t, d, 64);
    tY = rt ? s.t : ot;
    s.t = s.t + ot;
    q2m(xq, RX); q2m(yq, RY);
    qmul(xq, yq, s.q);
  }

  // ---- dv, dp (dp before dv) ----
  {
    float xu[3], yu[3], xw[3], yw[3];
    shsel<3>(s.dv, d, rt, xu, yu);
    shsel<3>(s.dp, d, rt, xw, yw);
#pragma unroll
    for (int i = 0; i < 3; i++)
      s.dp[i] = xw[i] + tY * xu[i] + RX[3 * i + 0] * yw[0] + RX[3 * i + 1] * yw[1] + RX[3 * i + 2] * yw[2];
#pragma unroll
    for (int i = 0; i < 3; i++)
      s.dv[i] = xu[i] + RX[3 * i + 0] * yu[0] + RX[3 * i + 1] * yu[1] + RX[3 * i + 2] * yu[2];
  }

  // ---- P20 before P10; keep M10, M20 for covariance ----
  float M20[9], M10[9];
  {
    float xP20[9], yP20[9], xP10[9], yP10[9];
    shsel<9>(s.P20, d, rt, xP20, yP20);
    shsel<9>(s.P10, d, rt, xP10, yP10);
    float T[9];
    mm(RX, yP20, M20); mmT(M20, RX, T);
#pragma unroll
    for (int k = 0; k < 9; k++) s.P20[k] = xP20[k] + tY * xP10[k] + T[k];
    mm(RX, yP10, M10); mmT(M10, RX, T);
#pragma unroll
    for (int k = 0; k < 9; k++) s.P10[k] = xP10[k] + T[k];
  }

  // ---- covariance: cov' = F covX F^T + T covY T^T ----
  float B0[9], U1[9], U2[9];
  {
    float x00[6], y00[6];
    shsel<6>(s.c00, d, rt, x00, y00);
    float X00f[9]; expand6(x00, X00f);
    mTm(RY, X00f, B0);
    mm(M10, X00f, U1);
    mm(M20, X00f, U2);
#pragma unroll
    for (int s6 = 0; s6 < 6; s6++) {
      const int i = SI6[s6], j = SJ6[s6];
      s.c00[s6] = B0[3 * i + 0] * RY[0 + j] + B0[3 * i + 1] * RY[3 + j] + B0[3 * i + 2] * RY[6 + j] + y00[s6];
    }
  }

  float V1[9], V2[9], B1[9];
  {
    float x01[9], y01[9];
    shsel<9>(s.c01, d, rt, x01, y01);
    mTm(RY, x01, B1);
    mm(M10, x01, V1);
    mm(M20, x01, V2);
    float T1[9]; mmT(B0, M10, T1);
    float T2[9]; mmT(y01, RX, T2);
#pragma unroll
    for (int k = 0; k < 9; k++) s.c01[k] = T1[k] + B1[k] + T2[k];
  }

  float W1[9], W2[9];
  {
    float x02[9], y02[9];
    shsel<9>(s.c02, d, rt, x02, y02);
    float B2[9]; mTm(RY, x02, B2);
    mm(M10, x02, W1);
    mm(M20, x02, W2);
    float T1[9]; mmT(B0, M20, T1);
    float T2[9]; mmT(y02, RX, T2);
#pragma unroll
    for (int k = 0; k < 9; k++) s.c02[k] = T1[k] + tY * B1[k] + B2[k] + T2[k];
  }

  float x11[6], y11[6], x12[9], y12[9];
  shsel<6>(s.c11, d, rt, x11, y11);
  shsel<9>(s.c12, d, rt, x12, y12);
  float X11f[9]; expand6(x11, X11f);

  // c22
  {
    float x22[6], y22[6];
    shsel<6>(s.c22, d, rt, x22, y22);
    float Ta[9]; mmT(U2, M20, Ta);
    float A5[9];
    {
      float Y22f[9]; expand6(y22, Y22f);
      mm(RX, Y22f, A5);
    }
#pragma unroll
    for (int s6 = 0; s6 < 6; s6++) {
      const int i = SI6[s6], j = SJ6[s6];
      float cj = A5[3 * i + 0] * RX[3 * j + 0] + A5[3 * i + 1] * RX[3 * j + 1] + A5[3 * i + 2] * RX[3 * j + 2];
      s.c22[s6] = Ta[3 * i + j] + tY * (V2[3 * i + j] + V2[3 * j + i])
                + (W2[3 * i + j] + W2[3 * j + i]) + tY * tY * X11f[3 * i + j]
                + tY * (x12[3 * i + j] + x12[3 * j + i]) + x22[s6] + cj;
    }
  }
  // c12
  {
    float Tb[9]; mmT(U1, M20, Tb);
    float C4[9];
    {
      float A4[9]; mm(RX, y12, A4);
      mmT(A4, RX, C4);
    }
#pragma unroll
    for (int i = 0; i < 3; i++)
#pragma unroll
      for (int j = 0; j < 3; j++)
        s.c12[3 * i + j] = Tb[3 * i + j] + tY * V1[3 * i + j] + W1[3 * i + j] + V2[3 * j + i]
                         + tY * X11f[3 * i + j] + x12[3 * i + j] + C4[3 * i + j];
  }
  // c11
  {
    float Tc[9]; mmT(U1, M10, Tc);
    float A3[9];
    {
      float Y11f[9]; expand6(y11, Y11f);
      mm(RX, Y11f, A3);
    }
#pragma unroll
    for (int s6 = 0; s6 < 6; s6++) {
      const int i = SI6[s6], j = SJ6[s6];
      float cj = A3[3 * i + 0] * RX[3 * j + 0] + A3[3 * i + 1] * RX[3 * j + 1] + A3[3 * i + 2] * RX[3 * j + 2];
      s.c11[s6] = Tc[3 * i + j] + V1[3 * i + j] + V1[3 * j + i] + x11[s6] + cj;
    }
  }
}

__global__ __launch_bounds__(64, 1) void imu_kernel(
    const float* __restrict__ dt, const float* __restrict__ ang, const float* __restrict__ acc,
    const float* __restrict__ pos0, const float* __restrict__ vel0, const float* __restrict__ rot0,
    float* __restrict__ out, int B, int N) {
  int lane = threadIdx.x & 63;
  int b = blockIdx.x;
  int chunk = N >> 6; // 16 steps per lane

  long base = (long)b * N + (long)lane * chunk;
  const float* dtp = dt + base;
  const float* angp = ang + base * 3;
  const float* accp = acc + base * 3;

  // ---- pre-pass: chunk rotation product (float4 loads, Taylor exp) ----
  float qc[4] = {0.f, 0.f, 0.f, 1.f};
#pragma unroll 1
  for (int jb = 0; jb < (chunk >> 2); ++jb) {
    float4 d4 = *reinterpret_cast<const float4*>(dtp + jb * 4);
    float4 g0 = *reinterpret_cast<const float4*>(angp + jb * 12 + 0);
    float4 g1 = *reinterpret_cast<const float4*>(angp + jb * 12 + 4);
    float4 g2 = *reinterpret_cast<const float4*>(angp + jb * 12 + 8);
    float dd[4] = {d4.x, d4.y, d4.z, d4.w};
    float gg[12] = {g0.x, g0.y, g0.z, g0.w, g1.x, g1.y, g1.z, g1.w, g2.x, g2.y, g2.z, g2.w};
#pragma unroll
    for (int u = 0; u < 4; ++u) {
      float dtv = dd[u];
      float px = gg[3 * u + 0] * dtv, py = gg[3 * u + 1] * dtv, pz = gg[3 * u + 2] * dtv;
      float t2 = px * px + py * py + pz * pz;
      float s_ = 0.5f - t2 * (1.0f / 48.0f);
      float qd[4] = {px * s_, py * s_, pz * s_, 1.0f - 0.125f * t2};
      float qn[4]; qmul(qc, qd, qn);
      qc[0] = qn[0]; qc[1] = qn[1]; qc[2] = qn[2]; qc[3] = qn[3];
    }
  }
  // inclusive shuffle-up scan (non-commutative: earlier on the left)
#pragma unroll
  for (int d = 1; d < 64; d <<= 1) {
    float o0 = __shfl_up(qc[0], d, 64);
    float o1 = __shfl_up(qc[1], d, 64);
    float o2 = __shfl_up(qc[2], d, 64);
    float o3 = __shfl_up(qc[3], d, 64);
    if (lane >= d) {
      float oq[4] = {o0, o1, o2, o3};
      float nn[4]; qmul(oq, qc, nn);
      qc[0] = nn[0]; qc[1] = nn[1]; qc[2] = nn[2]; qc[3] = nn[3];
    }
  }
  // exclusive prefix Q
  float Q[4];
  Q[0] = __shfl_up(qc[0], 1, 64);
  Q[1] = __shfl_up(qc[1], 1, 64);
  Q[2] = __shfl_up(qc[2], 1, 64);
  Q[3] = __shfl_up(qc[3], 1, 64);
  if (lane == 0) { Q[0] = 0.f; Q[1] = 0.f; Q[2] = 0.f; Q[3] = 1.f; }

  // per-lane constant gravity in chunk-start frame: g_l = R(Q)^T R0^T g
  float r0q[4] = {rot0[b * 4 + 0], rot0[b * 4 + 1], rot0[b * 4 + 2], rot0[b * 4 + 3]};
  float g_l[3];
  {
    float R0[9]; q2m(r0q, R0);
    float gp[3] = {R0[6] * GRAVITY_C, R0[7] * GRAVITY_C, R0[8] * GRAVITY_C}; // R0^T g
    float RQ[9]; q2m(Q, RQ);
#pragma unroll
    for (int i = 0; i < 3; i++)
      g_l[i] = RQ[0 + i] * gp[0] + RQ[3 + i] * gp[1] + RQ[6 + i] * gp[2];
  }

  Seg s = {};
  s.q[3] = 1.0f;
  float Ro[9] = {1.f, 0.f, 0.f, 0.f, 1.f, 0.f, 0.f, 0.f, 1.f};
  float gb[3] = {g_l[0], g_l[1], g_l[2]};

  // ---- phase 1: sequential integration with 1-deep input prefetch ----
  float dc = dtp[0];
  float gx = angp[0], gy = angp[1], gz = angp[2];
  float ax = accp[0], ay = accp[1], az = accp[2];
#pragma unroll 1
  for (int j = 0; j < chunk; ++j) {
    int jn = (j + 1 < chunk) ? j + 1 : j;
    float dn = dtp[jn];
    float gnx = angp[3 * jn + 0], gny = angp[3 * jn + 1], gnz = angp[3 * jn + 2];
    float anx = accp[3 * jn + 0], any2 = accp[3 * jn + 1], anz = accp[3 * jn + 2];
    step(s, Ro, gb, dc, gx, gy, gz, ax, ay, az);
    dc = dn; gx = gnx; gy = gny; gz = gnz; ax = anx; ay = any2; az = anz;
  }

  // ---- phase 2: non-commutative butterfly reduction over 64 chunks ----
#pragma unroll 1
  for (int d = 1; d < 64; d <<= 1) compose(s, d, lane);

  if (lane == 0) {
    float p0[3] = {pos0[b * 3 + 0], pos0[b * 3 + 1], pos0[b * 3 + 2]};
    float v0[3] = {vel0[b * 3 + 0], vel0[b * 3 + 1], vel0[b * 3 + 2]};
    float R0[9]; q2m(r0q, R0);
    float qo[4]; qmul(r0q, s.q, qo);
#pragma unroll
    for (int i = 0; i < 4; i++) out[b * 4 + i] = qo[i];
#pragma unroll
    for (int i = 0; i < 3; i++) {
      float vv = v0[i] + R0[3 * i + 0] * s.dv[0] + R0[3 * i + 1] * s.dv[1] + R0[3 * i + 2] * s.dv[2];
      float pv = p0[i] + v0[i] * s.t + R0[3 * i + 0] * s.dp[0] + R0[3 * i + 1] * s.dp[1] + R0[3 * i + 2] * s.dp[2];
      out[4 * B + b * 3 + i] = vv;
      out[7 * B + b * 3 + i] = pv;
    }
    long cb = 10L * B + (long)b * 81;
    float C00f[9], C11f[9], C22f[9];
    expand6(s.c00, C00f); expand6(s.c11, C11f); expand6(s.c22, C22f);
#pragma unroll
    for (int i = 0; i < 3; i++)
#pragma unroll
      for (int j = 0; j < 3; j++) {
        out[cb + i * 9 + j]           = C00f[3 * i + j];
        out[cb + i * 9 + (j + 3)]     = s.c01[3 * i + j];
        out[cb + i * 9 + (j + 6)]     = s.c02[3 * i + j];
        out[cb + (i + 3) * 9 + j]     = s.c01[3 * j + i];
        out[cb + (i + 3) * 9 + j + 3] = C11f[3 * i + j];
        out[cb + (i + 3) * 9 + j + 6] = s.c12[3 * i + j];
        out[cb + (i + 6) * 9 + j]     = s.c02[3 * j + i];
        out[cb + (i + 6) * 9 + j + 3] = s.c12[3 * j + i];
        out[cb + (i + 6) * 9 + j + 6] = C22f[3 * i + j];
      }
  }
}

extern "C" void kernel_launch(void* const* d_in, const int* in_sizes, int n_in,
                              void* d_out, int out_size, void* d_ws, size_t ws_size,
                              hipStream_t stream) {
  const float* dt   = (const float*)d_in[0];
  const float* ang  = (const float*)d_in[1];
  const float* acc  = (const float*)d_in[2];
  const float* pos0 = (const float*)d_in[3];
  const float* vel0 = (const float*)d_in[4];
  const float* rot0 = (const float*)d_in[5];
  int B = in_sizes[5] / 4;
  int N = in_sizes[0] / B;
  float* out = (float*)d_out;
  dim3 grid(B), block(64);
  imu_kernel<<<grid, block, 0, stream>>>(dt, ang, acc, pos0, vel0, rot0, out, B, N);
}

// Round 5
// 98.071 us; speedup vs baseline: 9.9080x; 1.0247x over previous
//
#include <hip/hip_runtime.h>
#include <math.h>

#define GRAVITY_C 9.81007f
#define SIG_G2_C (1.6968e-4f * 1.6968e-4f)
#define SIG_A2_C (2.0e-3f * 2.0e-3f)

// Segment summary: composable preintegration state (74 floats).
// Gravity folded per-lane via prefix rotation => dp/dv are TRUE deltas
// in the segment-start frame.
struct Seg {
  float q[4];            // segment delta-rotation quat (xyzw)
  float t;               // accumulated time
  float dv[3], dp[3];    // true velocity/position deltas (gravity included)
  float P10[9], P20[9];  // Phi(1,0), Phi(2,0) blocks of 9x9 transition
  float c00[6], c01[9], c02[9], c11[6], c12[9], c22[6]; // sym cov blocks
};

static __device__ __forceinline__ void q2m(const float q[4], float R[9]) {
  float x = q[0], y = q[1], z = q[2], w = q[3];
  R[0] = 1.f - 2.f * (y * y + z * z); R[1] = 2.f * (x * y - z * w);       R[2] = 2.f * (x * z + y * w);
  R[3] = 2.f * (x * y + z * w);       R[4] = 1.f - 2.f * (x * x + z * z); R[5] = 2.f * (y * z - x * w);
  R[6] = 2.f * (x * z - y * w);       R[7] = 2.f * (y * z + x * w);       R[8] = 1.f - 2.f * (x * x + y * y);
}

static __device__ __forceinline__ void qmul(const float a[4], const float b[4], float o[4]) {
  float x1 = a[0], y1 = a[1], z1 = a[2], w1 = a[3];
  float x2 = b[0], y2 = b[1], z2 = b[2], w2 = b[3];
  o[0] = w1 * x2 + x1 * w2 + y1 * z2 - z1 * y2;
  o[1] = w1 * y2 - x1 * z2 + y1 * w2 + z1 * x2;
  o[2] = w1 * z2 + x1 * y2 - y1 * x2 + z1 * w2;
  o[3] = w1 * w2 - x1 * x2 - y1 * y2 - z1 * z2;
}

// C = A @ B
static __device__ __forceinline__ void mm(const float A[9], const float B[9], float C[9]) {
#pragma unroll
  for (int i = 0; i < 3; i++)
#pragma unroll
    for (int j = 0; j < 3; j++)
      C[3 * i + j] = A[3 * i + 0] * B[0 + j] + A[3 * i + 1] * B[3 + j] + A[3 * i + 2] * B[6 + j];
}
// C = A @ B^T
static __device__ __forceinline__ void mmT(const float A[9], const float B[9], float C[9]) {
#pragma unroll
  for (int i = 0; i < 3; i++)
#pragma unroll
    for (int j = 0; j < 3; j++)
      C[3 * i + j] = A[3 * i + 0] * B[3 * j + 0] + A[3 * i + 1] * B[3 * j + 1] + A[3 * i + 2] * B[3 * j + 2];
}
// C = A^T @ B
static __device__ __forceinline__ void mTm(const float A[9], const float B[9], float C[9]) {
#pragma unroll
  for (int i = 0; i < 3; i++)
#pragma unroll
    for (int j = 0; j < 3; j++)
      C[3 * i + j] = A[0 + i] * B[0 + j] + A[3 + i] * B[3 + j] + A[6 + i] * B[6 + j];
}

static __device__ __forceinline__ void expand6(const float c[6], float f[9]) {
  f[0] = c[0]; f[1] = c[1]; f[2] = c[2];
  f[3] = c[1]; f[4] = c[3]; f[5] = c[4];
  f[6] = c[2]; f[7] = c[4]; f[8] = c[5];
}

// sym index tables: entries (0,0),(0,1),(0,2),(1,1),(1,2),(2,2)
__device__ __constant__ const int SI6[6] = {0, 0, 0, 1, 1, 2};
__device__ __constant__ const int SJ6[6] = {0, 1, 2, 1, 2, 2};

// One IMU step. Ro = R(s.q) carried; gb = body-frame gravity carried.
// Taylor forms valid for |phi| <~ 0.05 rad (data: <= ~0.02), err ~1e-10.
static __device__ __forceinline__ void step(Seg& s, float Ro[9], float gb[3], float dtv,
                                            float omx, float omy, float omz,
                                            float acx, float acy, float acz) {
  float px = omx * dtv, py = omy * dtv, pz = omz * dtv;
  float t2 = px * px + py * py + pz * pz;
  float s_ = 0.5f - t2 * (1.0f / 48.0f);
  float qd[4] = {px * s_, py * s_, pz * s_, 1.0f - 0.125f * t2};
  float c1 = 0.5f - t2 * (1.0f / 24.0f);
  float c2 = (1.0f / 6.0f) - t2 * (1.0f / 120.0f);

  float Rd[9]; q2m(qd, Rd);
  float qn[4]; qmul(s.q, qd, qn);
  float Rn[9]; q2m(qn, Rn);

  // gb' = Rd^T gb  (gravity in new body frame)
  float gbn[3];
#pragma unroll
  for (int i = 0; i < 3; i++)
    gbn[i] = Rd[0 + i] * gb[0] + Rd[3 + i] * gb[1] + Rd[6 + i] * gb[2];
  // Ra = Ro * (acc - gb')
  float bx = acx - gbn[0], by = acy - gbn[1], bz = acz - gbn[2];
  float Ra[3];
#pragma unroll
  for (int i = 0; i < 3; i++)
    Ra[i] = Ro[3 * i + 0] * bx + Ro[3 * i + 1] * by + Ro[3 * i + 2] * bz;

  // dp (old dv) then dv
  float hdt = 0.5f * dtv;
  float hdt2 = hdt * dtv;
#pragma unroll
  for (int i = 0; i < 3; i++) s.dp[i] += s.dv[i] * dtv + Ra[i] * hdt2;
#pragma unroll
  for (int i = 0; i < 3; i++) s.dv[i] += Ra[i] * dtv;

  // M = -dt * (Rn @ skew(acc))
  float M[9];
#pragma unroll
  for (int i = 0; i < 3; i++) {
    M[3 * i + 0] = -dtv * (Rn[3 * i + 1] * acz - Rn[3 * i + 2] * acy);
    M[3 * i + 1] = -dtv * (-Rn[3 * i + 0] * acz + Rn[3 * i + 2] * acx);
    M[3 * i + 2] = -dtv * (Rn[3 * i + 0] * acy - Rn[3 * i + 1] * acx);
  }

  // Phi blocks: P20 before P10
  {
    float TP[9]; mmT(M, Ro, TP); // M @ Ro^T  (Ro = OLD rotation)
#pragma unroll
    for (int k = 0; k < 9; k++) s.P20[k] += hdt * TP[k] + dtv * s.P10[k];
#pragma unroll
    for (int k = 0; k < 9; k++) s.P10[k] += TP[k];
  }

  // ---- covariance ----
  float X0[9], Y0[9];
  {
    float C00f[9]; expand6(s.c00, C00f);
    mTm(Rd, C00f, X0); // Rd^T C00
    mm(M, C00f, Y0);   // M C00
  }

  // c00' = X0 Rd + SIG_G2 dt^2 Jr Jr^T
  {
    float omc = 1.0f - c2 * t2;
    float Jr[9] = {omc + c2 * px * px,  c1 * pz + c2 * px * py, -c1 * py + c2 * px * pz,
                   -c1 * pz + c2 * py * px, omc + c2 * py * py,  c1 * px + c2 * py * pz,
                    c1 * py + c2 * pz * px, -c1 * px + c2 * pz * py, omc + c2 * pz * pz};
    float sgdt2 = SIG_G2_C * dtv * dtv;
#pragma unroll
    for (int s6 = 0; s6 < 6; s6++) {
      const int i = SI6[s6], j = SJ6[s6];
      float v = X0[3 * i + 0] * Rd[0 + j] + X0[3 * i + 1] * Rd[3 + j] + X0[3 * i + 2] * Rd[6 + j];
      float jj = Jr[3 * i + 0] * Jr[3 * j + 0] + Jr[3 * i + 1] * Jr[3 * j + 1] + Jr[3 * i + 2] * Jr[3 * j + 2];
      s.c00[s6] = v + sgdt2 * jj;
    }
  }

  float Z[9];  mmT(X0, M, Z);  // (Rd^T C00) M^T
  // Wm = M C00 M^T, symmetric: 6 entries only
  float Wm6[6];
#pragma unroll
  for (int s6 = 0; s6 < 6; s6++) {
    const int i = SI6[s6], j = SJ6[s6];
    Wm6[s6] = Y0[3 * i + 0] * M[3 * j + 0] + Y0[3 * i + 1] * M[3 * j + 1] + Y0[3 * i + 2] * M[3 * j + 2];
  }
  float WmF[9]; expand6(Wm6, WmF);

  float Y1[9], Y2[9];
  {
    float X1[9]; mTm(Rd, s.c01, X1);
    mm(M, s.c01, Y1);
    float X2[9]; mTm(Rd, s.c02, X2);
    mm(M, s.c02, Y2);
#pragma unroll
    for (int k = 0; k < 9; k++) s.c01[k] = Z[k] + X1[k];
    // c02' = hdt*(c01' + X1) + X2   (== hdt*Z + dt*X1 + X2)
#pragma unroll
    for (int k = 0; k < 9; k++) s.c02[k] = hdt * (s.c01[k] + X1[k]) + X2[k];
  }

  float C11f[9]; expand6(s.c11, C11f);
  // c11pre = Wm + Y1 + Y1^T + c11_old (pre-noise), full 9
  float c11p[9];
#pragma unroll
  for (int i = 0; i < 3; i++)
#pragma unroll
    for (int j = 0; j < 3; j++)
      c11p[3 * i + j] = WmF[3 * i + j] + Y1[3 * i + j] + Y1[3 * j + i] + C11f[3 * i + j];

  float dt2v = dtv * dtv;
  // c22 (old c11, old c12, old c22)
#pragma unroll
  for (int s6 = 0; s6 < 6; s6++) {
    const int i = SI6[s6], j = SJ6[s6];
    float v = 0.25f * dt2v * WmF[3 * i + j]
            + 0.5f * dt2v * (Y1[3 * i + j] + Y1[3 * j + i])
            + hdt * (Y2[3 * i + j] + Y2[3 * j + i])
            + dt2v * C11f[3 * i + j]
            + dtv * (s.c12[3 * i + j] + s.c12[3 * j + i])
            + s.c22[s6];
    if (i == j) v += SIG_A2_C * 0.25f * dt2v * dt2v;
    s.c22[s6] = v;
  }
  // c12' = hdt*(c11pre + Y1 + c11_old) + Y2 + c12_old  (+ noise diag)
#pragma unroll
  for (int i = 0; i < 3; i++)
#pragma unroll
    for (int j = 0; j < 3; j++) {
      float v = hdt * (c11p[3 * i + j] + Y1[3 * i + j] + C11f[3 * i + j])
              + Y2[3 * i + j] + s.c12[3 * i + j];
      if (i == j) v += SIG_A2_C * hdt * dt2v;
      s.c12[3 * i + j] = v;
    }
  // c11 = c11pre + noise diag
#pragma unroll
  for (int s6 = 0; s6 < 6; s6++) {
    const int i = SI6[s6], j = SJ6[s6];
    float v = c11p[3 * i + j];
    if (i == j) v += SIG_A2_C * dt2v;
    s.c11[s6] = v;
  }

  // commit
#pragma unroll
  for (int i = 0; i < 4; i++) s.q[i] = qn[i];
#pragma unroll
  for (int k = 0; k < 9; k++) Ro[k] = Rn[k];
#pragma unroll
  for (int i = 0; i < 3; i++) gb[i] = gbn[i];
  s.t += dtv;
}

template <int CNT>
static __device__ __forceinline__ void shsel(const float* v, int d, bool rt, float* X, float* Y) {
#pragma unroll
  for (int i = 0; i < CNT; i++) {
    float o = __shfl_xor(v[i], d, 64);
    X[i] = rt ? o : v[i];
    Y[i] = rt ? v[i] : o;
  }
}

// Compose partner segments across lanes: result = X (earlier) then Y (later).
static __device__ __forceinline__ void compose(Seg& s, int d, int lane) {
  bool rt = (lane & d) != 0;

  // ---- rotation + time ----
  float RX[9], RY[9], tY;
  {
    float xq[4], yq[4];
    shsel<4>(s.q, d, rt, xq, yq);
    float ot = __shfl_xor(s.t, d, 64);
    tY = rt ? s.t : ot;
    s.t = s.t + ot;
    q2m(xq, RX); q2m(yq, RY);
    qmul(xq, yq, s.q);
  }

  // ---- dv, dp (dp before dv) ----
  {
    float xu[3], yu[3], xw[3], yw[3];
    shsel<3>(s.dv, d, rt, xu, yu);
    shsel<3>(s.dp, d, rt, xw, yw);
#pragma unroll
    for (int i = 0; i < 3; i++)
      s.dp[i] = xw[i] + tY * xu[i] + RX[3 * i + 0] * yw[0] + RX[3 * i + 1] * yw[1] + RX[3 * i + 2] * yw[2];
#pragma unroll
    for (int i = 0; i < 3; i++)
      s.dv[i] = xu[i] + RX[3 * i + 0] * yu[0] + RX[3 * i + 1] * yu[1] + RX[3 * i + 2] * yu[2];
  }

  // ---- P20 before P10; keep M10, M20 for covariance ----
  float M20[9], M10[9];
  {
    float xP20[9], yP20[9], xP10[9], yP10[9];
    shsel<9>(s.P20, d, rt, xP20, yP20);
    shsel<9>(s.P10, d, rt, xP10, yP10);
    float T[9];
    mm(RX, yP20, M20); mmT(M20, RX, T);
#pragma unroll
    for (int k = 0; k < 9; k++) s.P20[k] = xP20[k] + tY * xP10[k] + T[k];
    mm(RX, yP10, M10); mmT(M10, RX, T);
#pragma unroll
    for (int k = 0; k < 9; k++) s.P10[k] = xP10[k] + T[k];
  }

  // ---- covariance: cov' = F covX F^T + T covY T^T ----
  float B0[9], U1[9], U2[9];
  {
    float x00[6], y00[6];
    shsel<6>(s.c00, d, rt, x00, y00);
    float X00f[9]; expand6(x00, X00f);
    mTm(RY, X00f, B0);
    mm(M10, X00f, U1);
    mm(M20, X00f, U2);
#pragma unroll
    for (int s6 = 0; s6 < 6; s6++) {
      const int i = SI6[s6], j = SJ6[s6];
      s.c00[s6] = B0[3 * i + 0] * RY[0 + j] + B0[3 * i + 1] * RY[3 + j] + B0[3 * i + 2] * RY[6 + j] + y00[s6];
    }
  }

  float V1[9], V2[9], B1[9];
  {
    float x01[9], y01[9];
    shsel<9>(s.c01, d, rt, x01, y01);
    mTm(RY, x01, B1);
    mm(M10, x01, V1);
    mm(M20, x01, V2);
    float T1[9]; mmT(B0, M10, T1);
    float T2[9]; mmT(y01, RX, T2);
#pragma unroll
    for (int k = 0; k < 9; k++) s.c01[k] = T1[k] + B1[k] + T2[k];
  }

  float W1[9], W2[9];
  {
    float x02[9], y02[9];
    shsel<9>(s.c02, d, rt, x02, y02);
    float B2[9]; mTm(RY, x02, B2);
    mm(M10, x02, W1);
    mm(M20, x02, W2);
    float T1[9]; mmT(B0, M20, T1);
    float T2[9]; mmT(y02, RX, T2);
#pragma unroll
    for (int k = 0; k < 9; k++) s.c02[k] = T1[k] + tY * B1[k] + B2[k] + T2[k];
  }

  float x11[6], y11[6], x12[9], y12[9];
  shsel<6>(s.c11, d, rt, x11, y11);
  shsel<9>(s.c12, d, rt, x12, y12);
  float X11f[9]; expand6(x11, X11f);

  // c22
  {
    float x22[6], y22[6];
    shsel<6>(s.c22, d, rt, x22, y22);
    float Ta[9]; mmT(U2, M20, Ta);
    float A5[9];
    {
      float Y22f[9]; expand6(y22, Y22f);
      mm(RX, Y22f, A5);
    }
#pragma unroll
    for (int s6 = 0; s6 < 6; s6++) {
      const int i = SI6[s6], j = SJ6[s6];
      float cj = A5[3 * i + 0] * RX[3 * j + 0] + A5[3 * i + 1] * RX[3 * j + 1] + A5[3 * i + 2] * RX[3 * j + 2];
      s.c22[s6] = Ta[3 * i + j] + tY * (V2[3 * i + j] + V2[3 * j + i])
                + (W2[3 * i + j] + W2[3 * j + i]) + tY * tY * X11f[3 * i + j]
                + tY * (x12[3 * i + j] + x12[3 * j + i]) + x22[s6] + cj;
    }
  }
  // c12
  {
    float Tb[9]; mmT(U1, M20, Tb);
    float C4[9];
    {
      float A4[9]; mm(RX, y12, A4);
      mmT(A4, RX, C4);
    }
#pragma unroll
    for (int i = 0; i < 3; i++)
#pragma unroll
      for (int j = 0; j < 3; j++)
        s.c12[3 * i + j] = Tb[3 * i + j] + tY * V1[3 * i + j] + W1[3 * i + j] + V2[3 * j + i]
                         + tY * X11f[3 * i + j] + x12[3 * i + j] + C4[3 * i + j];
  }
  // c11
  {
    float Tc[9]; mmT(U1, M10, Tc);
    float A3[9];
    {
      float Y11f[9]; expand6(y11, Y11f);
      mm(RX, Y11f, A3);
    }
#pragma unroll
    for (int s6 = 0; s6 < 6; s6++) {
      const int i = SI6[s6], j = SJ6[s6];
      float cj = A3[3 * i + 0] * RX[3 * j + 0] + A3[3 * i + 1] * RX[3 * j + 1] + A3[3 * i + 2] * RX[3 * j + 2];
      s.c11[s6] = Tc[3 * i + j] + V1[3 * i + j] + V1[3 * j + i] + x11[s6] + cj;
    }
  }
}

// 256-thread blocks, 4 independent batch-waves per block (no inter-wave
// communication). min 1 wave/EU keeps the 512-VGPR regalloc budget while
// giving the HW scheduler large workgroups (fixes the ~4 workgroups/CU
// small-block residency limit seen at 64-thread blocks).
__global__ __launch_bounds__(256, 1) void imu_kernel(
    const float* __restrict__ dt, const float* __restrict__ ang, const float* __restrict__ acc,
    const float* __restrict__ pos0, const float* __restrict__ vel0, const float* __restrict__ rot0,
    float* __restrict__ out, int B, int N) {
  int lane = threadIdx.x & 63;
  int wave = threadIdx.x >> 6;
  int b = blockIdx.x * 4 + wave;
  if (b >= B) return;
  int chunk = N >> 6; // 16 steps per lane

  long base = (long)b * N + (long)lane * chunk;
  const float* dtp = dt + base;
  const float* angp = ang + base * 3;
  const float* accp = acc + base * 3;

  // ---- pre-pass: chunk rotation product (float4 loads, Taylor exp) ----
  float qc[4] = {0.f, 0.f, 0.f, 1.f};
#pragma unroll 1
  for (int jb = 0; jb < (chunk >> 2); ++jb) {
    float4 d4 = *reinterpret_cast<const float4*>(dtp + jb * 4);
    float4 g0 = *reinterpret_cast<const float4*>(angp + jb * 12 + 0);
    float4 g1 = *reinterpret_cast<const float4*>(angp + jb * 12 + 4);
    float4 g2 = *reinterpret_cast<const float4*>(angp + jb * 12 + 8);
    float dd[4] = {d4.x, d4.y, d4.z, d4.w};
    float gg[12] = {g0.x, g0.y, g0.z, g0.w, g1.x, g1.y, g1.z, g1.w, g2.x, g2.y, g2.z, g2.w};
#pragma unroll
    for (int u = 0; u < 4; ++u) {
      float dtv = dd[u];
      float px = gg[3 * u + 0] * dtv, py = gg[3 * u + 1] * dtv, pz = gg[3 * u + 2] * dtv;
      float t2 = px * px + py * py + pz * pz;
      float s_ = 0.5f - t2 * (1.0f / 48.0f);
      float qd[4] = {px * s_, py * s_, pz * s_, 1.0f - 0.125f * t2};
      float qn[4]; qmul(qc, qd, qn);
      qc[0] = qn[0]; qc[1] = qn[1]; qc[2] = qn[2]; qc[3] = qn[3];
    }
  }
  // inclusive shuffle-up scan (non-commutative: earlier on the left)
#pragma unroll
  for (int d = 1; d < 64; d <<= 1) {
    float o0 = __shfl_up(qc[0], d, 64);
    float o1 = __shfl_up(qc[1], d, 64);
    float o2 = __shfl_up(qc[2], d, 64);
    float o3 = __shfl_up(qc[3], d, 64);
    if (lane >= d) {
      float oq[4] = {o0, o1, o2, o3};
      float nn[4]; qmul(oq, qc, nn);
      qc[0] = nn[0]; qc[1] = nn[1]; qc[2] = nn[2]; qc[3] = nn[3];
    }
  }
  // exclusive prefix Q
  float Q[4];
  Q[0] = __shfl_up(qc[0], 1, 64);
  Q[1] = __shfl_up(qc[1], 1, 64);
  Q[2] = __shfl_up(qc[2], 1, 64);
  Q[3] = __shfl_up(qc[3], 1, 64);
  if (lane == 0) { Q[0] = 0.f; Q[1] = 0.f; Q[2] = 0.f; Q[3] = 1.f; }

  // per-lane constant gravity in chunk-start frame: g_l = R(Q)^T R0^T g
  float r0q[4] = {rot0[b * 4 + 0], rot0[b * 4 + 1], rot0[b * 4 + 2], rot0[b * 4 + 3]};
  float g_l[3];
  {
    float R0[9]; q2m(r0q, R0);
    float gp[3] = {R0[6] * GRAVITY_C, R0[7] * GRAVITY_C, R0[8] * GRAVITY_C}; // R0^T g
    float RQ[9]; q2m(Q, RQ);
#pragma unroll
    for (int i = 0; i < 3; i++)
      g_l[i] = RQ[0 + i] * gp[0] + RQ[3 + i] * gp[1] + RQ[6 + i] * gp[2];
  }

  Seg s = {};
  s.q[3] = 1.0f;
  float Ro[9] = {1.f, 0.f, 0.f, 0.f, 1.f, 0.f, 0.f, 0.f, 1.f};
  float gb[3] = {g_l[0], g_l[1], g_l[2]};

  // ---- phase 1: sequential integration with 1-deep input prefetch ----
  float dc = dtp[0];
  float gx = angp[0], gy = angp[1], gz = angp[2];
  float ax = accp[0], ay = accp[1], az = accp[2];
#pragma unroll 1
  for (int j = 0; j < chunk; ++j) {
    int jn = (j + 1 < chunk) ? j + 1 : j;
    float dn = dtp[jn];
    float gnx = angp[3 * jn + 0], gny = angp[3 * jn + 1], gnz = angp[3 * jn + 2];
    float anx = accp[3 * jn + 0], any2 = accp[3 * jn + 1], anz = accp[3 * jn + 2];
    step(s, Ro, gb, dc, gx, gy, gz, ax, ay, az);
    dc = dn; gx = gnx; gy = gny; gz = gnz; ax = anx; ay = any2; az = anz;
  }

  // ---- phase 2: non-commutative butterfly reduction over 64 chunks ----
#pragma unroll 1
  for (int d = 1; d < 64; d <<= 1) compose(s, d, lane);

  if (lane == 0) {
    float p0[3] = {pos0[b * 3 + 0], pos0[b * 3 + 1], pos0[b * 3 + 2]};
    float v0[3] = {vel0[b * 3 + 0], vel0[b * 3 + 1], vel0[b * 3 + 2]};
    float R0[9]; q2m(r0q, R0);
    float qo[4]; qmul(r0q, s.q, qo);
#pragma unroll
    for (int i = 0; i < 4; i++) out[b * 4 + i] = qo[i];
#pragma unroll
    for (int i = 0; i < 3; i++) {
      float vv = v0[i] + R0[3 * i + 0] * s.dv[0] + R0[3 * i + 1] * s.dv[1] + R0[3 * i + 2] * s.dv[2];
      float pv = p0[i] + v0[i] * s.t + R0[3 * i + 0] * s.dp[0] + R0[3 * i + 1] * s.dp[1] + R0[3 * i + 2] * s.dp[2];
      out[4 * B + b * 3 + i] = vv;
      out[7 * B + b * 3 + i] = pv;
    }
    long cb = 10L * B + (long)b * 81;
    float C00f[9], C11f[9], C22f[9];
    expand6(s.c00, C00f); expand6(s.c11, C11f); expand6(s.c22, C22f);
#pragma unroll
    for (int i = 0; i < 3; i++)
#pragma unroll
      for (int j = 0; j < 3; j++) {
        out[cb + i * 9 + j]           = C00f[3 * i + j];
        out[cb + i * 9 + (j + 3)]     = s.c01[3 * i + j];
        out[cb + i * 9 + (j + 6)]     = s.c02[3 * i + j];
        out[cb + (i + 3) * 9 + j]     = s.c01[3 * j + i];
        out[cb + (i + 3) * 9 + j + 3] = C11f[3 * i + j];
        out[cb + (i + 3) * 9 + j + 6] = s.c12[3 * i + j];
        out[cb + (i + 6) * 9 + j]     = s.c02[3 * j + i];
        out[cb + (i + 6) * 9 + j + 3] = s.c12[3 * j + i];
        out[cb + (i + 6) * 9 + j + 6] = C22f[3 * i + j];
      }
  }
}

extern "C" void kernel_launch(void* const* d_in, const int* in_sizes, int n_in,
                              void* d_out, int out_size, void* d_ws, size_t ws_size,
                              hipStream_t stream) {
  const float* dt   = (const float*)d_in[0];
  const float* ang  = (const float*)d_in[1];
  const float* acc  = (const float*)d_in[2];
  const float* pos0 = (const float*)d_in[3];
  const float* vel0 = (const float*)d_in[4];
  const float* rot0 = (const float*)d_in[5];
  int B = in_sizes[5] / 4;
  int N = in_sizes[0] / B;
  float* out = (float*)d_out;
  dim3 grid((B + 3) / 4), block(256);
  imu_kernel<<<grid, block, 0, stream>>>(dt, ang, acc, pos0, vel0, rot0, out, B, N);
}

// Round 6
// 94.895 us; speedup vs baseline: 10.2396x; 1.0335x over previous
//
#include <hip/hip_runtime.h>
#include <math.h>

#define GRAVITY_C 9.81007f
#define SIG_G2_C (1.6968e-4f * 1.6968e-4f)
#define SIG_A2_C (2.0e-3f * 2.0e-3f)

// Segment summary: composable preintegration state (74 floats).
// During phase 1 the c00/c01/c02 blocks are kept in "hat" (chunk-start) frame:
//   ^c00 = Rq c00 Rq^T, ^c01 = Rq c01, ^c02 = Rq c02
// which removes the per-step Rd sandwich; un-hatted once at phase-1 end.
struct Seg {
  float q[4];            // segment delta-rotation quat (xyzw)
  float t;               // accumulated time
  float dv[3], dp[3];    // true velocity/position deltas (gravity included)
  float P10[9], P20[9];  // Phi(1,0), Phi(2,0) blocks of 9x9 transition
  float c00[6], c01[9], c02[9], c11[6], c12[9], c22[6]; // sym cov blocks
};

static __device__ __forceinline__ void q2m(const float q[4], float R[9]) {
  float x = q[0], y = q[1], z = q[2], w = q[3];
  R[0] = 1.f - 2.f * (y * y + z * z); R[1] = 2.f * (x * y - z * w);       R[2] = 2.f * (x * z + y * w);
  R[3] = 2.f * (x * y + z * w);       R[4] = 1.f - 2.f * (x * x + z * z); R[5] = 2.f * (y * z - x * w);
  R[6] = 2.f * (x * z - y * w);       R[7] = 2.f * (y * z + x * w);       R[8] = 1.f - 2.f * (x * x + y * y);
}

static __device__ __forceinline__ void qmul(const float a[4], const float b[4], float o[4]) {
  float x1 = a[0], y1 = a[1], z1 = a[2], w1 = a[3];
  float x2 = b[0], y2 = b[1], z2 = b[2], w2 = b[3];
  o[0] = w1 * x2 + x1 * w2 + y1 * z2 - z1 * y2;
  o[1] = w1 * y2 - x1 * z2 + y1 * w2 + z1 * x2;
  o[2] = w1 * z2 + x1 * y2 - y1 * x2 + z1 * w2;
  o[3] = w1 * w2 - x1 * x2 - y1 * y2 - z1 * z2;
}

// C = A @ B
static __device__ __forceinline__ void mm(const float A[9], const float B[9], float C[9]) {
#pragma unroll
  for (int i = 0; i < 3; i++)
#pragma unroll
    for (int j = 0; j < 3; j++)
      C[3 * i + j] = A[3 * i + 0] * B[0 + j] + A[3 * i + 1] * B[3 + j] + A[3 * i + 2] * B[6 + j];
}
// C = A @ B^T
static __device__ __forceinline__ void mmT(const float A[9], const float B[9], float C[9]) {
#pragma unroll
  for (int i = 0; i < 3; i++)
#pragma unroll
    for (int j = 0; j < 3; j++)
      C[3 * i + j] = A[3 * i + 0] * B[3 * j + 0] + A[3 * i + 1] * B[3 * j + 1] + A[3 * i + 2] * B[3 * j + 2];
}
// C = A^T @ B
static __device__ __forceinline__ void mTm(const float A[9], const float B[9], float C[9]) {
#pragma unroll
  for (int i = 0; i < 3; i++)
#pragma unroll
    for (int j = 0; j < 3; j++)
      C[3 * i + j] = A[0 + i] * B[0 + j] + A[3 + i] * B[3 + j] + A[6 + i] * B[6 + j];
}

static __device__ __forceinline__ void expand6(const float c[6], float f[9]) {
  f[0] = c[0]; f[1] = c[1]; f[2] = c[2];
  f[3] = c[1]; f[4] = c[3]; f[5] = c[4];
  f[6] = c[2]; f[7] = c[4]; f[8] = c[5];
}

// sym index tables: entries (0,0),(0,1),(0,2),(1,1),(1,2),(2,2)
__device__ __constant__ const int SI6[6] = {0, 0, 0, 1, 1, 2};
__device__ __constant__ const int SJ6[6] = {0, 1, 2, 1, 2, 2};

// One IMU step in hat frame. Ro = R(s.q) carried; gb = body-frame gravity carried.
// Taylor forms valid for |phi| <~ 0.05 rad (data: <= ~0.02), err ~1e-10.
static __device__ __forceinline__ void step(Seg& s, float Ro[9], float gb[3], float dtv,
                                            float omx, float omy, float omz,
                                            float acx, float acy, float acz) {
  float px = omx * dtv, py = omy * dtv, pz = omz * dtv;
  float t2 = px * px + py * py + pz * pz;
  float s_ = 0.5f - t2 * (1.0f / 48.0f);
  float qd[4] = {px * s_, py * s_, pz * s_, 1.0f - 0.125f * t2};

  float Rd[9]; q2m(qd, Rd);
  float qn[4]; qmul(s.q, qd, qn);
  float Rn[9]; q2m(qn, Rn);

  // gb' = Rd^T gb  (gravity in new body frame)
  float gbn[3];
#pragma unroll
  for (int i = 0; i < 3; i++)
    gbn[i] = Rd[0 + i] * gb[0] + Rd[3 + i] * gb[1] + Rd[6 + i] * gb[2];
  // Ra = Ro * (acc - gb')
  float bx = acx - gbn[0], by = acy - gbn[1], bz = acz - gbn[2];
  float Ra[3];
#pragma unroll
  for (int i = 0; i < 3; i++)
    Ra[i] = Ro[3 * i + 0] * bx + Ro[3 * i + 1] * by + Ro[3 * i + 2] * bz;

  float hdt = 0.5f * dtv;
  float hdt2 = hdt * dtv;
#pragma unroll
  for (int i = 0; i < 3; i++) s.dp[i] += s.dv[i] * dtv + Ra[i] * hdt2;
#pragma unroll
  for (int i = 0; i < 3; i++) s.dv[i] += Ra[i] * dtv;

  // M = -dt * (Rn @ skew(acc))
  float M[9];
#pragma unroll
  for (int i = 0; i < 3; i++) {
    M[3 * i + 0] = -dtv * (Rn[3 * i + 1] * acz - Rn[3 * i + 2] * acy);
    M[3 * i + 1] = -dtv * (-Rn[3 * i + 0] * acz + Rn[3 * i + 2] * acx);
    M[3 * i + 2] = -dtv * (Rn[3 * i + 0] * acy - Rn[3 * i + 1] * acx);
  }

  // TP = M @ Ro^T (shared by Phi blocks AND hat-cov updates)
  float TP[9]; mmT(M, Ro, TP);
#pragma unroll
  for (int k = 0; k < 9; k++) s.P20[k] += hdt * TP[k] + dtv * s.P10[k];
#pragma unroll
  for (int k = 0; k < 9; k++) s.P10[k] += TP[k];

  // ---- hat-frame covariance ----
  float C00f[9]; expand6(s.c00, C00f);

  // W01 = ^c00 @ TP^T ; Y-blocks from OLD ^c01/^c02
  float W01[9]; mmT(C00f, TP, W01);
  float Y0h[9]; mm(TP, C00f, Y0h);
  float Y1h[9]; mm(TP, s.c01, Y1h);
  float Y2h[9]; mm(TP, s.c02, Y2h);

  // Wm = TP ^c00 TP^T (sym)
  float Wm6[6];
#pragma unroll
  for (int s6 = 0; s6 < 6; s6++) {
    const int i = SI6[s6], j = SJ6[s6];
    Wm6[s6] = Y0h[3 * i + 0] * TP[3 * j + 0] + Y0h[3 * i + 1] * TP[3 * j + 1] + Y0h[3 * i + 2] * TP[3 * j + 2];
  }
  float WmF[9]; expand6(Wm6, WmF);

  // ^c02' = hdt*(W01 + 2*^c01) + ^c02 ; then ^c01' = ^c01 + W01
#pragma unroll
  for (int k = 0; k < 9; k++) s.c02[k] += hdt * (W01[k] + 2.0f * s.c01[k]);
#pragma unroll
  for (int k = 0; k < 9; k++) s.c01[k] += W01[k];

  // ^c00' = ^c00 + sg*dt^2*(alpha I + beta p^ p^^T), p^ = Rn p
  {
    float ph[3];
#pragma unroll
    for (int i = 0; i < 3; i++)
      ph[i] = Rn[3 * i + 0] * px + Rn[3 * i + 1] * py + Rn[3 * i + 2] * pz;
    float sgdt2 = SIG_G2_C * dtv * dtv;
    float a_ = sgdt2 * (1.0f - t2 * (1.0f / 12.0f));
    float b_ = sgdt2 * ((1.0f / 12.0f) - t2 * (1.0f / 36.0f));
#pragma unroll
    for (int s6 = 0; s6 < 6; s6++) {
      const int i = SI6[s6], j = SJ6[s6];
      float v = s.c00[s6] + b_ * ph[i] * ph[j];
      if (i == j) v += a_;
      s.c00[s6] = v;
    }
  }

  float C11f[9]; expand6(s.c11, C11f);
  // c11pre = Wm + Y1 + Y1^T + c11_old (sym, pre-noise)
  float c11p[9];
#pragma unroll
  for (int i = 0; i < 3; i++)
#pragma unroll
    for (int j = 0; j < 3; j++)
      c11p[3 * i + j] = WmF[3 * i + j] + Y1h[3 * i + j] + Y1h[3 * j + i] + C11f[3 * i + j];

  // c12pre = hdt*(c11p + Y1 + c11_old) + Y2 + c12_old
  float c12p[9];
#pragma unroll
  for (int i = 0; i < 3; i++)
#pragma unroll
    for (int j = 0; j < 3; j++)
      c12p[3 * i + j] = hdt * (c11p[3 * i + j] + Y1h[3 * i + j] + C11f[3 * i + j])
                      + Y2h[3 * i + j] + s.c12[3 * i + j];

  float dt2v = dtv * dtv;
  // c22' = c22 + hdt*(c12p+c12p^T+c12+c12^T) - hdt^2*(c11p - c11_old) + noise
  float nh2 = -hdt * hdt;
#pragma unroll
  for (int s6 = 0; s6 < 6; s6++) {
    const int i = SI6[s6], j = SJ6[s6];
    float v = s.c22[s6]
            + hdt * (c12p[3 * i + j] + c12p[3 * j + i] + s.c12[3 * i + j] + s.c12[3 * j + i])
            + nh2 * (c11p[3 * i + j] - C11f[3 * i + j]);
    if (i == j) v += SIG_A2_C * 0.25f * dt2v * dt2v;
    s.c22[s6] = v;
  }
  // c12 = c12p + noise diag
#pragma unroll
  for (int i = 0; i < 3; i++)
#pragma unroll
    for (int j = 0; j < 3; j++) {
      float v = c12p[3 * i + j];
      if (i == j) v += SIG_A2_C * hdt * dt2v;
      s.c12[3 * i + j] = v;
    }
  // c11 = c11p + noise diag
#pragma unroll
  for (int s6 = 0; s6 < 6; s6++) {
    const int i = SI6[s6], j = SJ6[s6];
    float v = c11p[3 * i + j];
    if (i == j) v += SIG_A2_C * dt2v;
    s.c11[s6] = v;
  }

  // commit
#pragma unroll
  for (int i = 0; i < 4; i++) s.q[i] = qn[i];
#pragma unroll
  for (int k = 0; k < 9; k++) Ro[k] = Rn[k];
#pragma unroll
  for (int i = 0; i < 3; i++) gb[i] = gbn[i];
  s.t += dtv;
}

template <int CNT>
static __device__ __forceinline__ void shsel(const float* v, int d, bool rt, float* X, float* Y) {
#pragma unroll
  for (int i = 0; i < CNT; i++) {
    float o = __shfl_xor(v[i], d, 64);
    X[i] = rt ? o : v[i];
    Y[i] = rt ? v[i] : o;
  }
}

// Compose partner segments across lanes: result = X (earlier) then Y (later).
// (verified in R3-R5, unchanged)
static __device__ __forceinline__ void compose(Seg& s, int d, int lane) {
  bool rt = (lane & d) != 0;

  float RX[9], RY[9], tY;
  {
    float xq[4], yq[4];
    shsel<4>(s.q, d, rt, xq, yq);
    float ot = __shfl_xor(s.t, d, 64);
    tY = rt ? s.t : ot;
    s.t = s.t + ot;
    q2m(xq, RX); q2m(yq, RY);
    qmul(xq, yq, s.q);
  }

  {
    float xu[3], yu[3], xw[3], yw[3];
    shsel<3>(s.dv, d, rt, xu, yu);
    shsel<3>(s.dp, d, rt, xw, yw);
#pragma unroll
    for (int i = 0; i < 3; i++)
      s.dp[i] = xw[i] + tY * xu[i] + RX[3 * i + 0] * yw[0] + RX[3 * i + 1] * yw[1] + RX[3 * i + 2] * yw[2];
#pragma unroll
    for (int i = 0; i < 3; i++)
      s.dv[i] = xu[i] + RX[3 * i + 0] * yu[0] + RX[3 * i + 1] * yu[1] + RX[3 * i + 2] * yu[2];
  }

  float M20[9], M10[9];
  {
    float xP20[9], yP20[9], xP10[9], yP10[9];
    shsel<9>(s.P20, d, rt, xP20, yP20);
    shsel<9>(s.P10, d, rt, xP10, yP10);
    float T[9];
    mm(RX, yP20, M20); mmT(M20, RX, T);
#pragma unroll
    for (int k = 0; k < 9; k++) s.P20[k] = xP20[k] + tY * xP10[k] + T[k];
    mm(RX, yP10, M10); mmT(M10, RX, T);
#pragma unroll
    for (int k = 0; k < 9; k++) s.P10[k] = xP10[k] + T[k];
  }

  float B0[9], U1[9], U2[9];
  {
    float x00[6], y00[6];
    shsel<6>(s.c00, d, rt, x00, y00);
    float X00f[9]; expand6(x00, X00f);
    mTm(RY, X00f, B0);
    mm(M10, X00f, U1);
    mm(M20, X00f, U2);
#pragma unroll
    for (int s6 = 0; s6 < 6; s6++) {
      const int i = SI6[s6], j = SJ6[s6];
      s.c00[s6] = B0[3 * i + 0] * RY[0 + j] + B0[3 * i + 1] * RY[3 + j] + B0[3 * i + 2] * RY[6 + j] + y00[s6];
    }
  }

  float V1[9], V2[9], B1[9];
  {
    float x01[9], y01[9];
    shsel<9>(s.c01, d, rt, x01, y01);
    mTm(RY, x01, B1);
    mm(M10, x01, V1);
    mm(M20, x01, V2);
    float T1[9]; mmT(B0, M10, T1);
    float T2[9]; mmT(y01, RX, T2);
#pragma unroll
    for (int k = 0; k < 9; k++) s.c01[k] = T1[k] + B1[k] + T2[k];
  }

  float W1[9], W2[9];
  {
    float x02[9], y02[9];
    shsel<9>(s.c02, d, rt, x02, y02);
    float B2[9]; mTm(RY, x02, B2);
    mm(M10, x02, W1);
    mm(M20, x02, W2);
    float T1[9]; mmT(B0, M20, T1);
    float T2[9]; mmT(y02, RX, T2);
#pragma unroll
    for (int k = 0; k < 9; k++) s.c02[k] = T1[k] + tY * B1[k] + B2[k] + T2[k];
  }

  float x11[6], y11[6], x12[9], y12[9];
  shsel<6>(s.c11, d, rt, x11, y11);
  shsel<9>(s.c12, d, rt, x12, y12);
  float X11f[9]; expand6(x11, X11f);

  {
    float x22[6], y22[6];
    shsel<6>(s.c22, d, rt, x22, y22);
    float Ta[9]; mmT(U2, M20, Ta);
    float A5[9];
    {
      float Y22f[9]; expand6(y22, Y22f);
      mm(RX, Y22f, A5);
    }
#pragma unroll
    for (int s6 = 0; s6 < 6; s6++) {
      const int i = SI6[s6], j = SJ6[s6];
      float cj = A5[3 * i + 0] * RX[3 * j + 0] + A5[3 * i + 1] * RX[3 * j + 1] + A5[3 * i + 2] * RX[3 * j + 2];
      s.c22[s6] = Ta[3 * i + j] + tY * (V2[3 * i + j] + V2[3 * j + i])
                + (W2[3 * i + j] + W2[3 * j + i]) + tY * tY * X11f[3 * i + j]
                + tY * (x12[3 * i + j] + x12[3 * j + i]) + x22[s6] + cj;
    }
  }
  {
    float Tb[9]; mmT(U1, M20, Tb);
    float C4[9];
    {
      float A4[9]; mm(RX, y12, A4);
      mmT(A4, RX, C4);
    }
#pragma unroll
    for (int i = 0; i < 3; i++)
#pragma unroll
      for (int j = 0; j < 3; j++)
        s.c12[3 * i + j] = Tb[3 * i + j] + tY * V1[3 * i + j] + W1[3 * i + j] + V2[3 * j + i]
                         + tY * X11f[3 * i + j] + x12[3 * i + j] + C4[3 * i + j];
  }
  {
    float Tc[9]; mmT(U1, M10, Tc);
    float A3[9];
    {
      float Y11f[9]; expand6(y11, Y11f);
      mm(RX, Y11f, A3);
    }
#pragma unroll
    for (int s6 = 0; s6 < 6; s6++) {
      const int i = SI6[s6], j = SJ6[s6];
      float cj = A3[3 * i + 0] * RX[3 * j + 0] + A3[3 * i + 1] * RX[3 * j + 1] + A3[3 * i + 2] * RX[3 * j + 2];
      s.c11[s6] = Tc[3 * i + j] + V1[3 * i + j] + V1[3 * j + i] + x11[s6] + cj;
    }
  }
}

__global__ __launch_bounds__(256, 1) void imu_kernel(
    const float* __restrict__ dt, const float* __restrict__ ang, const float* __restrict__ acc,
    const float* __restrict__ pos0, const float* __restrict__ vel0, const float* __restrict__ rot0,
    float* __restrict__ out, int B, int N) {
  int lane = threadIdx.x & 63;
  int wave = threadIdx.x >> 6;
  int b = blockIdx.x * 4 + wave;
  if (b >= B) return;
  int chunk = N >> 6; // 16 steps per lane

  long base = (long)b * N + (long)lane * chunk;
  const float* dtp = dt + base;
  const float* angp = ang + base * 3;
  const float* accp = acc + base * 3;

  // ---- pre-pass: chunk rotation product (float4 loads, Taylor exp) ----
  float qc[4] = {0.f, 0.f, 0.f, 1.f};
#pragma unroll 1
  for (int jb = 0; jb < (chunk >> 2); ++jb) {
    float4 d4 = *reinterpret_cast<const float4*>(dtp + jb * 4);
    float4 g0 = *reinterpret_cast<const float4*>(angp + jb * 12 + 0);
    float4 g1 = *reinterpret_cast<const float4*>(angp + jb * 12 + 4);
    float4 g2 = *reinterpret_cast<const float4*>(angp + jb * 12 + 8);
    float dd[4] = {d4.x, d4.y, d4.z, d4.w};
    float gg[12] = {g0.x, g0.y, g0.z, g0.w, g1.x, g1.y, g1.z, g1.w, g2.x, g2.y, g2.z, g2.w};
#pragma unroll
    for (int u = 0; u < 4; ++u) {
      float dtv = dd[u];
      float px = gg[3 * u + 0] * dtv, py = gg[3 * u + 1] * dtv, pz = gg[3 * u + 2] * dtv;
      float t2 = px * px + py * py + pz * pz;
      float s_ = 0.5f - t2 * (1.0f / 48.0f);
      float qd[4] = {px * s_, py * s_, pz * s_, 1.0f - 0.125f * t2};
      float qn[4]; qmul(qc, qd, qn);
      qc[0] = qn[0]; qc[1] = qn[1]; qc[2] = qn[2]; qc[3] = qn[3];
    }
  }
  // inclusive shuffle-up scan (non-commutative: earlier on the left)
#pragma unroll
  for (int d = 1; d < 64; d <<= 1) {
    float o0 = __shfl_up(qc[0], d, 64);
    float o1 = __shfl_up(qc[1], d, 64);
    float o2 = __shfl_up(qc[2], d, 64);
    float o3 = __shfl_up(qc[3], d, 64);
    if (lane >= d) {
      float oq[4] = {o0, o1, o2, o3};
      float nn[4]; qmul(oq, qc, nn);
      qc[0] = nn[0]; qc[1] = nn[1]; qc[2] = nn[2]; qc[3] = nn[3];
    }
  }
  // exclusive prefix Q
  float Q[4];
  Q[0] = __shfl_up(qc[0], 1, 64);
  Q[1] = __shfl_up(qc[1], 1, 64);
  Q[2] = __shfl_up(qc[2], 1, 64);
  Q[3] = __shfl_up(qc[3], 1, 64);
  if (lane == 0) { Q[0] = 0.f; Q[1] = 0.f; Q[2] = 0.f; Q[3] = 1.f; }

  // per-lane constant gravity in chunk-start frame: g_l = R(Q)^T R0^T g
  float r0q[4] = {rot0[b * 4 + 0], rot0[b * 4 + 1], rot0[b * 4 + 2], rot0[b * 4 + 3]};
  float g_l[3];
  {
    float R0[9]; q2m(r0q, R0);
    float gp[3] = {R0[6] * GRAVITY_C, R0[7] * GRAVITY_C, R0[8] * GRAVITY_C}; // R0^T g
    float RQ[9]; q2m(Q, RQ);
#pragma unroll
    for (int i = 0; i < 3; i++)
      g_l[i] = RQ[0 + i] * gp[0] + RQ[3 + i] * gp[1] + RQ[6 + i] * gp[2];
  }

  Seg s = {};
  s.q[3] = 1.0f;
  float Ro[9] = {1.f, 0.f, 0.f, 0.f, 1.f, 0.f, 0.f, 0.f, 1.f};
  float gb[3] = {g_l[0], g_l[1], g_l[2]};

  // ---- phase 1: sequential integration, 4 steps per float4-load block ----
#pragma unroll 1
  for (int jb = 0; jb < (chunk >> 2); ++jb) {
    float4 d4 = *reinterpret_cast<const float4*>(dtp + jb * 4);
    float4 g0 = *reinterpret_cast<const float4*>(angp + jb * 12 + 0);
    float4 g1 = *reinterpret_cast<const float4*>(angp + jb * 12 + 4);
    float4 g2 = *reinterpret_cast<const float4*>(angp + jb * 12 + 8);
    float4 a0 = *reinterpret_cast<const float4*>(accp + jb * 12 + 0);
    float4 a1 = *reinterpret_cast<const float4*>(accp + jb * 12 + 4);
    float4 a2 = *reinterpret_cast<const float4*>(accp + jb * 12 + 8);
    step(s, Ro, gb, d4.x, g0.x, g0.y, g0.z, a0.x, a0.y, a0.z);
    step(s, Ro, gb, d4.y, g0.w, g1.x, g1.y, a0.w, a1.x, a1.y);
    step(s, Ro, gb, d4.z, g1.z, g1.w, g2.x, a1.z, a1.w, a2.x);
    step(s, Ro, gb, d4.w, g2.y, g2.z, g2.w, a2.y, a2.z, a2.w);
  }

  // ---- un-hat: c00 = Ro^T ^c00 Ro, c01 = Ro^T ^c01, c02 = Ro^T ^c02 ----
  {
    float C00f[9]; expand6(s.c00, C00f);
    float T1[9]; mTm(Ro, C00f, T1);
    float T2[9]; mm(T1, Ro, T2);
    s.c00[0] = T2[0]; s.c00[1] = T2[1]; s.c00[2] = T2[2];
    s.c00[3] = T2[4]; s.c00[4] = T2[5]; s.c00[5] = T2[8];
    float T3[9]; mTm(Ro, s.c01, T3);
#pragma unroll
    for (int k = 0; k < 9; k++) s.c01[k] = T3[k];
    float T4[9]; mTm(Ro, s.c02, T4);
#pragma unroll
    for (int k = 0; k < 9; k++) s.c02[k] = T4[k];
  }

  // ---- phase 2: non-commutative butterfly reduction over 64 chunks ----
#pragma unroll 1
  for (int d = 1; d < 64; d <<= 1) compose(s, d, lane);

  if (lane == 0) {
    float p0[3] = {pos0[b * 3 + 0], pos0[b * 3 + 1], pos0[b * 3 + 2]};
    float v0[3] = {vel0[b * 3 + 0], vel0[b * 3 + 1], vel0[b * 3 + 2]};
    float R0[9]; q2m(r0q, R0);
    float qo[4]; qmul(r0q, s.q, qo);
#pragma unroll
    for (int i = 0; i < 4; i++) out[b * 4 + i] = qo[i];
#pragma unroll
    for (int i = 0; i < 3; i++) {
      float vv = v0[i] + R0[3 * i + 0] * s.dv[0] + R0[3 * i + 1] * s.dv[1] + R0[3 * i + 2] * s.dv[2];
      float pv = p0[i] + v0[i] * s.t + R0[3 * i + 0] * s.dp[0] + R0[3 * i + 1] * s.dp[1] + R0[3 * i + 2] * s.dp[2];
      out[4 * B + b * 3 + i] = vv;
      out[7 * B + b * 3 + i] = pv;
    }
    long cb = 10L * B + (long)b * 81;
    float C00f[9], C11f[9], C22f[9];
    expand6(s.c00, C00f); expand6(s.c11, C11f); expand6(s.c22, C22f);
#pragma unroll
    for (int i = 0; i < 3; i++)
#pragma unroll
      for (int j = 0; j < 3; j++) {
        out[cb + i * 9 + j]           = C00f[3 * i + j];
        out[cb + i * 9 + (j + 3)]     = s.c01[3 * i + j];
        out[cb + i * 9 + (j + 6)]     = s.c02[3 * i + j];
        out[cb + (i + 3) * 9 + j]     = s.c01[3 * j + i];
        out[cb + (i + 3) * 9 + j + 3] = C11f[3 * i + j];
        out[cb + (i + 3) * 9 + j + 6] = s.c12[3 * i + j];
        out[cb + (i + 6) * 9 + j]     = s.c02[3 * j + i];
        out[cb + (i + 6) * 9 + j + 3] = s.c12[3 * j + i];
        out[cb + (i + 6) * 9 + j + 6] = C22f[3 * i + j];
      }
  }
}

extern "C" void kernel_launch(void* const* d_in, const int* in_sizes, int n_in,
                              void* d_out, int out_size, void* d_ws, size_t ws_size,
                              hipStream_t stream) {
  const float* dt   = (const float*)d_in[0];
  const float* ang  = (const float*)d_in[1];
  const float* acc  = (const float*)d_in[2];
  const float* pos0 = (const float*)d_in[3];
  const float* vel0 = (const float*)d_in[4];
  const float* rot0 = (const float*)d_in[5];
  int B = in_sizes[5] / 4;
  int N = in_sizes[0] / B;
  float* out = (float*)d_out;
  dim3 grid((B + 3) / 4), block(256);
  imu_kernel<<<grid, block, 0, stream>>>(dt, ang, acc, pos0, vel0, rot0, out, B, N);
}

// Round 7
// 82.833 us; speedup vs baseline: 11.7307x; 1.1456x over previous
//
#include <hip/hip_runtime.h>
#include <math.h>

#define GRAVITY_C 9.81007f
#define SIG_G2_C (1.6968e-4f * 1.6968e-4f)
#define SIG_A2_C (2.0e-3f * 2.0e-3f)

// Segment summary (74 floats). Phase 1 keeps cov blocks in "hat" (chunk-start)
// frame; after phase 1 every block is rotated into the SEQUENCE-START frame
// ("global"), where composition is rotation-free:
//   A_g = [[I,0,0],[N1,I,0],[N2, tY I, I]],  cov_XY = A_g covX A_g^T + covY,
//   P10/dv additive, P20/dp additive + tY coupling.
struct Seg {
  float q[4];            // segment delta-rotation quat (xyzw)
  float t;               // accumulated time
  float dv[3], dp[3];    // true deltas (gravity included)
  float P10[9], P20[9];  // Phi(1,0), Phi(2,0) blocks
  float c00[6], c01[9], c02[9], c11[6], c12[9], c22[6]; // sym cov blocks
};

static __device__ __forceinline__ void q2m(const float q[4], float R[9]) {
  float x = q[0], y = q[1], z = q[2], w = q[3];
  R[0] = 1.f - 2.f * (y * y + z * z); R[1] = 2.f * (x * y - z * w);       R[2] = 2.f * (x * z + y * w);
  R[3] = 2.f * (x * y + z * w);       R[4] = 1.f - 2.f * (x * x + z * z); R[5] = 2.f * (y * z - x * w);
  R[6] = 2.f * (x * z - y * w);       R[7] = 2.f * (y * z + x * w);       R[8] = 1.f - 2.f * (x * x + y * y);
}

static __device__ __forceinline__ void qmul(const float a[4], const float b[4], float o[4]) {
  float x1 = a[0], y1 = a[1], z1 = a[2], w1 = a[3];
  float x2 = b[0], y2 = b[1], z2 = b[2], w2 = b[3];
  o[0] = w1 * x2 + x1 * w2 + y1 * z2 - z1 * y2;
  o[1] = w1 * y2 - x1 * z2 + y1 * w2 + z1 * x2;
  o[2] = w1 * z2 + x1 * y2 - y1 * x2 + z1 * w2;
  o[3] = w1 * w2 - x1 * x2 - y1 * y2 - z1 * z2;
}

// C = A @ B
static __device__ __forceinline__ void mm(const float A[9], const float B[9], float C[9]) {
#pragma unroll
  for (int i = 0; i < 3; i++)
#pragma unroll
    for (int j = 0; j < 3; j++)
      C[3 * i + j] = A[3 * i + 0] * B[0 + j] + A[3 * i + 1] * B[3 + j] + A[3 * i + 2] * B[6 + j];
}
// C = A @ B^T
static __device__ __forceinline__ void mmT(const float A[9], const float B[9], float C[9]) {
#pragma unroll
  for (int i = 0; i < 3; i++)
#pragma unroll
    for (int j = 0; j < 3; j++)
      C[3 * i + j] = A[3 * i + 0] * B[3 * j + 0] + A[3 * i + 1] * B[3 * j + 1] + A[3 * i + 2] * B[3 * j + 2];
}
// C = A^T @ B
static __device__ __forceinline__ void mTm(const float A[9], const float B[9], float C[9]) {
#pragma unroll
  for (int i = 0; i < 3; i++)
#pragma unroll
    for (int j = 0; j < 3; j++)
      C[3 * i + j] = A[0 + i] * B[0 + j] + A[3 + i] * B[3 + j] + A[6 + i] * B[6 + j];
}

static __device__ __forceinline__ void expand6(const float c[6], float f[9]) {
  f[0] = c[0]; f[1] = c[1]; f[2] = c[2];
  f[3] = c[1]; f[4] = c[3]; f[5] = c[4];
  f[6] = c[2]; f[7] = c[4]; f[8] = c[5];
}

// sym index tables: entries (0,0),(0,1),(0,2),(1,1),(1,2),(2,2)
__device__ __constant__ const int SI6[6] = {0, 0, 0, 1, 1, 2};
__device__ __constant__ const int SJ6[6] = {0, 1, 2, 1, 2, 2};

// One IMU step in hat frame (verified R6). Y0h = W01^T reuse added.
static __device__ __forceinline__ void step(Seg& s, float Ro[9], float gb[3], float dtv,
                                            float omx, float omy, float omz,
                                            float acx, float acy, float acz) {
  float px = omx * dtv, py = omy * dtv, pz = omz * dtv;
  float t2 = px * px + py * py + pz * pz;
  float s_ = 0.5f - t2 * (1.0f / 48.0f);
  float qd[4] = {px * s_, py * s_, pz * s_, 1.0f - 0.125f * t2};

  float Rd[9]; q2m(qd, Rd);
  float qn[4]; qmul(s.q, qd, qn);
  float Rn[9]; q2m(qn, Rn);

  // gb' = Rd^T gb
  float gbn[3];
#pragma unroll
  for (int i = 0; i < 3; i++)
    gbn[i] = Rd[0 + i] * gb[0] + Rd[3 + i] * gb[1] + Rd[6 + i] * gb[2];
  float bx = acx - gbn[0], by = acy - gbn[1], bz = acz - gbn[2];
  float Ra[3];
#pragma unroll
  for (int i = 0; i < 3; i++)
    Ra[i] = Ro[3 * i + 0] * bx + Ro[3 * i + 1] * by + Ro[3 * i + 2] * bz;

  float hdt = 0.5f * dtv;
  float hdt2 = hdt * dtv;
#pragma unroll
  for (int i = 0; i < 3; i++) s.dp[i] += s.dv[i] * dtv + Ra[i] * hdt2;
#pragma unroll
  for (int i = 0; i < 3; i++) s.dv[i] += Ra[i] * dtv;

  // M = -dt * (Rn @ skew(acc))
  float M[9];
#pragma unroll
  for (int i = 0; i < 3; i++) {
    M[3 * i + 0] = -dtv * (Rn[3 * i + 1] * acz - Rn[3 * i + 2] * acy);
    M[3 * i + 1] = -dtv * (-Rn[3 * i + 0] * acz + Rn[3 * i + 2] * acx);
    M[3 * i + 2] = -dtv * (Rn[3 * i + 0] * acy - Rn[3 * i + 1] * acx);
  }

  // TP = M @ Ro^T (shared)
  float TP[9]; mmT(M, Ro, TP);
#pragma unroll
  for (int k = 0; k < 9; k++) s.P20[k] += hdt * TP[k] + dtv * s.P10[k];
#pragma unroll
  for (int k = 0; k < 9; k++) s.P10[k] += TP[k];

  // ---- hat-frame covariance ----
  float C00f[9]; expand6(s.c00, C00f);

  // W01 = ^c00 @ TP^T ; Y0h = TP ^c00 = W01^T (c00 sym)
  float W01[9]; mmT(C00f, TP, W01);
  float Y1h[9]; mm(TP, s.c01, Y1h);
  float Y2h[9]; mm(TP, s.c02, Y2h);

  // Wm = TP ^c00 TP^T (sym): row i of (TP c00) is col i of W01
  float Wm6[6];
#pragma unroll
  for (int s6 = 0; s6 < 6; s6++) {
    const int i = SI6[s6], j = SJ6[s6];
    Wm6[s6] = W01[0 + i] * TP[3 * j + 0] + W01[3 + i] * TP[3 * j + 1] + W01[6 + i] * TP[3 * j + 2];
  }
  float WmF[9]; expand6(Wm6, WmF);

  // ^c02' = hdt*(W01 + 2*^c01) + ^c02 ; then ^c01' += W01
#pragma unroll
  for (int k = 0; k < 9; k++) s.c02[k] += hdt * (W01[k] + 2.0f * s.c01[k]);
#pragma unroll
  for (int k = 0; k < 9; k++) s.c01[k] += W01[k];

  // ^c00' += sg*dt^2*(alpha I + beta p^ p^^T), p^ = Rn p
  {
    float ph[3];
#pragma unroll
    for (int i = 0; i < 3; i++)
      ph[i] = Rn[3 * i + 0] * px + Rn[3 * i + 1] * py + Rn[3 * i + 2] * pz;
    float sgdt2 = SIG_G2_C * dtv * dtv;
    float a_ = sgdt2 * (1.0f - t2 * (1.0f / 12.0f));
    float b_ = sgdt2 * ((1.0f / 12.0f) - t2 * (1.0f / 36.0f));
#pragma unroll
    for (int s6 = 0; s6 < 6; s6++) {
      const int i = SI6[s6], j = SJ6[s6];
      float v = s.c00[s6] + b_ * ph[i] * ph[j];
      if (i == j) v += a_;
      s.c00[s6] = v;
    }
  }

  float C11f[9]; expand6(s.c11, C11f);
  float c11p[9];
#pragma unroll
  for (int i = 0; i < 3; i++)
#pragma unroll
    for (int j = 0; j < 3; j++)
      c11p[3 * i + j] = WmF[3 * i + j] + Y1h[3 * i + j] + Y1h[3 * j + i] + C11f[3 * i + j];

  float c12p[9];
#pragma unroll
  for (int i = 0; i < 3; i++)
#pragma unroll
    for (int j = 0; j < 3; j++)
      c12p[3 * i + j] = hdt * (c11p[3 * i + j] + Y1h[3 * i + j] + C11f[3 * i + j])
                      + Y2h[3 * i + j] + s.c12[3 * i + j];

  float dt2v = dtv * dtv;
  float nh2 = -hdt * hdt;
#pragma unroll
  for (int s6 = 0; s6 < 6; s6++) {
    const int i = SI6[s6], j = SJ6[s6];
    float v = s.c22[s6]
            + hdt * (c12p[3 * i + j] + c12p[3 * j + i] + s.c12[3 * i + j] + s.c12[3 * j + i])
            + nh2 * (c11p[3 * i + j] - C11f[3 * i + j]);
    if (i == j) v += SIG_A2_C * 0.25f * dt2v * dt2v;
    s.c22[s6] = v;
  }
#pragma unroll
  for (int i = 0; i < 3; i++)
#pragma unroll
    for (int j = 0; j < 3; j++) {
      float v = c12p[3 * i + j];
      if (i == j) v += SIG_A2_C * hdt * dt2v;
      s.c12[3 * i + j] = v;
    }
#pragma unroll
  for (int s6 = 0; s6 < 6; s6++) {
    const int i = SI6[s6], j = SJ6[s6];
    float v = c11p[3 * i + j];
    if (i == j) v += SIG_A2_C * dt2v;
    s.c11[s6] = v;
  }

  // commit
#pragma unroll
  for (int i = 0; i < 4; i++) s.q[i] = qn[i];
#pragma unroll
  for (int k = 0; k < 9; k++) Ro[k] = Rn[k];
#pragma unroll
  for (int i = 0; i < 3; i++) gb[i] = gbn[i];
  s.t += dtv;
}

template <int CNT>
static __device__ __forceinline__ void shsel(const float* v, int d, bool rt, float* X, float* Y) {
#pragma unroll
  for (int i = 0; i < CNT; i++) {
    float o = __shfl_xor(v[i], d, 64);
    X[i] = rt ? o : v[i];
    Y[i] = rt ? v[i] : o;
  }
}

// Rotation-free global-frame compose: result = X (earlier) then Y (later).
// N1 = Y.P10_g, N2 = Y.P20_g, tY = Y.t.
static __device__ __forceinline__ void compose(Seg& s, int d, int lane) {
  bool rt = (lane & d) != 0;

  // q, t
  {
    float xq[4], yq[4];
    shsel<4>(s.q, d, rt, xq, yq);
    qmul(xq, yq, s.q);
  }
  float ot = __shfl_xor(s.t, d, 64);
  float tY = rt ? s.t : ot;
  s.t = s.t + ot;

  // dv, dp
  {
    float xu[3], yu[3], xw[3], yw[3];
    shsel<3>(s.dv, d, rt, xu, yu);
    shsel<3>(s.dp, d, rt, xw, yw);
#pragma unroll
    for (int i = 0; i < 3; i++) s.dp[i] = xw[i] + tY * xu[i] + yw[i];
#pragma unroll
    for (int i = 0; i < 3; i++) s.dv[i] = xu[i] + yu[i];
  }

  // P blocks: keep N1,N2 (Y side) for cov
  float N1[9], N2[9], xP10[9], xP20[9];
  shsel<9>(s.P10, d, rt, xP10, N1);
  shsel<9>(s.P20, d, rt, xP20, N2);

  // cov
  float x00[6], y00[6];
  shsel<6>(s.c00, d, rt, x00, y00);
  float X00f[9]; expand6(x00, X00f);
  float K1[9]; mm(N1, X00f, K1);
  float K2[9]; mm(N2, X00f, K2);
#pragma unroll
  for (int s6 = 0; s6 < 6; s6++) s.c00[s6] = x00[s6] + y00[s6];

  float x01[9], y01[9];
  shsel<9>(s.c01, d, rt, x01, y01);
  float L1[9]; mm(N1, x01, L1);
  float L2[9]; mm(N2, x01, L2);
  float x02[9], y02[9];
  shsel<9>(s.c02, d, rt, x02, y02);
  float L3[9]; mm(N1, x02, L3);
  float L4[9]; mm(N2, x02, L4);

#pragma unroll
  for (int i = 0; i < 3; i++)
#pragma unroll
    for (int j = 0; j < 3; j++) {
      s.c01[3 * i + j] = x01[3 * i + j] + K1[3 * j + i] + y01[3 * i + j];
      s.c02[3 * i + j] = x02[3 * i + j] + tY * x01[3 * i + j] + K2[3 * j + i] + y02[3 * i + j];
    }

  float x11[6], y11[6], x12[9], y12[9], x22[6], y22[6];
  shsel<6>(s.c11, d, rt, x11, y11);
  shsel<9>(s.c12, d, rt, x12, y12);
  shsel<6>(s.c22, d, rt, x22, y22);
  float X11f[9]; expand6(x11, X11f);

  // c11' = x11 + L1 + L1^T + K1 N1^T + y11
#pragma unroll
  for (int s6 = 0; s6 < 6; s6++) {
    const int i = SI6[s6], j = SJ6[s6];
    float kn = K1[3 * i + 0] * N1[3 * j + 0] + K1[3 * i + 1] * N1[3 * j + 1] + K1[3 * i + 2] * N1[3 * j + 2];
    s.c11[s6] = x11[s6] + L1[3 * i + j] + L1[3 * j + i] + kn + y11[s6];
  }
  // c12' = x12 + L3 + tY*(L1 + x11) + L2^T + K1 N2^T + y12
#pragma unroll
  for (int i = 0; i < 3; i++)
#pragma unroll
    for (int j = 0; j < 3; j++) {
      float kn = K1[3 * i + 0] * N2[3 * j + 0] + K1[3 * i + 1] * N2[3 * j + 1] + K1[3 * i + 2] * N2[3 * j + 2];
      s.c12[3 * i + j] = x12[3 * i + j] + L3[3 * i + j] + tY * (L1[3 * i + j] + X11f[3 * i + j])
                       + L2[3 * j + i] + kn + y12[3 * i + j];
    }
  // c22' = x22 + K2 N2^T + (L4+L4^T) + tY*(L2+L2^T + x12+x12^T) + tY^2*x11 + y22
  float tY2 = tY * tY;
#pragma unroll
  for (int s6 = 0; s6 < 6; s6++) {
    const int i = SI6[s6], j = SJ6[s6];
    float kn = K2[3 * i + 0] * N2[3 * j + 0] + K2[3 * i + 1] * N2[3 * j + 1] + K2[3 * i + 2] * N2[3 * j + 2];
    s.c22[s6] = x22[s6] + kn + L4[3 * i + j] + L4[3 * j + i]
              + tY * (L2[3 * i + j] + L2[3 * j + i] + x12[3 * i + j] + x12[3 * j + i])
              + tY2 * X11f[3 * i + j] + y22[s6];
  }

  // P update last
#pragma unroll
  for (int k = 0; k < 9; k++) s.P20[k] = xP20[k] + tY * xP10[k] + N2[k];
#pragma unroll
  for (int k = 0; k < 9; k++) s.P10[k] = xP10[k] + N1[k];
}

// full sandwich A <- R A R^T
static __device__ __forceinline__ void sandw(const float R[9], float A[9]) {
  float T1[9]; mm(R, A, T1);
  mmT(T1, R, A);
}

__global__ __launch_bounds__(256, 1) void imu_kernel(
    const float* __restrict__ dt, const float* __restrict__ ang, const float* __restrict__ acc,
    const float* __restrict__ pos0, const float* __restrict__ vel0, const float* __restrict__ rot0,
    float* __restrict__ out, int B, int N) {
  int lane = threadIdx.x & 63;
  int wave = threadIdx.x >> 6;
  int b = blockIdx.x * 4 + wave;
  if (b >= B) return;
  int chunk = N >> 6; // 16 steps per lane

  long base = (long)b * N + (long)lane * chunk;
  const float* dtp = dt + base;
  const float* angp = ang + base * 3;
  const float* accp = acc + base * 3;

  // ---- pre-pass: chunk rotation product (float4 loads, Taylor exp) ----
  float qc[4] = {0.f, 0.f, 0.f, 1.f};
#pragma unroll 1
  for (int jb = 0; jb < (chunk >> 2); ++jb) {
    float4 d4 = *reinterpret_cast<const float4*>(dtp + jb * 4);
    float4 g0 = *reinterpret_cast<const float4*>(angp + jb * 12 + 0);
    float4 g1 = *reinterpret_cast<const float4*>(angp + jb * 12 + 4);
    float4 g2 = *reinterpret_cast<const float4*>(angp + jb * 12 + 8);
    float dd[4] = {d4.x, d4.y, d4.z, d4.w};
    float gg[12] = {g0.x, g0.y, g0.z, g0.w, g1.x, g1.y, g1.z, g1.w, g2.x, g2.y, g2.z, g2.w};
#pragma unroll
    for (int u = 0; u < 4; ++u) {
      float dtv = dd[u];
      float px = gg[3 * u + 0] * dtv, py = gg[3 * u + 1] * dtv, pz = gg[3 * u + 2] * dtv;
      float t2 = px * px + py * py + pz * pz;
      float s_ = 0.5f - t2 * (1.0f / 48.0f);
      float qd[4] = {px * s_, py * s_, pz * s_, 1.0f - 0.125f * t2};
      float qn[4]; qmul(qc, qd, qn);
      qc[0] = qn[0]; qc[1] = qn[1]; qc[2] = qn[2]; qc[3] = qn[3];
    }
  }
  // inclusive shuffle-up scan (non-commutative)
#pragma unroll
  for (int d = 1; d < 64; d <<= 1) {
    float o0 = __shfl_up(qc[0], d, 64);
    float o1 = __shfl_up(qc[1], d, 64);
    float o2 = __shfl_up(qc[2], d, 64);
    float o3 = __shfl_up(qc[3], d, 64);
    if (lane >= d) {
      float oq[4] = {o0, o1, o2, o3};
      float nn[4]; qmul(oq, qc, nn);
      qc[0] = nn[0]; qc[1] = nn[1]; qc[2] = nn[2]; qc[3] = nn[3];
    }
  }
  // exclusive prefix Q
  float Q[4];
  Q[0] = __shfl_up(qc[0], 1, 64);
  Q[1] = __shfl_up(qc[1], 1, 64);
  Q[2] = __shfl_up(qc[2], 1, 64);
  Q[3] = __shfl_up(qc[3], 1, 64);
  if (lane == 0) { Q[0] = 0.f; Q[1] = 0.f; Q[2] = 0.f; Q[3] = 1.f; }

  float RQ[9]; q2m(Q, RQ);

  // per-lane gravity in chunk-start frame: g_l = RQ^T (R0^T g)
  float r0q[4] = {rot0[b * 4 + 0], rot0[b * 4 + 1], rot0[b * 4 + 2], rot0[b * 4 + 3]};
  float g_l[3];
  {
    float R0[9]; q2m(r0q, R0);
    float gp[3] = {R0[6] * GRAVITY_C, R0[7] * GRAVITY_C, R0[8] * GRAVITY_C};
#pragma unroll
    for (int i = 0; i < 3; i++)
      g_l[i] = RQ[0 + i] * gp[0] + RQ[3 + i] * gp[1] + RQ[6 + i] * gp[2];
  }

  Seg s = {};
  s.q[3] = 1.0f;
  float Ro[9] = {1.f, 0.f, 0.f, 0.f, 1.f, 0.f, 0.f, 0.f, 1.f};
  float gb[3] = {g_l[0], g_l[1], g_l[2]};

  // ---- phase 1 ----
#pragma unroll 1
  for (int jb = 0; jb < (chunk >> 2); ++jb) {
    float4 d4 = *reinterpret_cast<const float4*>(dtp + jb * 4);
    float4 g0 = *reinterpret_cast<const float4*>(angp + jb * 12 + 0);
    float4 g1 = *reinterpret_cast<const float4*>(angp + jb * 12 + 4);
    float4 g2 = *reinterpret_cast<const float4*>(angp + jb * 12 + 8);
    float4 a0 = *reinterpret_cast<const float4*>(accp + jb * 12 + 0);
    float4 a1 = *reinterpret_cast<const float4*>(accp + jb * 12 + 4);
    float4 a2 = *reinterpret_cast<const float4*>(accp + jb * 12 + 8);
    step(s, Ro, gb, d4.x, g0.x, g0.y, g0.z, a0.x, a0.y, a0.z);
    step(s, Ro, gb, d4.y, g0.w, g1.x, g1.y, a0.w, a1.x, a1.y);
    step(s, Ro, gb, d4.z, g1.z, g1.w, g2.x, a1.z, a1.w, a2.x);
    step(s, Ro, gb, d4.w, g2.y, g2.z, g2.w, a2.y, a2.z, a2.w);
  }

  // ---- globalize: every block -> sequence-start frame via RQ ----
  {
    // vectors
    float tv[3];
#pragma unroll
    for (int i = 0; i < 3; i++)
      tv[i] = RQ[3 * i + 0] * s.dv[0] + RQ[3 * i + 1] * s.dv[1] + RQ[3 * i + 2] * s.dv[2];
#pragma unroll
    for (int i = 0; i < 3; i++) s.dv[i] = tv[i];
#pragma unroll
    for (int i = 0; i < 3; i++)
      tv[i] = RQ[3 * i + 0] * s.dp[0] + RQ[3 * i + 1] * s.dp[1] + RQ[3 * i + 2] * s.dp[2];
#pragma unroll
    for (int i = 0; i < 3; i++) s.dp[i] = tv[i];
    // full blocks
    sandw(RQ, s.P10);
    sandw(RQ, s.P20);
    sandw(RQ, s.c01);
    sandw(RQ, s.c02);
    sandw(RQ, s.c12);
    // sym blocks
    float F[9];
    expand6(s.c00, F); sandw(RQ, F);
    s.c00[0] = F[0]; s.c00[1] = F[1]; s.c00[2] = F[2]; s.c00[3] = F[4]; s.c00[4] = F[5]; s.c00[5] = F[8];
    expand6(s.c11, F); sandw(RQ, F);
    s.c11[0] = F[0]; s.c11[1] = F[1]; s.c11[2] = F[2]; s.c11[3] = F[4]; s.c11[4] = F[5]; s.c11[5] = F[8];
    expand6(s.c22, F); sandw(RQ, F);
    s.c22[0] = F[0]; s.c22[1] = F[1]; s.c22[2] = F[2]; s.c22[3] = F[4]; s.c22[4] = F[5]; s.c22[5] = F[8];
  }

  // ---- phase 2: rotation-free butterfly ----
#pragma unroll 1
  for (int d = 1; d < 64; d <<= 1) compose(s, d, lane);

  if (lane == 0) {
    float p0[3] = {pos0[b * 3 + 0], pos0[b * 3 + 1], pos0[b * 3 + 2]};
    float v0[3] = {vel0[b * 3 + 0], vel0[b * 3 + 1], vel0[b * 3 + 2]};
    float R0[9]; q2m(r0q, R0);
    float qo[4]; qmul(r0q, s.q, qo);
#pragma unroll
    for (int i = 0; i < 4; i++) out[b * 4 + i] = qo[i];
#pragma unroll
    for (int i = 0; i < 3; i++) {
      float vv = v0[i] + R0[3 * i + 0] * s.dv[0] + R0[3 * i + 1] * s.dv[1] + R0[3 * i + 2] * s.dv[2];
      float pv = p0[i] + v0[i] * s.t + R0[3 * i + 0] * s.dp[0] + R0[3 * i + 1] * s.dp[1] + R0[3 * i + 2] * s.dp[2];
      out[4 * B + b * 3 + i] = vv;
      out[7 * B + b * 3 + i] = pv;
    }
    // convert theta-indexed blocks back to reference convention (end-body frame):
    // c00_ref = Rq^T c00_g Rq, c01_ref = Rq^T c01_g, c02_ref = Rq^T c02_g
    float Rq[9]; q2m(s.q, Rq);
    float C00f[9];
    {
      float G[9]; expand6(s.c00, G);
      float T1[9]; mTm(Rq, G, T1);
      mm(T1, Rq, C00f);
    }
    float C01f[9]; mTm(Rq, s.c01, C01f);
    float C02f[9]; mTm(Rq, s.c02, C02f);
    float C11f[9], C22f[9];
    expand6(s.c11, C11f); expand6(s.c22, C22f);

    long cb = 10L * B + (long)b * 81;
#pragma unroll
    for (int i = 0; i < 3; i++)
#pragma unroll
      for (int j = 0; j < 3; j++) {
        out[cb + i * 9 + j]           = C00f[3 * i + j];
        out[cb + i * 9 + (j + 3)]     = C01f[3 * i + j];
        out[cb + i * 9 + (j + 6)]     = C02f[3 * i + j];
        out[cb + (i + 3) * 9 + j]     = C01f[3 * j + i];
        out[cb + (i + 3) * 9 + j + 3] = C11f[3 * i + j];
        out[cb + (i + 3) * 9 + j + 6] = s.c12[3 * i + j];
        out[cb + (i + 6) * 9 + j]     = C02f[3 * j + i];
        out[cb + (i + 6) * 9 + j + 3] = s.c12[3 * j + i];
        out[cb + (i + 6) * 9 + j + 6] = C22f[3 * i + j];
      }
  }
}

extern "C" void kernel_launch(void* const* d_in, const int* in_sizes, int n_in,
                              void* d_out, int out_size, void* d_ws, size_t ws_size,
                              hipStream_t stream) {
  const float* dt   = (const float*)d_in[0];
  const float* ang  = (const float*)d_in[1];
  const float* acc  = (const float*)d_in[2];
  const float* pos0 = (const float*)d_in[3];
  const float* vel0 = (const float*)d_in[4];
  const float* rot0 = (const float*)d_in[5];
  int B = in_sizes[5] / 4;
  int N = in_sizes[0] / B;
  float* out = (float*)d_out;
  dim3 grid((B + 3) / 4), block(256);
  imu_kernel<<<grid, block, 0, stream>>>(dt, ang, acc, pos0, vel0, rot0, out, B, N);
}

// Round 8
// 76.927 us; speedup vs baseline: 12.6313x; 1.0768x over previous
//
#include <hip/hip_runtime.h>
#include <math.h>

#define GRAVITY_C 9.81007f
#define SIG_G2_C (1.6968e-4f * 1.6968e-4f)
#define SIG_A2_C (2.0e-3f * 2.0e-3f)

// Segment summary (74 floats). Phase 1 keeps cov blocks in "hat" (chunk-start)
// frame; after phase 1 every block is rotated into the SEQUENCE-START frame
// ("global"), where composition is rotation-free.
struct Seg {
  float q[4];            // segment delta-rotation quat (xyzw)
  float t;               // accumulated time
  float dv[3], dp[3];    // true deltas (gravity included)
  float P10[9], P20[9];  // Phi(1,0), Phi(2,0) blocks
  float c00[6], c01[9], c02[9], c11[6], c12[9], c22[6]; // sym cov blocks
};

static __device__ __forceinline__ void q2m(const float q[4], float R[9]) {
  float x = q[0], y = q[1], z = q[2], w = q[3];
  R[0] = 1.f - 2.f * (y * y + z * z); R[1] = 2.f * (x * y - z * w);       R[2] = 2.f * (x * z + y * w);
  R[3] = 2.f * (x * y + z * w);       R[4] = 1.f - 2.f * (x * x + z * z); R[5] = 2.f * (y * z - x * w);
  R[6] = 2.f * (x * z - y * w);       R[7] = 2.f * (y * z + x * w);       R[8] = 1.f - 2.f * (x * x + y * y);
}

static __device__ __forceinline__ void qmul(const float a[4], const float b[4], float o[4]) {
  float x1 = a[0], y1 = a[1], z1 = a[2], w1 = a[3];
  float x2 = b[0], y2 = b[1], z2 = b[2], w2 = b[3];
  o[0] = w1 * x2 + x1 * w2 + y1 * z2 - z1 * y2;
  o[1] = w1 * y2 - x1 * z2 + y1 * w2 + z1 * x2;
  o[2] = w1 * z2 + x1 * y2 - y1 * x2 + z1 * w2;
  o[3] = w1 * w2 - x1 * x2 - y1 * y2 - z1 * z2;
}

// C = A @ B
static __device__ __forceinline__ void mm(const float A[9], const float B[9], float C[9]) {
#pragma unroll
  for (int i = 0; i < 3; i++)
#pragma unroll
    for (int j = 0; j < 3; j++)
      C[3 * i + j] = A[3 * i + 0] * B[0 + j] + A[3 * i + 1] * B[3 + j] + A[3 * i + 2] * B[6 + j];
}
// C = A @ B^T
static __device__ __forceinline__ void mmT(const float A[9], const float B[9], float C[9]) {
#pragma unroll
  for (int i = 0; i < 3; i++)
#pragma unroll
    for (int j = 0; j < 3; j++)
      C[3 * i + j] = A[3 * i + 0] * B[3 * j + 0] + A[3 * i + 1] * B[3 * j + 1] + A[3 * i + 2] * B[3 * j + 2];
}
// C = A^T @ B
static __device__ __forceinline__ void mTm(const float A[9], const float B[9], float C[9]) {
#pragma unroll
  for (int i = 0; i < 3; i++)
#pragma unroll
    for (int j = 0; j < 3; j++)
      C[3 * i + j] = A[0 + i] * B[0 + j] + A[3 + i] * B[3 + j] + A[6 + i] * B[6 + j];
}

static __device__ __forceinline__ void expand6(const float c[6], float f[9]) {
  f[0] = c[0]; f[1] = c[1]; f[2] = c[2];
  f[3] = c[1]; f[4] = c[3]; f[5] = c[4];
  f[6] = c[2]; f[7] = c[4]; f[8] = c[5];
}

// sym index tables: entries (0,0),(0,1),(0,2),(1,1),(1,2),(2,2)
__device__ __constant__ const int SI6[6] = {0, 0, 0, 1, 1, 2};
__device__ __constant__ const int SJ6[6] = {0, 1, 2, 1, 2, 2};

// One IMU step in hat frame (verified R6/R7).
static __device__ __forceinline__ void step(Seg& s, float Ro[9], float gb[3], float dtv,
                                            float omx, float omy, float omz,
                                            float acx, float acy, float acz) {
  float px = omx * dtv, py = omy * dtv, pz = omz * dtv;
  float t2 = px * px + py * py + pz * pz;
  float s_ = 0.5f - t2 * (1.0f / 48.0f);
  float qd[4] = {px * s_, py * s_, pz * s_, 1.0f - 0.125f * t2};

  float Rd[9]; q2m(qd, Rd);
  float qn[4]; qmul(s.q, qd, qn);
  float Rn[9]; q2m(qn, Rn);

  // gb' = Rd^T gb
  float gbn[3];
#pragma unroll
  for (int i = 0; i < 3; i++)
    gbn[i] = Rd[0 + i] * gb[0] + Rd[3 + i] * gb[1] + Rd[6 + i] * gb[2];
  float bx = acx - gbn[0], by = acy - gbn[1], bz = acz - gbn[2];
  float Ra[3];
#pragma unroll
  for (int i = 0; i < 3; i++)
    Ra[i] = Ro[3 * i + 0] * bx + Ro[3 * i + 1] * by + Ro[3 * i + 2] * bz;

  float hdt = 0.5f * dtv;
  float hdt2 = hdt * dtv;
#pragma unroll
  for (int i = 0; i < 3; i++) s.dp[i] += s.dv[i] * dtv + Ra[i] * hdt2;
#pragma unroll
  for (int i = 0; i < 3; i++) s.dv[i] += Ra[i] * dtv;

  // M = -dt * (Rn @ skew(acc))
  float M[9];
#pragma unroll
  for (int i = 0; i < 3; i++) {
    M[3 * i + 0] = -dtv * (Rn[3 * i + 1] * acz - Rn[3 * i + 2] * acy);
    M[3 * i + 1] = -dtv * (-Rn[3 * i + 0] * acz + Rn[3 * i + 2] * acx);
    M[3 * i + 2] = -dtv * (Rn[3 * i + 0] * acy - Rn[3 * i + 1] * acx);
  }

  // TP = M @ Ro^T (shared)
  float TP[9]; mmT(M, Ro, TP);
#pragma unroll
  for (int k = 0; k < 9; k++) s.P20[k] += hdt * TP[k] + dtv * s.P10[k];
#pragma unroll
  for (int k = 0; k < 9; k++) s.P10[k] += TP[k];

  // ---- hat-frame covariance ----
  float C00f[9]; expand6(s.c00, C00f);

  // W01 = ^c00 @ TP^T
  float W01[9]; mmT(C00f, TP, W01);
  float Y1h[9]; mm(TP, s.c01, Y1h);
  float Y2h[9]; mm(TP, s.c02, Y2h);

  // Wm = TP ^c00 TP^T (sym): row i of (TP c00) is col i of W01
  float Wm6[6];
#pragma unroll
  for (int s6 = 0; s6 < 6; s6++) {
    const int i = SI6[s6], j = SJ6[s6];
    Wm6[s6] = W01[0 + i] * TP[3 * j + 0] + W01[3 + i] * TP[3 * j + 1] + W01[6 + i] * TP[3 * j + 2];
  }
  float WmF[9]; expand6(Wm6, WmF);

  // ^c02' = hdt*(W01 + 2*^c01) + ^c02 ; then ^c01' += W01
#pragma unroll
  for (int k = 0; k < 9; k++) s.c02[k] += hdt * (W01[k] + 2.0f * s.c01[k]);
#pragma unroll
  for (int k = 0; k < 9; k++) s.c01[k] += W01[k];

  // ^c00' += sg*dt^2*(alpha I + beta p^ p^^T), p^ = Rn p
  {
    float ph[3];
#pragma unroll
    for (int i = 0; i < 3; i++)
      ph[i] = Rn[3 * i + 0] * px + Rn[3 * i + 1] * py + Rn[3 * i + 2] * pz;
    float sgdt2 = SIG_G2_C * dtv * dtv;
    float a_ = sgdt2 * (1.0f - t2 * (1.0f / 12.0f));
    float b_ = sgdt2 * ((1.0f / 12.0f) - t2 * (1.0f / 36.0f));
#pragma unroll
    for (int s6 = 0; s6 < 6; s6++) {
      const int i = SI6[s6], j = SJ6[s6];
      float v = s.c00[s6] + b_ * ph[i] * ph[j];
      if (i == j) v += a_;
      s.c00[s6] = v;
    }
  }

  float C11f[9]; expand6(s.c11, C11f);
  float c11p[9];
#pragma unroll
  for (int i = 0; i < 3; i++)
#pragma unroll
    for (int j = 0; j < 3; j++)
      c11p[3 * i + j] = WmF[3 * i + j] + Y1h[3 * i + j] + Y1h[3 * j + i] + C11f[3 * i + j];

  float c12p[9];
#pragma unroll
  for (int i = 0; i < 3; i++)
#pragma unroll
    for (int j = 0; j < 3; j++)
      c12p[3 * i + j] = hdt * (c11p[3 * i + j] + Y1h[3 * i + j] + C11f[3 * i + j])
                      + Y2h[3 * i + j] + s.c12[3 * i + j];

  float dt2v = dtv * dtv;
  float nh2 = -hdt * hdt;
#pragma unroll
  for (int s6 = 0; s6 < 6; s6++) {
    const int i = SI6[s6], j = SJ6[s6];
    float v = s.c22[s6]
            + hdt * (c12p[3 * i + j] + c12p[3 * j + i] + s.c12[3 * i + j] + s.c12[3 * j + i])
            + nh2 * (c11p[3 * i + j] - C11f[3 * i + j]);
    if (i == j) v += SIG_A2_C * 0.25f * dt2v * dt2v;
    s.c22[s6] = v;
  }
#pragma unroll
  for (int i = 0; i < 3; i++)
#pragma unroll
    for (int j = 0; j < 3; j++) {
      float v = c12p[3 * i + j];
      if (i == j) v += SIG_A2_C * hdt * dt2v;
      s.c12[3 * i + j] = v;
    }
#pragma unroll
  for (int s6 = 0; s6 < 6; s6++) {
    const int i = SI6[s6], j = SJ6[s6];
    float v = c11p[3 * i + j];
    if (i == j) v += SIG_A2_C * dt2v;
    s.c11[s6] = v;
  }

  // commit
#pragma unroll
  for (int i = 0; i < 4; i++) s.q[i] = qn[i];
#pragma unroll
  for (int k = 0; k < 9; k++) Ro[k] = Rn[k];
#pragma unroll
  for (int i = 0; i < 3; i++) gb[i] = gbn[i];
  s.t += dtv;
}

template <int CNT>
static __device__ __forceinline__ void shsel(const float* v, int d, bool rt, float* X, float* Y) {
#pragma unroll
  for (int i = 0; i < CNT; i++) {
    float o = __shfl_xor(v[i], d, 64);
    X[i] = rt ? o : v[i];
    Y[i] = rt ? v[i] : o;
  }
}

// Rotation-free global-frame compose (verified R7).
static __device__ __forceinline__ void compose(Seg& s, int d, int lane) {
  bool rt = (lane & d) != 0;

  {
    float xq[4], yq[4];
    shsel<4>(s.q, d, rt, xq, yq);
    qmul(xq, yq, s.q);
  }
  float ot = __shfl_xor(s.t, d, 64);
  float tY = rt ? s.t : ot;
  s.t = s.t + ot;

  {
    float xu[3], yu[3], xw[3], yw[3];
    shsel<3>(s.dv, d, rt, xu, yu);
    shsel<3>(s.dp, d, rt, xw, yw);
#pragma unroll
    for (int i = 0; i < 3; i++) s.dp[i] = xw[i] + tY * xu[i] + yw[i];
#pragma unroll
    for (int i = 0; i < 3; i++) s.dv[i] = xu[i] + yu[i];
  }

  float N1[9], N2[9], xP10[9], xP20[9];
  shsel<9>(s.P10, d, rt, xP10, N1);
  shsel<9>(s.P20, d, rt, xP20, N2);

  float x00[6], y00[6];
  shsel<6>(s.c00, d, rt, x00, y00);
  float X00f[9]; expand6(x00, X00f);
  float K1[9]; mm(N1, X00f, K1);
  float K2[9]; mm(N2, X00f, K2);
#pragma unroll
  for (int s6 = 0; s6 < 6; s6++) s.c00[s6] = x00[s6] + y00[s6];

  float x01[9], y01[9];
  shsel<9>(s.c01, d, rt, x01, y01);
  float L1[9]; mm(N1, x01, L1);
  float L2[9]; mm(N2, x01, L2);
  float x02[9], y02[9];
  shsel<9>(s.c02, d, rt, x02, y02);
  float L3[9]; mm(N1, x02, L3);
  float L4[9]; mm(N2, x02, L4);

#pragma unroll
  for (int i = 0; i < 3; i++)
#pragma unroll
    for (int j = 0; j < 3; j++) {
      s.c01[3 * i + j] = x01[3 * i + j] + K1[3 * j + i] + y01[3 * i + j];
      s.c02[3 * i + j] = x02[3 * i + j] + tY * x01[3 * i + j] + K2[3 * j + i] + y02[3 * i + j];
    }

  float x11[6], y11[6], x12[9], y12[9], x22[6], y22[6];
  shsel<6>(s.c11, d, rt, x11, y11);
  shsel<9>(s.c12, d, rt, x12, y12);
  shsel<6>(s.c22, d, rt, x22, y22);
  float X11f[9]; expand6(x11, X11f);

#pragma unroll
  for (int s6 = 0; s6 < 6; s6++) {
    const int i = SI6[s6], j = SJ6[s6];
    float kn = K1[3 * i + 0] * N1[3 * j + 0] + K1[3 * i + 1] * N1[3 * j + 1] + K1[3 * i + 2] * N1[3 * j + 2];
    s.c11[s6] = x11[s6] + L1[3 * i + j] + L1[3 * j + i] + kn + y11[s6];
  }
#pragma unroll
  for (int i = 0; i < 3; i++)
#pragma unroll
    for (int j = 0; j < 3; j++) {
      float kn = K1[3 * i + 0] * N2[3 * j + 0] + K1[3 * i + 1] * N2[3 * j + 1] + K1[3 * i + 2] * N2[3 * j + 2];
      s.c12[3 * i + j] = x12[3 * i + j] + L3[3 * i + j] + tY * (L1[3 * i + j] + X11f[3 * i + j])
                       + L2[3 * j + i] + kn + y12[3 * i + j];
    }
  float tY2 = tY * tY;
#pragma unroll
  for (int s6 = 0; s6 < 6; s6++) {
    const int i = SI6[s6], j = SJ6[s6];
    float kn = K2[3 * i + 0] * N2[3 * j + 0] + K2[3 * i + 1] * N2[3 * j + 1] + K2[3 * i + 2] * N2[3 * j + 2];
    s.c22[s6] = x22[s6] + kn + L4[3 * i + j] + L4[3 * j + i]
              + tY * (L2[3 * i + j] + L2[3 * j + i] + x12[3 * i + j] + x12[3 * j + i])
              + tY2 * X11f[3 * i + j] + y22[s6];
  }

#pragma unroll
  for (int k = 0; k < 9; k++) s.P20[k] = xP20[k] + tY * xP10[k] + N2[k];
#pragma unroll
  for (int k = 0; k < 9; k++) s.P10[k] = xP10[k] + N1[k];
}

// full sandwich A <- R A R^T
static __device__ __forceinline__ void sandw(const float R[9], float A[9]) {
  float T1[9]; mm(R, A, T1);
  mmT(T1, R, A);
}

__global__ __launch_bounds__(256, 1) void imu_kernel(
    const float* __restrict__ dt, const float* __restrict__ ang, const float* __restrict__ acc,
    const float* __restrict__ pos0, const float* __restrict__ vel0, const float* __restrict__ rot0,
    float* __restrict__ out, int B, int N) {
  int lane = threadIdx.x & 63;
  int wave = threadIdx.x >> 6;
  int b = blockIdx.x * 4 + wave;
  if (b >= B) return;
  int chunk = N >> 6; // 16 steps per lane

  long base = (long)b * N + (long)lane * chunk;
  const float* dtp = dt + base;
  const float* angp = ang + base * 3;
  const float* accp = acc + base * 3;

  // ---- pre-pass: chunk rotation product (float4 loads, Taylor exp) ----
  float qc[4] = {0.f, 0.f, 0.f, 1.f};
#pragma unroll 1
  for (int jb = 0; jb < (chunk >> 2); ++jb) {
    float4 d4 = *reinterpret_cast<const float4*>(dtp + jb * 4);
    float4 g0 = *reinterpret_cast<const float4*>(angp + jb * 12 + 0);
    float4 g1 = *reinterpret_cast<const float4*>(angp + jb * 12 + 4);
    float4 g2 = *reinterpret_cast<const float4*>(angp + jb * 12 + 8);
    float dd[4] = {d4.x, d4.y, d4.z, d4.w};
    float gg[12] = {g0.x, g0.y, g0.z, g0.w, g1.x, g1.y, g1.z, g1.w, g2.x, g2.y, g2.z, g2.w};
#pragma unroll
    for (int u = 0; u < 4; ++u) {
      float dtv = dd[u];
      float px = gg[3 * u + 0] * dtv, py = gg[3 * u + 1] * dtv, pz = gg[3 * u + 2] * dtv;
      float t2 = px * px + py * py + pz * pz;
      float s_ = 0.5f - t2 * (1.0f / 48.0f);
      float qd[4] = {px * s_, py * s_, pz * s_, 1.0f - 0.125f * t2};
      float qn[4]; qmul(qc, qd, qn);
      qc[0] = qn[0]; qc[1] = qn[1]; qc[2] = qn[2]; qc[3] = qn[3];
    }
  }
  // inclusive shuffle-up scan (non-commutative)
#pragma unroll
  for (int d = 1; d < 64; d <<= 1) {
    float o0 = __shfl_up(qc[0], d, 64);
    float o1 = __shfl_up(qc[1], d, 64);
    float o2 = __shfl_up(qc[2], d, 64);
    float o3 = __shfl_up(qc[3], d, 64);
    if (lane >= d) {
      float oq[4] = {o0, o1, o2, o3};
      float nn[4]; qmul(oq, qc, nn);
      qc[0] = nn[0]; qc[1] = nn[1]; qc[2] = nn[2]; qc[3] = nn[3];
    }
  }
  // exclusive prefix Q
  float Q[4];
  Q[0] = __shfl_up(qc[0], 1, 64);
  Q[1] = __shfl_up(qc[1], 1, 64);
  Q[2] = __shfl_up(qc[2], 1, 64);
  Q[3] = __shfl_up(qc[3], 1, 64);
  if (lane == 0) { Q[0] = 0.f; Q[1] = 0.f; Q[2] = 0.f; Q[3] = 1.f; }

  float RQ[9]; q2m(Q, RQ);

  // per-lane gravity in chunk-start frame: g_l = RQ^T (R0^T g)
  float r0q[4] = {rot0[b * 4 + 0], rot0[b * 4 + 1], rot0[b * 4 + 2], rot0[b * 4 + 3]};
  float g_l[3];
  {
    float R0[9]; q2m(r0q, R0);
    float gp[3] = {R0[6] * GRAVITY_C, R0[7] * GRAVITY_C, R0[8] * GRAVITY_C};
#pragma unroll
    for (int i = 0; i < 3; i++)
      g_l[i] = RQ[0 + i] * gp[0] + RQ[3 + i] * gp[1] + RQ[6 + i] * gp[2];
  }

  Seg s = {};
  s.q[3] = 1.0f;
  float Ro[9] = {1.f, 0.f, 0.f, 0.f, 1.f, 0.f, 0.f, 0.f, 1.f};
  float gb[3] = {g_l[0], g_l[1], g_l[2]};

  // ---- phase 1: 1 step/iter with 1-deep prefetch (tight body, R4 shape) ----
  float dc = dtp[0];
  float gx = angp[0], gy = angp[1], gz = angp[2];
  float ax = accp[0], ay = accp[1], az = accp[2];
#pragma unroll 1
  for (int j = 0; j < chunk; ++j) {
    int jn = (j + 1 < chunk) ? j + 1 : j;
    float dn = dtp[jn];
    float gnx = angp[3 * jn + 0], gny = angp[3 * jn + 1], gnz = angp[3 * jn + 2];
    float anx = accp[3 * jn + 0], any2 = accp[3 * jn + 1], anz = accp[3 * jn + 2];
    step(s, Ro, gb, dc, gx, gy, gz, ax, ay, az);
    dc = dn; gx = gnx; gy = gny; gz = gnz; ax = anx; ay = any2; az = anz;
  }

  // ---- globalize: every block -> sequence-start frame via RQ ----
  {
    float tv[3];
#pragma unroll
    for (int i = 0; i < 3; i++)
      tv[i] = RQ[3 * i + 0] * s.dv[0] + RQ[3 * i + 1] * s.dv[1] + RQ[3 * i + 2] * s.dv[2];
#pragma unroll
    for (int i = 0; i < 3; i++) s.dv[i] = tv[i];
#pragma unroll
    for (int i = 0; i < 3; i++)
      tv[i] = RQ[3 * i + 0] * s.dp[0] + RQ[3 * i + 1] * s.dp[1] + RQ[3 * i + 2] * s.dp[2];
#pragma unroll
    for (int i = 0; i < 3; i++) s.dp[i] = tv[i];
    sandw(RQ, s.P10);
    sandw(RQ, s.P20);
    sandw(RQ, s.c01);
    sandw(RQ, s.c02);
    sandw(RQ, s.c12);
    float F[9];
    expand6(s.c00, F); sandw(RQ, F);
    s.c00[0] = F[0]; s.c00[1] = F[1]; s.c00[2] = F[2]; s.c00[3] = F[4]; s.c00[4] = F[5]; s.c00[5] = F[8];
    expand6(s.c11, F); sandw(RQ, F);
    s.c11[0] = F[0]; s.c11[1] = F[1]; s.c11[2] = F[2]; s.c11[3] = F[4]; s.c11[4] = F[5]; s.c11[5] = F[8];
    expand6(s.c22, F); sandw(RQ, F);
    s.c22[0] = F[0]; s.c22[1] = F[1]; s.c22[2] = F[2]; s.c22[3] = F[4]; s.c22[4] = F[5]; s.c22[5] = F[8];
  }

  // ---- phase 2: rotation-free butterfly ----
#pragma unroll 1
  for (int d = 1; d < 64; d <<= 1) compose(s, d, lane);

  if (lane == 0) {
    float p0[3] = {pos0[b * 3 + 0], pos0[b * 3 + 1], pos0[b * 3 + 2]};
    float v0[3] = {vel0[b * 3 + 0], vel0[b * 3 + 1], vel0[b * 3 + 2]};
    float R0[9]; q2m(r0q, R0);
    float qo[4]; qmul(r0q, s.q, qo);
#pragma unroll
    for (int i = 0; i < 4; i++) out[b * 4 + i] = qo[i];
#pragma unroll
    for (int i = 0; i < 3; i++) {
      float vv = v0[i] + R0[3 * i + 0] * s.dv[0] + R0[3 * i + 1] * s.dv[1] + R0[3 * i + 2] * s.dv[2];
      float pv = p0[i] + v0[i] * s.t + R0[3 * i + 0] * s.dp[0] + R0[3 * i + 1] * s.dp[1] + R0[3 * i + 2] * s.dp[2];
      out[4 * B + b * 3 + i] = vv;
      out[7 * B + b * 3 + i] = pv;
    }
    // convert theta-indexed blocks back to end-body frame convention
    float Rq[9]; q2m(s.q, Rq);
    float C00f[9];
    {
      float G[9]; expand6(s.c00, G);
      float T1[9]; mTm(Rq, G, T1);
      mm(T1, Rq, C00f);
    }
    float C01f[9]; mTm(Rq, s.c01, C01f);
    float C02f[9]; mTm(Rq, s.c02, C02f);
    float C11f[9], C22f[9];
    expand6(s.c11, C11f); expand6(s.c22, C22f);

    long cb = 10L * B + (long)b * 81;
#pragma unroll
    for (int i = 0; i < 3; i++)
#pragma unroll
      for (int j = 0; j < 3; j++) {
        out[cb + i * 9 + j]           = C00f[3 * i + j];
        out[cb + i * 9 + (j + 3)]     = C01f[3 * i + j];
        out[cb + i * 9 + (j + 6)]     = C02f[3 * i + j];
        out[cb + (i + 3) * 9 + j]     = C01f[3 * j + i];
        out[cb + (i + 3) * 9 + j + 3] = C11f[3 * i + j];
        out[cb + (i + 3) * 9 + j + 6] = s.c12[3 * i + j];
        out[cb + (i + 6) * 9 + j]     = C02f[3 * j + i];
        out[cb + (i + 6) * 9 + j + 3] = s.c12[3 * j + i];
        out[cb + (i + 6) * 9 + j + 6] = C22f[3 * i + j];
      }
  }
}

extern "C" void kernel_launch(void* const* d_in, const int* in_sizes, int n_in,
                              void* d_out, int out_size, void* d_ws, size_t ws_size,
                              hipStream_t stream) {
  const float* dt   = (const float*)d_in[0];
  const float* ang  = (const float*)d_in[1];
  const float* acc  = (const float*)d_in[2];
  const float* pos0 = (const float*)d_in[3];
  const float* vel0 = (const float*)d_in[4];
  const float* rot0 = (const float*)d_in[5];
  int B = in_sizes[5] / 4;
  int N = in_sizes[0] / B;
  float* out = (float*)d_out;
  dim3 grid((B + 3) / 4), block(256);
  imu_kernel<<<grid, block, 0, stream>>>(dt, ang, acc, pos0, vel0, rot0, out, B, N);
}